// Round 4
// baseline (1057.047 us; speedup 1.0000x reference)
//
#include <hip/hip_runtime.h>
#include <hip/hip_bf16.h>

// PCT segmentation forward. R21 = R20 + K2 (128x128-tile split-bf16 GEMM).
// - K2 (gemm_nt_split2): BM=BN=128, BK=64, 4 waves each 64x64 out (acc 4x4),
//   96 MFMA/wave/K-step vs K1's 24, MFMA:ds_read 3:1 vs 1.5:1 (ladder: 64sq
//   343 TF -> 128sq 912 TF). Same XOR-swizzled staging + epilogue as K1.
//   Routed: conv3, pt1, pt2, xv, tconv, s2 (128-block grids), cf, s1 (256).
//   Kept on K1/K1B: conv2, xq (N=128 -> 64-block grid too small), s3 (N=50).
// - attention path identical to R20/R13 (attn_pv 50.5us x4, rs_k pipelined).
// Ledger: R18 direct-V (60us) and R19 CSPLIT (85us) attn variants regressed;
// R18 rs_k pipeline is neutral (784 vs 787), kept.

#define NPTS 4096
#define BATCH 2
#define MSPLIT 4
#define RSSPLIT 8
static constexpr float INV_STD = 0.9999950000374997f;  // 1/sqrt(1+1e-5)

__device__ __forceinline__ float bf2f(unsigned short u) {
    return __uint_as_float(((unsigned int)u) << 16);
}
__device__ __forceinline__ unsigned short f2bf(float f) {
    unsigned int x = __float_as_uint(f);
    unsigned int r = (x + 0x7FFFu + ((x >> 16) & 1u)) >> 16;
    return (unsigned short)r;
}

// async global->LDS 16B DMA: LDS base wave-uniform; HW writes lptr+lane*16.
__device__ __forceinline__ void async16(const unsigned short* g, unsigned short* l)
{
    __builtin_amdgcn_global_load_lds(
        (const __attribute__((address_space(1))) unsigned int*)(const void*)g,
        (__attribute__((address_space(3))) unsigned int*)(void*)l,
        16, 0, 0);
}

typedef __attribute__((ext_vector_type(8))) short short8;
typedef __attribute__((ext_vector_type(4))) float f32x4;

// ---------------- weight pre-split ----------------
struct WSplit {
    const float* src[14];
    int n[14];
    long long off[14];   // ushort offset of hi plane; lo at off+n
};

__global__ __launch_bounds__(256)
void presplit_k(WSplit d, unsigned short* __restrict__ wbuf)
{
    int wi = blockIdx.y;
    int i = blockIdx.x * 256 + threadIdx.x;
    int n = d.n[wi];
    if (i >= n) return;
    float v = d.src[wi][i];
    unsigned short h = f2bf(v);
    unsigned short* dst = wbuf + d.off[wi];
    dst[i] = h;
    dst[n + i] = f2bf(v - bf2f(h));
}

// shared epilogue
__device__ __forceinline__ void nt_epilogue(
    float y, int rg, int cg, int b, int Nb,
    const float* bias, int bias_mode,
    const float* bng, const float* bnb,
    const unsigned short* res, long long res_bs, int res_ld, long long res_po,
    int act, int out_mode,
    void* Cp, long long c_bs, int c_ld, long long c_po)
{
    if (bias) {
        if (bias_mode == 3)      y += bias[rg];
        else if (bias_mode == 2) y += bias[b * Nb + cg];
        else                     y += bias[cg];
    }
    if (bng) y = y * (INV_STD * bng[cg]) + bnb[cg];
    if (act == 1) y = fmaxf(y, 0.f);
    else if (act == 2) y = (y > 0.f) ? y : 0.2f * y;
    if (res) {
        long long ri_ = (long long)b * res_bs + (long long)rg * res_ld + cg;
        y += bf2f(res[ri_]) + bf2f(res[res_po + ri_]);
    }
    long long ci = (long long)b * c_bs + (long long)rg * c_ld + cg;
    if (out_mode == 0) {
        unsigned short* C = (unsigned short*)Cp;
        unsigned short h = f2bf(y);
        C[ci] = h;
        C[c_po + ci] = f2bf(y - bf2f(h));
    } else if (out_mode == 1) {
        ((unsigned short*)Cp)[ci] = f2bf(y);
    } else {
        if (cg < Nb) ((float*)Cp)[ci] = y;
    }
}

// ---------------- K1: split-bf16 NT GEMM, 64x64 tile, BK=64 ----------------
__global__ __launch_bounds__(256)
void gemm_nt_split(const unsigned short* __restrict__ A, long long a_bs, int a_lda, long long a_po,
                   const unsigned short* __restrict__ B, long long b_bs, int b_lda, long long b_po,
                   void* __restrict__ Cp, long long c_bs, int c_ld, long long c_po,
                   int Nb, int K,
                   const float* __restrict__ bias, int bias_mode,
                   const float* __restrict__ bng, const float* __restrict__ bnb,
                   const unsigned short* __restrict__ res, long long res_bs, int res_ld, long long res_po,
                   int act, int out_mode)
{
    __shared__ unsigned short As[2][64 * 64];
    __shared__ unsigned short Bs[2][64 * 64];
    const int b = blockIdx.z;
    const int m0 = blockIdx.y * 64, n0 = blockIdx.x * 64;
    const int t = threadIdx.x;
    const int lane = t & 63, w = t >> 6;
    const int wr = (w >> 1) * 32, wc = (w & 1) * 32;
    const int ml = lane & 15, q = lane >> 4;

    f32x4 acc[2][2] = {};

    for (int k0 = 0; k0 < K; k0 += 64) {
        __syncthreads();
        #pragma unroll
        for (int e = 0; e < 2; e++) {
            int idx = t + e * 256;
            int row = idx >> 3, blk = idx & 7;
            int gblk = blk ^ (row & 7);
            int lofs = (e * 256 + (t & 192)) * 8;
            const unsigned short* sA = A + (long long)b * a_bs
                                     + (long long)(m0 + row) * a_lda + k0 + gblk * 8;
            const unsigned short* sB = B + (long long)b * b_bs
                                     + (long long)(n0 + row) * b_lda + k0 + gblk * 8;
            async16(sA,        &As[0][0] + lofs);
            async16(sA + a_po, &As[1][0] + lofs);
            async16(sB,        &Bs[0][0] + lofs);
            async16(sB + b_po, &Bs[1][0] + lofs);
        }
        __syncthreads();
        #pragma unroll
        for (int kk = 0; kk < 2; kk++) {
            short8 ah[2], al[2], bh[2], bl[2];
            #pragma unroll
            for (int it = 0; it < 2; it++) {
                int row = wr + it * 16 + ml;
                int slot = (kk * 4 + q) ^ (row & 7);
                ah[it] = *(const short8*)(&As[0][row * 64 + slot * 8]);
                al[it] = *(const short8*)(&As[1][row * 64 + slot * 8]);
            }
            #pragma unroll
            for (int jt = 0; jt < 2; jt++) {
                int row = wc + jt * 16 + ml;
                int slot = (kk * 4 + q) ^ (row & 7);
                bh[jt] = *(const short8*)(&Bs[0][row * 64 + slot * 8]);
                bl[jt] = *(const short8*)(&Bs[1][row * 64 + slot * 8]);
            }
            #pragma unroll
            for (int it = 0; it < 2; it++)
                #pragma unroll
                for (int jt = 0; jt < 2; jt++) {
                    acc[it][jt] = __builtin_amdgcn_mfma_f32_16x16x32_bf16(ah[it], bh[jt], acc[it][jt], 0, 0, 0);
                    acc[it][jt] = __builtin_amdgcn_mfma_f32_16x16x32_bf16(ah[it], bl[jt], acc[it][jt], 0, 0, 0);
                    acc[it][jt] = __builtin_amdgcn_mfma_f32_16x16x32_bf16(al[it], bh[jt], acc[it][jt], 0, 0, 0);
                }
        }
    }

    #pragma unroll
    for (int it = 0; it < 2; it++)
        #pragma unroll
        for (int jt = 0; jt < 2; jt++)
            #pragma unroll
            for (int r = 0; r < 4; r++)
                nt_epilogue(acc[it][jt][r], m0 + wr + it * 16 + q * 4 + r,
                            n0 + wc + jt * 16 + ml, b, Nb,
                            bias, bias_mode, bng, bnb, res, res_bs, res_ld, res_po,
                            act, out_mode, Cp, c_bs, c_ld, c_po);
}

// ---------------- K1B: split-bf16 NT GEMM, 64x64 tile, BK=128 ----------------
__global__ __launch_bounds__(256)
void gemm_nt_splitB(const unsigned short* __restrict__ A, long long a_bs, int a_lda, long long a_po,
                    const unsigned short* __restrict__ B, long long b_bs, int b_lda, long long b_po,
                    void* __restrict__ Cp, long long c_bs, int c_ld, long long c_po,
                    int Nb, int K,
                    const float* __restrict__ bias, int bias_mode,
                    const float* __restrict__ bng, const float* __restrict__ bnb,
                    const unsigned short* __restrict__ res, long long res_bs, int res_ld, long long res_po,
                    int act, int out_mode)
{
    __shared__ unsigned short As[2][2][64 * 64];   // [plane][sub] 32 KB
    __shared__ unsigned short Bs[2][2][64 * 64];   // 32 KB
    const int b = blockIdx.z;
    const int m0 = blockIdx.y * 64, n0 = blockIdx.x * 64;
    const int t = threadIdx.x;
    const int lane = t & 63, w = t >> 6;
    const int wr = (w >> 1) * 32, wc = (w & 1) * 32;
    const int ml = lane & 15, q = lane >> 4;

    f32x4 acc[2][2] = {};

    for (int k0 = 0; k0 < K; k0 += 128) {
        __syncthreads();
        #pragma unroll
        for (int sub = 0; sub < 2; sub++) {
            int kb = k0 + sub * 64;
            #pragma unroll
            for (int e = 0; e < 2; e++) {
                int idx = t + e * 256;
                int row = idx >> 3, blk = idx & 7;
                int gblk = blk ^ (row & 7);
                int lofs = (e * 256 + (t & 192)) * 8;
                const unsigned short* sA = A + (long long)b * a_bs
                                         + (long long)(m0 + row) * a_lda + kb + gblk * 8;
                const unsigned short* sB = B + (long long)b * b_bs
                                         + (long long)(n0 + row) * b_lda + kb + gblk * 8;
                async16(sA,        &As[0][sub][0] + lofs);
                async16(sA + a_po, &As[1][sub][0] + lofs);
                async16(sB,        &Bs[0][sub][0] + lofs);
                async16(sB + b_po, &Bs[1][sub][0] + lofs);
            }
        }
        __syncthreads();
        #pragma unroll
        for (int sub = 0; sub < 2; sub++)
            #pragma unroll
            for (int kk = 0; kk < 2; kk++) {
                short8 ah[2], al[2], bh[2], bl[2];
                #pragma unroll
                for (int it = 0; it < 2; it++) {
                    int row = wr + it * 16 + ml;
                    int slot = (kk * 4 + q) ^ (row & 7);
                    ah[it] = *(const short8*)(&As[0][sub][row * 64 + slot * 8]);
                    al[it] = *(const short8*)(&As[1][sub][row * 64 + slot * 8]);
                }
                #pragma unroll
                for (int jt = 0; jt < 2; jt++) {
                    int row = wc + jt * 16 + ml;
                    int slot = (kk * 4 + q) ^ (row & 7);
                    bh[jt] = *(const short8*)(&Bs[0][sub][row * 64 + slot * 8]);
                    bl[jt] = *(const short8*)(&Bs[1][sub][row * 64 + slot * 8]);
                }
                #pragma unroll
                for (int it = 0; it < 2; it++)
                    #pragma unroll
                    for (int jt = 0; jt < 2; jt++) {
                        acc[it][jt] = __builtin_amdgcn_mfma_f32_16x16x32_bf16(ah[it], bh[jt], acc[it][jt], 0, 0, 0);
                        acc[it][jt] = __builtin_amdgcn_mfma_f32_16x16x32_bf16(ah[it], bl[jt], acc[it][jt], 0, 0, 0);
                        acc[it][jt] = __builtin_amdgcn_mfma_f32_16x16x32_bf16(al[it], bh[jt], acc[it][jt], 0, 0, 0);
                    }
            }
    }

    #pragma unroll
    for (int it = 0; it < 2; it++)
        #pragma unroll
        for (int jt = 0; jt < 2; jt++)
            #pragma unroll
            for (int r = 0; r < 4; r++)
                nt_epilogue(acc[it][jt][r], m0 + wr + it * 16 + q * 4 + r,
                            n0 + wc + jt * 16 + ml, b, Nb,
                            bias, bias_mode, bng, bnb, res, res_bs, res_ld, res_po,
                            act, out_mode, Cp, c_bs, c_ld, c_po);
}

// ---------------- K2: split-bf16 NT GEMM, 128x128 tile, BK=64 ----------------
// 4 waves, each owns a 64x64 output quadrant (acc 4x4 of 16x16 frags).
// 96 MFMA/wave/K-step, 32 ds_read_b128/wave/K-step. LDS 64 KB (4 planes).
__global__ __launch_bounds__(256)
void gemm_nt_split2(const unsigned short* __restrict__ A, long long a_bs, int a_lda, long long a_po,
                    const unsigned short* __restrict__ B, long long b_bs, int b_lda, long long b_po,
                    void* __restrict__ Cp, long long c_bs, int c_ld, long long c_po,
                    int Nb, int K,
                    const float* __restrict__ bias, int bias_mode,
                    const float* __restrict__ bng, const float* __restrict__ bnb,
                    const unsigned short* __restrict__ res, long long res_bs, int res_ld, long long res_po,
                    int act, int out_mode)
{
    __shared__ unsigned short As[2][128 * 64];   // [plane] 16 KB each
    __shared__ unsigned short Bs[2][128 * 64];
    const int b = blockIdx.z;
    const int m0 = blockIdx.y * 128, n0 = blockIdx.x * 128;
    const int t = threadIdx.x;
    const int lane = t & 63, w = t >> 6;
    const int wr = (w >> 1) * 64, wc = (w & 1) * 64;
    const int ml = lane & 15, q = lane >> 4;

    f32x4 acc[4][4] = {};

    for (int k0 = 0; k0 < K; k0 += 64) {
        __syncthreads();
        #pragma unroll
        for (int e = 0; e < 4; e++) {
            int idx = t + e * 256;            // 0..1023: row=idx>>3 (0..127), blk=idx&7
            int row = idx >> 3, blk = idx & 7;
            int gblk = blk ^ (row & 7);
            int lofs = (e * 256 + (t & 192)) * 8;
            const unsigned short* sA = A + (long long)b * a_bs
                                     + (long long)(m0 + row) * a_lda + k0 + gblk * 8;
            const unsigned short* sB = B + (long long)b * b_bs
                                     + (long long)(n0 + row) * b_lda + k0 + gblk * 8;
            async16(sA,        &As[0][0] + lofs);
            async16(sA + a_po, &As[1][0] + lofs);
            async16(sB,        &Bs[0][0] + lofs);
            async16(sB + b_po, &Bs[1][0] + lofs);
        }
        __syncthreads();
        #pragma unroll
        for (int kk = 0; kk < 2; kk++) {
            short8 ah[4], al[4], bh[4], bl[4];
            #pragma unroll
            for (int it = 0; it < 4; it++) {
                int row = wr + it * 16 + ml;
                int slot = (kk * 4 + q) ^ (row & 7);
                ah[it] = *(const short8*)(&As[0][row * 64 + slot * 8]);
                al[it] = *(const short8*)(&As[1][row * 64 + slot * 8]);
            }
            #pragma unroll
            for (int jt = 0; jt < 4; jt++) {
                int row = wc + jt * 16 + ml;
                int slot = (kk * 4 + q) ^ (row & 7);
                bh[jt] = *(const short8*)(&Bs[0][row * 64 + slot * 8]);
                bl[jt] = *(const short8*)(&Bs[1][row * 64 + slot * 8]);
            }
            #pragma unroll
            for (int it = 0; it < 4; it++)
                #pragma unroll
                for (int jt = 0; jt < 4; jt++) {
                    acc[it][jt] = __builtin_amdgcn_mfma_f32_16x16x32_bf16(ah[it], bh[jt], acc[it][jt], 0, 0, 0);
                    acc[it][jt] = __builtin_amdgcn_mfma_f32_16x16x32_bf16(ah[it], bl[jt], acc[it][jt], 0, 0, 0);
                    acc[it][jt] = __builtin_amdgcn_mfma_f32_16x16x32_bf16(al[it], bh[jt], acc[it][jt], 0, 0, 0);
                }
        }
    }

    #pragma unroll
    for (int it = 0; it < 4; it++)
        #pragma unroll
        for (int jt = 0; jt < 4; jt++)
            #pragma unroll
            for (int r = 0; r < 4; r++)
                nt_epilogue(acc[it][jt][r], m0 + wr + it * 16 + q * 4 + r,
                            n0 + wc + jt * 16 + ml, b, Nb,
                            bias, bias_mode, bng, bnb, res, res_bs, res_ld, res_po,
                            act, out_mode, Cp, c_bs, c_ld, c_po);
}

// ---------------- E1: rs[p] = sum_m exp(e[p][m]), atomic row-sums ----------------
__global__ __launch_bounds__(256)
void rs_k(const unsigned short* __restrict__ xq, float* __restrict__ rs)
{
    __shared__ unsigned short Kq[2][2][64 * 64];   // [dbuf][half] 32 KB
    const int b = blockIdx.z;
    const int p0 = blockIdx.y * 64;
    const int m_beg = blockIdx.x * (NPTS / RSSPLIT);
    const unsigned short* xqB = xq + (long long)b * NPTS * 128;
    const int t = threadIdx.x;
    const int lane = t & 63, w = t >> 6;
    const int pw = w * 16;
    const int ml = lane & 15, q = lane >> 4;

    short8 af[4];
    #pragma unroll
    for (int ks = 0; ks < 4; ks++)
        af[ks] = *(const short8*)(xqB + (long long)(p0 + pw + ml) * 128 + ks * 32 + q * 8);

    float rsum[4] = {0.f, 0.f, 0.f, 0.f};

    auto stageK = [&](int m0, int buf) {
        #pragma unroll
        for (int e = 0; e < 4; e++) {
            int idx = t + e * 256;
            int sub = idx >> 9, row = (idx >> 3) & 63, blk = idx & 7;
            int gblk = blk ^ (row & 7);
            int lofs = (e * 256 + (t & 192)) * 8;
            async16(xqB + (long long)(m0 + row) * 128 + sub * 64 + gblk * 8,
                    &Kq[buf][0][0] + lofs);
        }
    };

    constexpr int NIT = (NPTS / RSSPLIT) / 64;
    stageK(m_beg, 0);
    __syncthreads();

    for (int it = 0; it < NIT; ++it) {
        const int m0 = m_beg + it * 64;
        const int cur = it & 1;
        if (it + 1 < NIT) stageK(m0 + 64, cur ^ 1);
        f32x4 acc[4] = {};
        #pragma unroll
        for (int ks = 0; ks < 4; ks++) {
            int kh = ks >> 1, kk = ks & 1;
            #pragma unroll
            for (int jt = 0; jt < 4; jt++) {
                int row = jt * 16 + ml;
                int slot = (kk * 4 + q) ^ (row & 7);
                short8 bf = *(const short8*)(&Kq[cur][kh][row * 64 + slot * 8]);
                acc[jt] = __builtin_amdgcn_mfma_f32_16x16x32_bf16(af[ks], bf, acc[jt], 0, 0, 0);
            }
        }
        #pragma unroll
        for (int jt = 0; jt < 4; jt++)
            #pragma unroll
            for (int r = 0; r < 4; r++)
                rsum[r] += __expf(acc[jt][r]);
        __syncthreads();   // drains next-iter staging; protects Kq[cur] overwrite
    }
    #pragma unroll
    for (int r = 0; r < 4; r++) {
        float s = rsum[r];
        s += __shfl_xor(s, 1); s += __shfl_xor(s, 2);
        s += __shfl_xor(s, 4); s += __shfl_xor(s, 8);
        if (ml == 0) atomicAdd(&rs[b * NPTS + p0 + pw + q * 4 + r], s);
    }
}

// ---------------- E2: QK -> exp/rs[m] -> PV partials + cs partials ----------------
// R13 structure: joint Kq+Vv DMA staging, 3 barriers/iter, 64p x 256c
// register PV, plain per-chunk partials + csp.
__global__ __launch_bounds__(256)
void attn_pv(const unsigned short* __restrict__ xq,   // [B][N][128]
             const unsigned short* __restrict__ xv,   // [B][256][N]
             const float* __restrict__ rs,
             float* __restrict__ part,                // [B*MSPLIT][N][256]
             float* __restrict__ csp)                 // [B*MSPLIT][N]
{
    __shared__ unsigned short Kq[2][64 * 64];   // 16 KB
    __shared__ unsigned short Vv[256 * 64];     // 32 KB
    __shared__ unsigned short Pl[64][72];       // 9.2 KB
    const int z = blockIdx.z, b = z / MSPLIT, ms = z % MSPLIT;
    const int p0 = blockIdx.y * 64;
    const unsigned short* xqB = xq + (long long)b * NPTS * 128;
    const unsigned short* xvB = xv + (long long)b * 256 * NPTS;
    const float* rsB = rs + b * NPTS;
    const int t = threadIdx.x;
    const int lane = t & 63, w = t >> 6;
    const int pw = w * 16;                      // QK p-strip
    const int cw = w * 64;                      // PV c-strip
    const int ml = lane & 15, q = lane >> 4;

    short8 af[4];
    #pragma unroll
    for (int ks = 0; ks < 4; ks++)
        af[ks] = *(const short8*)(xqB + (long long)(p0 + pw + ml) * 128 + ks * 32 + q * 8);

    f32x4 pv[4][4] = {};                        // [p-tile][c-tile]
    float csr[4] = {0.f, 0.f, 0.f, 0.f};

    const int m_beg = ms * (NPTS / MSPLIT);
    for (int m0 = m_beg; m0 < m_beg + NPTS / MSPLIT; m0 += 64) {
        __syncthreads();
        #pragma unroll
        for (int e = 0; e < 4; e++) {
            int idx = t + e * 256;
            int sub = idx >> 9, row = (idx >> 3) & 63, blk = idx & 7;
            int gblk = blk ^ (row & 7);
            int lofs = (e * 256 + (t & 192)) * 8;
            async16(xqB + (long long)(m0 + row) * 128 + sub * 64 + gblk * 8,
                    &Kq[0][0] + lofs);
        }
        #pragma unroll
        for (int e = 0; e < 8; e++) {
            int idx = t + e * 256;
            int row = idx >> 3, blk = idx & 7;
            int gblk = blk ^ (row & 7);
            int lofs = (e * 256 + (t & 192)) * 8;
            async16(xvB + (long long)row * NPTS + m0 + gblk * 8, Vv + lofs);
        }
        __syncthreads();
        // QK: e[p64][m64]; this wave: p-strip pw (identical chain to rs_k)
        f32x4 acc[4] = {};
        #pragma unroll
        for (int ks = 0; ks < 4; ks++) {
            int kh = ks >> 1, kk = ks & 1;
            #pragma unroll
            for (int jt = 0; jt < 4; jt++) {
                int row = jt * 16 + ml;
                int slot = (kk * 4 + q) ^ (row & 7);
                short8 bf = *(const short8*)(&Kq[kh][row * 64 + slot * 8]);
                acc[jt] = __builtin_amdgcn_mfma_f32_16x16x32_bf16(af[ks], bf, acc[jt], 0, 0, 0);
            }
        }
        // P' = exp(e)/rs[m]
        #pragma unroll
        for (int jt = 0; jt < 4; jt++) {
            float rvm = 1.f / rsB[m0 + jt * 16 + ml];
            #pragma unroll
            for (int r = 0; r < 4; r++) {
                float pvv = __expf(acc[jt][r]) * rvm;
                csr[r] += pvv;
                Pl[pw + q * 4 + r][jt * 16 + ml] = f2bf(pvv);
            }
        }
        __syncthreads();
        // PV: this wave c-strip cw; A = P'[64p][64m] (shared), B = Vv rows
        #pragma unroll
        for (int kk = 0; kk < 2; kk++) {
            short8 ap[4];
            #pragma unroll
            for (int pst = 0; pst < 4; pst++)
                ap[pst] = *(const short8*)(&Pl[pst * 16 + ml][kk * 32 + q * 8]);
            #pragma unroll
            for (int jt = 0; jt < 4; jt++) {
                int row = cw + jt * 16 + ml;
                int slot = (kk * 4 + q) ^ (row & 7);
                short8 bv = *(const short8*)(&Vv[row * 64 + slot * 8]);
                #pragma unroll
                for (int pst = 0; pst < 4; pst++)
                    pv[pst][jt] = __builtin_amdgcn_mfma_f32_16x16x32_bf16(
                        ap[pst], bv, pv[pst][jt], 0, 0, 0);
            }
        }
    }
    // cs partial: reduce over 16 m-lanes, one PLAIN store per (z, p-row)
    #pragma unroll
    for (int r = 0; r < 4; r++) {
        float s = csr[r];
        s += __shfl_xor(s, 1); s += __shfl_xor(s, 2);
        s += __shfl_xor(s, 4); s += __shfl_xor(s, 8);
        if (ml == 0) csp[(long long)z * NPTS + p0 + pw + q * 4 + r] = s;
    }
    // store PV partials (plain f32)
    float* C = part + (long long)z * ((long long)NPTS * 256);
    #pragma unroll
    for (int pst = 0; pst < 4; pst++)
        #pragma unroll
        for (int jt = 0; jt < 4; jt++)
            #pragma unroll
            for (int r = 0; r < 4; r++) {
                int rg = p0 + pst * 16 + q * 4 + r;
                int cg = cw + jt * 16 + ml;
                C[(long long)rg * 256 + cg] = pv[pst][jt][r];
            }
}

// ---------------- small kernels ----------------
__global__ __launch_bounds__(256)
void conv1_k(const float* __restrict__ x, const float* __restrict__ w,
             const float* __restrict__ g, const float* __restrict__ bb,
             unsigned short* __restrict__ h, long long h_po)
{
    int b = blockIdx.y;
    int p = blockIdx.x * 4 + (threadIdx.x >> 6);
    int c = threadIdx.x & 63;
    const float* xp = x + ((long long)b * NPTS + p) * 3;
    float y = xp[0] * w[c * 3] + xp[1] * w[c * 3 + 1] + xp[2] * w[c * 3 + 2];
    y = y * (INV_STD * g[c]) + bb[c];
    y = fmaxf(y, 0.f);
    long long i = ((long long)b * NPTS + p) * 64 + c;
    unsigned short hi = f2bf(y);
    h[i] = hi;
    h[h_po + i] = f2bf(y - bf2f(hi));
}

__global__ __launch_bounds__(256)
void zero_k(float* __restrict__ p, int n)
{
    int i = blockIdx.x * 256 + threadIdx.x;
    if (i < n) p[i] = 0.f;
}

// d = x - (sum_ms part)/(1e-9 + sum_ms csp); point-major, 256 channels
__global__ __launch_bounds__(256)
void diff_k(const unsigned short* __restrict__ xin, long long x_bs, int x_ld, long long x_po,
            const float* __restrict__ part, const float* __restrict__ csp,
            unsigned short* __restrict__ d, long long d_po)
{
    long long i = (long long)blockIdx.x * 256 + threadIdx.x;  // over NPTS*256
    int b = blockIdx.y;
    int p = (int)(i >> 8), c = (int)(i & 255);
    long long xi = (long long)b * x_bs + (long long)p * x_ld + c;
    float xv = bf2f(xin[xi]) + bf2f(xin[x_po + xi]);
    float xr = 0.f, den = 1e-9f;
    #pragma unroll
    for (int ks = 0; ks < MSPLIT; ks++) {
        int z = b * MSPLIT + ks;
        xr  += part[(long long)z * ((long long)NPTS * 256) + i];
        den += csp[(long long)z * NPTS + p];
    }
    float v = xv - xr / den;
    long long di = (long long)b * NPTS * 256 + i;
    unsigned short hi = f2bf(v);
    d[di] = hi;
    d[d_po + di] = f2bf(v - bf2f(hi));
}

__global__ __launch_bounds__(256)
void gmaxp_k(const unsigned short* __restrict__ face, long long f_po, float* __restrict__ pm)
{
    int c = blockIdx.x * 256 + threadIdx.x;   // 0..511
    int ch = blockIdx.y;                      // 16 point-chunks
    int b = blockIdx.z;
    float m = -3.4e38f;
    for (int j = 0; j < 256; j++) {
        long long i = ((long long)b * NPTS + ch * 256 + j) * 512 + c;
        m = fmaxf(m, bf2f(face[i]) + bf2f(face[f_po + i]));
    }
    pm[((long long)b * 16 + ch) * 512 + c] = m;
}

__global__ __launch_bounds__(256)
void gmaxr_k(const float* __restrict__ pm, float* __restrict__ gm)
{
    int idx = blockIdx.x * 256 + threadIdx.x;  // over BATCH*512
    int b = idx >> 9, c = idx & 511;
    float m = -3.4e38f;
    for (int ch = 0; ch < 16; ch++)
        m = fmaxf(m, pm[((long long)b * 16 + ch) * 512 + c]);
    gm[idx] = m;
}

__global__ __launch_bounds__(256)
void bias2_k(const float* __restrict__ w, const float* __restrict__ g, float* __restrict__ b2)
{
    int o = blockIdx.x * 256 + threadIdx.x;
    int b = blockIdx.y;
    if (o >= 512) return;
    float s = 0.f;
    for (int c = 0; c < 512; c++) s += w[(long long)o * 1024 + 512 + c] * g[b * 512 + c];
    b2[b * 512 + o] = s;
}

extern "C" void kernel_launch(void* const* d_in, const int* in_sizes, int n_in,
                              void* d_out, int out_size, void* d_ws, size_t ws_size,
                              hipStream_t stream)
{
    const float* x       = (const float*)d_in[0];
    const float* conv1_w = (const float*)d_in[1];
    const float* bn1_g   = (const float*)d_in[2];
    const float* bn1_b   = (const float*)d_in[3];
    const float* conv2_w = (const float*)d_in[4];
    const float* bn2_g   = (const float*)d_in[5];
    const float* bn2_b   = (const float*)d_in[6];
    const float* conv3_w = (const float*)d_in[7];
    const float* bn3_g   = (const float*)d_in[8];
    const float* bn3_b   = (const float*)d_in[9];
    const float* pt1_w   = (const float*)d_in[10];
    const float* pt1_g   = (const float*)d_in[11];
    const float* pt1_b   = (const float*)d_in[12];
    const float* pt2_w   = (const float*)d_in[13];
    const float* pt2_g   = (const float*)d_in[14];
    const float* pt2_b   = (const float*)d_in[15];
    const float* sa_qk[2] = {(const float*)d_in[16], (const float*)d_in[23]};
    const float* sa_vw[2] = {(const float*)d_in[17], (const float*)d_in[24]};
    const float* sa_vb[2] = {(const float*)d_in[18], (const float*)d_in[25]};
    const float* sa_tw[2] = {(const float*)d_in[19], (const float*)d_in[26]};
    const float* sa_tb[2] = {(const float*)d_in[20], (const float*)d_in[27]};
    const float* sa_g[2]  = {(const float*)d_in[21], (const float*)d_in[28]};
    const float* sa_b[2]  = {(const float*)d_in[22], (const float*)d_in[29]};
    const float* cf_w = (const float*)d_in[30];
    const float* cf_g = (const float*)d_in[31];
    const float* cf_b = (const float*)d_in[32];
    const float* s1_w = (const float*)d_in[33];
    const float* s1_g = (const float*)d_in[34];
    const float* s1_b = (const float*)d_in[35];
    const float* s2_w = (const float*)d_in[36];
    const float* s2_g = (const float*)d_in[37];
    const float* s2_b = (const float*)d_in[38];
    const float* s3_w = (const float*)d_in[39];

    char* base = (char*)d_ws;
    size_t off = 0;
    auto alloc = [&](size_t bytes) -> void* {
        void* p = base + off;
        off = (off + bytes + 255) & ~(size_t)255;
        return p;
    };
    const long long N = NPTS;
    const long long PO64   = (long long)BATCH * N * 64;
    const long long PO128  = (long long)BATCH * N * 128;
    const long long PO256  = (long long)BATCH * N * 256;
    const long long PO512  = (long long)BATCH * N * 512;
    const long long PO1024 = (long long)BATCH * N * 1024;

    unsigned short* S1  = (unsigned short*)alloc(2 * PO256 * 2);
    unsigned short* S2  = (unsigned short*)alloc(2 * PO256 * 2);
    unsigned short* Dv  = (unsigned short*)alloc(2 * PO256 * 2);
    unsigned short* cat = (unsigned short*)alloc(2 * PO1024 * 2);
    unsigned short* face = (unsigned short*)alloc(2 * PO512 * 2);
    unsigned short* xq  = (unsigned short*)alloc((size_t)BATCH * N * 128 * 2);
    unsigned short* xv  = (unsigned short*)alloc((size_t)BATCH * 256 * N * 2);
    unsigned short* s1b = (unsigned short*)alloc(2 * PO512 * 2);
    unsigned short* s2b = (unsigned short*)alloc(2 * PO256 * 2);
    float* part = (float*)alloc((size_t)BATCH * MSPLIT * N * 256 * 4);          // 32 MB
    float* csp  = (float*)alloc((size_t)BATCH * MSPLIT * N * 4);
    float* rs = (float*)alloc((size_t)BATCH * N * 4);
    float* pm = (float*)alloc((size_t)BATCH * 16 * 512 * 4);
    float* gm = (float*)alloc((size_t)BATCH * 512 * 4);
    float* b2 = (float*)alloc((size_t)BATCH * 512 * 4);
    unsigned short* wb = (unsigned short*)alloc((size_t)3400000 * 2);  // pre-split weights

    // ---- weight pre-split table ----
    WSplit wd;
    const float* wsrc[14] = {conv2_w, conv3_w, pt1_w, pt2_w, sa_qk[0], sa_qk[1],
                             sa_vw[0], sa_vw[1], sa_tw[0], sa_tw[1], cf_w, s1_w, s2_w, s3_w};
    int wn[14] = {128*64, 256*128, 256*256, 256*256, 128*256, 128*256,
                  256*256, 256*256, 256*256, 256*256, 512*1024, 512*1024, 256*512, 50*256};
    long long wo[14]; long long acc_ = 0;
    for (int i = 0; i < 14; i++) { wd.src[i] = wsrc[i]; wd.n[i] = wn[i]; wd.off[i] = acc_; wo[i] = acc_; acc_ += 2LL * wn[i]; }
    presplit_k<<<dim3((512*1024 + 255) / 256, 14), 256, 0, stream>>>(wd, wb);
    auto W = [&](int i) { return wb + wo[i]; };

    auto nt = [&](const unsigned short* A, long long a_bs, int a_lda, long long a_po,
                  const unsigned short* B, long long b_bs, int b_lda, long long b_po,
                  void* C, long long c_bs, int c_ld, long long c_po,
                  int Mrows, int Nb, int K,
                  const float* bias, int bias_mode,
                  const float* bng, const float* bnb,
                  const unsigned short* res, long long res_bs, int res_ld, long long res_po,
                  int act, int out_mode) {
        dim3 g((Nb + 63) / 64, Mrows / 64, BATCH);
        gemm_nt_split<<<g, 256, 0, stream>>>(A, a_bs, a_lda, a_po, B, b_bs, b_lda, b_po,
                                             C, c_bs, c_ld, c_po, Nb, K,
                                             bias, bias_mode, bng, bnb,
                                             res, res_bs, res_ld, res_po, act, out_mode);
    };
    auto ntB = [&](const unsigned short* A, long long a_bs, int a_lda, long long a_po,
                   const unsigned short* B, long long b_bs, int b_lda, long long b_po,
                   void* C, long long c_bs, int c_ld, long long c_po,
                   int Mrows, int Nb, int K,
                   const float* bias, int bias_mode,
                   const float* bng, const float* bnb,
                   const unsigned short* res, long long res_bs, int res_ld, long long res_po,
                   int act, int out_mode) {
        dim3 g((Nb + 63) / 64, Mrows / 64, BATCH);
        gemm_nt_splitB<<<g, 256, 0, stream>>>(A, a_bs, a_lda, a_po, B, b_bs, b_lda, b_po,
                                              C, c_bs, c_ld, c_po, Nb, K,
                                              bias, bias_mode, bng, bnb,
                                              res, res_bs, res_ld, res_po, act, out_mode);
    };
    auto nt2 = [&](const unsigned short* A, long long a_bs, int a_lda, long long a_po,
                   const unsigned short* B, long long b_bs, int b_lda, long long b_po,
                   void* C, long long c_bs, int c_ld, long long c_po,
                   int Mrows, int Nb, int K,
                   const float* bias, int bias_mode,
                   const float* bng, const float* bnb,
                   const unsigned short* res, long long res_bs, int res_ld, long long res_po,
                   int act, int out_mode) {
        dim3 g((Nb + 127) / 128, Mrows / 128, BATCH);
        gemm_nt_split2<<<g, 256, 0, stream>>>(A, a_bs, a_lda, a_po, B, b_bs, b_lda, b_po,
                                              C, c_bs, c_ld, c_po, Nb, K,
                                              bias, bias_mode, bng, bnb,
                                              res, res_bs, res_ld, res_po, act, out_mode);
    };

    // ---- stem ----
    conv1_k<<<dim3(NPTS / 4, BATCH), 256, 0, stream>>>(x, conv1_w, bn1_g, bn1_b, S1, PO64);
    nt(S1, N * 64, 64, PO64,    W(0), 0, 64, wn[0],  S2, N * 128, 128, PO128,
       NPTS, 128, 64,  nullptr, 0, bn2_g, bn2_b, nullptr, 0, 0, 0, 1, 0);
    nt2(S2, N * 128, 128, PO128, W(1), 0, 128, wn[1], S1, N * 256, 256, PO256,
        NPTS, 256, 128, nullptr, 0, bn3_g, bn3_b, nullptr, 0, 0, 0, 1, 0);
    nt2(S1, N * 256, 256, PO256, W(2), 0, 256, wn[2], S2, N * 256, 256, PO256,
        NPTS, 256, 256, nullptr, 0, pt1_g, pt1_b, nullptr, 0, 0, 0, 1, 0);
    nt2(S2, N * 256, 256, PO256, W(3), 0, 256, wn[3], S1, N * 256, 256, PO256,
        NPTS, 256, 256, nullptr, 0, pt2_g, pt2_b, nullptr, 0, 0, 0, 1, 0);

    // ---- 4 SA layers ----
    for (int i = 0; i < 4; i++) {
        int p = (i == 0) ? 0 : 1;
        const unsigned short* xin = (i == 0) ? S1 : cat + (size_t)(i - 1) * 256;
        long long xin_bs = (i == 0) ? N * 256 : N * 1024;
        int xin_ld = (i == 0) ? 256 : 1024;
        long long xin_po = (i == 0) ? PO256 : PO1024;

        // xq[n][128] plain bf16 (K=256) — N=128 stays on K1B (grid width)
        ntB(xin, xin_bs, xin_ld, xin_po, W(4 + p), 0, 256, wn[4 + p],
            xq, N * 128, 128, 0, NPTS, 128, 256,
            nullptr, 0, nullptr, nullptr, nullptr, 0, 0, 0, 0, 1);
        // xv[c][n] plain bf16 (A = weights M=256, B = xin N=4096, K=256)
        nt2(W(6 + p), 0, 256, wn[6 + p], xin, xin_bs, xin_ld, xin_po,
            xv, 256 * N, NPTS, 0, 256, NPTS, 256,
            sa_vb[p], 3, nullptr, nullptr, nullptr, 0, 0, 0, 0, 1);
        // zero rs (needed for rs_k atomics)
        zero_k<<<(BATCH * NPTS + 255) / 256, 256, 0, stream>>>(rs, BATCH * NPTS);
        // E1: rs row-sums (no att store)
        rs_k<<<dim3(RSSPLIT, NPTS / 64, BATCH), 256, 0, stream>>>(xq, rs);
        // E2: fused QK->exp/rs->PV partials + cs partials
        attn_pv<<<dim3(1, NPTS / 64, BATCH * MSPLIT), 256, 0, stream>>>(
            xq, xv, rs, part, csp);
        // d = x - (sum partials)/(1e-9 + sum cs partials)
        diff_k<<<dim3(NPTS * 256 / 256, BATCH), 256, 0, stream>>>(
            xin, xin_bs, xin_ld, xin_po, part, csp, Dv, PO256);
        // x_out = x + relu(bn(tw@d + tb)) -> cat slice i (K=256)
        nt2(Dv, N * 256, 256, PO256, W(8 + p), 0, 256, wn[8 + p],
            cat + (size_t)i * 256, N * 1024, 1024, PO1024,
            NPTS, 256, 256, sa_tb[p], 1, sa_g[p], sa_b[p],
            xin, xin_bs, xin_ld, xin_po, 1, 0);
    }

    // ---- head ----
    nt2(cat, N * 1024, 1024, PO1024, W(10), 0, 1024, wn[10],
        face, N * 512, 512, PO512, NPTS, 512, 1024,
        nullptr, 0, cf_g, cf_b, nullptr, 0, 0, 0, 2, 0);
    gmaxp_k<<<dim3(2, 16, BATCH), 256, 0, stream>>>(face, PO512, pm);
    gmaxr_k<<<dim3(BATCH * 512 / 256), 256, 0, stream>>>(pm, gm);
    bias2_k<<<dim3(2, BATCH), 256, 0, stream>>>(s1_w, gm, b2);
    nt2(face, N * 512, 512, PO512, W(11), 0, 1024, wn[11],
        s1b, N * 512, 512, PO512, NPTS, 512, 512,
        b2, 2, s1_g, s1_b, nullptr, 0, 0, 0, 2, 0);
    nt2(s1b, N * 512, 512, PO512, W(12), 0, 512, wn[12],
        s2b, N * 256, 256, PO256, NPTS, 256, 512,
        nullptr, 0, s2_g, s2_b, nullptr, 0, 0, 0, 2, 0);
    ntB(s2b, N * 256, 256, PO256, W(13), 0, 256, wn[13],
        d_out, N * 50, 50, 0, NPTS, 50, 256,
        nullptr, 0, nullptr, nullptr, nullptr, 0, 0, 0, 0, 2);
}

// Round 5
// 752.798 us; speedup vs baseline: 1.4042x; 1.4042x over previous
//
#include <hip/hip_runtime.h>
#include <hip/hip_bf16.h>

// PCT segmentation forward. R22 = R20 (784us baseline) + bijective XCD swizzle
// (T1/m204) on all heavy kernels. K2 (128sq tile, R21) fully reverted: its
// 128-256 block grids ran 1 block/CU (half-chip idle, no overlap) and FETCH
// doubled (cross-XCD panel refetch, 68MB on cf).
// Swizzle mechanism: HW assigns dispatch-slot d -> XCD d%8; remap logical work
// w = (d%8)*(n/8) + d/8 so each XCD processes a CONTIGUOUS logical chunk:
// - attn_pv (512 blocks): XCD k gets exactly z=k's 64 p0-blocks -> per-XCD
//   working set (xq quarter 256KB*2pl + xv quarter 512KB) L2-resident;
//   FETCH was 25MB vs ~7MB unique (16x re-stage of shared panels).
// - rs_k: y-fastest decode -> each XCD owns 2 m-eighths for all p0.
// - GEMMs: each XCD gets 16 consecutive A-strips (x-fastest decode).
// Identity fallback if grid % 8 != 0 (never hit with current shapes).

#define NPTS 4096
#define BATCH 2
#define MSPLIT 4
#define RSSPLIT 8
static constexpr float INV_STD = 0.9999950000374997f;  // 1/sqrt(1+1e-5)

__device__ __forceinline__ float bf2f(unsigned short u) {
    return __uint_as_float(((unsigned int)u) << 16);
}
__device__ __forceinline__ unsigned short f2bf(float f) {
    unsigned int x = __float_as_uint(f);
    unsigned int r = (x + 0x7FFFu + ((x >> 16) & 1u)) >> 16;
    return (unsigned short)r;
}

// async global->LDS 16B DMA: LDS base wave-uniform; HW writes lptr+lane*16.
__device__ __forceinline__ void async16(const unsigned short* g, unsigned short* l)
{
    __builtin_amdgcn_global_load_lds(
        (const __attribute__((address_space(1))) unsigned int*)(const void*)g,
        (__attribute__((address_space(3))) unsigned int*)(void*)l,
        16, 0, 0);
}

typedef __attribute__((ext_vector_type(8))) short short8;
typedef __attribute__((ext_vector_type(4))) float f32x4;

// ---------------- weight pre-split ----------------
struct WSplit {
    const float* src[14];
    int n[14];
    long long off[14];   // ushort offset of hi plane; lo at off+n
};

__global__ __launch_bounds__(256)
void presplit_k(WSplit d, unsigned short* __restrict__ wbuf)
{
    int wi = blockIdx.y;
    int i = blockIdx.x * 256 + threadIdx.x;
    int n = d.n[wi];
    if (i >= n) return;
    float v = d.src[wi][i];
    unsigned short h = f2bf(v);
    unsigned short* dst = wbuf + d.off[wi];
    dst[i] = h;
    dst[n + i] = f2bf(v - bf2f(h));
}

// shared epilogue
__device__ __forceinline__ void nt_epilogue(
    float y, int rg, int cg, int b, int Nb,
    const float* bias, int bias_mode,
    const float* bng, const float* bnb,
    const unsigned short* res, long long res_bs, int res_ld, long long res_po,
    int act, int out_mode,
    void* Cp, long long c_bs, int c_ld, long long c_po)
{
    if (bias) {
        if (bias_mode == 3)      y += bias[rg];
        else if (bias_mode == 2) y += bias[b * Nb + cg];
        else                     y += bias[cg];
    }
    if (bng) y = y * (INV_STD * bng[cg]) + bnb[cg];
    if (act == 1) y = fmaxf(y, 0.f);
    else if (act == 2) y = (y > 0.f) ? y : 0.2f * y;
    if (res) {
        long long ri_ = (long long)b * res_bs + (long long)rg * res_ld + cg;
        y += bf2f(res[ri_]) + bf2f(res[res_po + ri_]);
    }
    long long ci = (long long)b * c_bs + (long long)rg * c_ld + cg;
    if (out_mode == 0) {
        unsigned short* C = (unsigned short*)Cp;
        unsigned short h = f2bf(y);
        C[ci] = h;
        C[c_po + ci] = f2bf(y - bf2f(h));
    } else if (out_mode == 1) {
        ((unsigned short*)Cp)[ci] = f2bf(y);
    } else {
        if (cg < Nb) ((float*)Cp)[ci] = y;
    }
}

// ---------------- K1: split-bf16 NT GEMM, 64x64 tile, BK=64 ----------------
__global__ __launch_bounds__(256)
void gemm_nt_split(const unsigned short* __restrict__ A, long long a_bs, int a_lda, long long a_po,
                   const unsigned short* __restrict__ B, long long b_bs, int b_lda, long long b_po,
                   void* __restrict__ Cp, long long c_bs, int c_ld, long long c_po,
                   int Nb, int K,
                   const float* __restrict__ bias, int bias_mode,
                   const float* __restrict__ bng, const float* __restrict__ bnb,
                   const unsigned short* __restrict__ res, long long res_bs, int res_ld, long long res_po,
                   int act, int out_mode)
{
    __shared__ unsigned short As[2][64 * 64];
    __shared__ unsigned short Bs[2][64 * 64];
    // bijective XCD swizzle: contiguous logical chunk per XCD
    const int gx = gridDim.x, gy = gridDim.y;
    const int nblk = gx * gy * (int)gridDim.z;
    int d_ = blockIdx.x + gx * (blockIdx.y + gy * blockIdx.z);
    int w_ = (nblk & 7) ? d_ : ((d_ & 7) * (nblk >> 3) + (d_ >> 3));
    const int b = w_ / (gx * gy);
    const int rem_ = w_ % (gx * gy);
    const int m0 = (rem_ / gx) * 64, n0 = (rem_ % gx) * 64;
    const int t = threadIdx.x;
    const int lane = t & 63, w = t >> 6;
    const int wr = (w >> 1) * 32, wc = (w & 1) * 32;
    const int ml = lane & 15, q = lane >> 4;

    f32x4 acc[2][2] = {};

    for (int k0 = 0; k0 < K; k0 += 64) {
        __syncthreads();
        #pragma unroll
        for (int e = 0; e < 2; e++) {
            int idx = t + e * 256;
            int row = idx >> 3, blk = idx & 7;
            int gblk = blk ^ (row & 7);
            int lofs = (e * 256 + (t & 192)) * 8;
            const unsigned short* sA = A + (long long)b * a_bs
                                     + (long long)(m0 + row) * a_lda + k0 + gblk * 8;
            const unsigned short* sB = B + (long long)b * b_bs
                                     + (long long)(n0 + row) * b_lda + k0 + gblk * 8;
            async16(sA,        &As[0][0] + lofs);
            async16(sA + a_po, &As[1][0] + lofs);
            async16(sB,        &Bs[0][0] + lofs);
            async16(sB + b_po, &Bs[1][0] + lofs);
        }
        __syncthreads();
        #pragma unroll
        for (int kk = 0; kk < 2; kk++) {
            short8 ah[2], al[2], bh[2], bl[2];
            #pragma unroll
            for (int it = 0; it < 2; it++) {
                int row = wr + it * 16 + ml;
                int slot = (kk * 4 + q) ^ (row & 7);
                ah[it] = *(const short8*)(&As[0][row * 64 + slot * 8]);
                al[it] = *(const short8*)(&As[1][row * 64 + slot * 8]);
            }
            #pragma unroll
            for (int jt = 0; jt < 2; jt++) {
                int row = wc + jt * 16 + ml;
                int slot = (kk * 4 + q) ^ (row & 7);
                bh[jt] = *(const short8*)(&Bs[0][row * 64 + slot * 8]);
                bl[jt] = *(const short8*)(&Bs[1][row * 64 + slot * 8]);
            }
            #pragma unroll
            for (int it = 0; it < 2; it++)
                #pragma unroll
                for (int jt = 0; jt < 2; jt++) {
                    acc[it][jt] = __builtin_amdgcn_mfma_f32_16x16x32_bf16(ah[it], bh[jt], acc[it][jt], 0, 0, 0);
                    acc[it][jt] = __builtin_amdgcn_mfma_f32_16x16x32_bf16(ah[it], bl[jt], acc[it][jt], 0, 0, 0);
                    acc[it][jt] = __builtin_amdgcn_mfma_f32_16x16x32_bf16(al[it], bh[jt], acc[it][jt], 0, 0, 0);
                }
        }
    }

    #pragma unroll
    for (int it = 0; it < 2; it++)
        #pragma unroll
        for (int jt = 0; jt < 2; jt++)
            #pragma unroll
            for (int r = 0; r < 4; r++)
                nt_epilogue(acc[it][jt][r], m0 + wr + it * 16 + q * 4 + r,
                            n0 + wc + jt * 16 + ml, b, Nb,
                            bias, bias_mode, bng, bnb, res, res_bs, res_ld, res_po,
                            act, out_mode, Cp, c_bs, c_ld, c_po);
}

// ---------------- K1B: split-bf16 NT GEMM, 64x64 tile, BK=128 ----------------
__global__ __launch_bounds__(256)
void gemm_nt_splitB(const unsigned short* __restrict__ A, long long a_bs, int a_lda, long long a_po,
                    const unsigned short* __restrict__ B, long long b_bs, int b_lda, long long b_po,
                    void* __restrict__ Cp, long long c_bs, int c_ld, long long c_po,
                    int Nb, int K,
                    const float* __restrict__ bias, int bias_mode,
                    const float* __restrict__ bng, const float* __restrict__ bnb,
                    const unsigned short* __restrict__ res, long long res_bs, int res_ld, long long res_po,
                    int act, int out_mode)
{
    __shared__ unsigned short As[2][2][64 * 64];   // [plane][sub] 32 KB
    __shared__ unsigned short Bs[2][2][64 * 64];   // 32 KB
    const int gx = gridDim.x, gy = gridDim.y;
    const int nblk = gx * gy * (int)gridDim.z;
    int d_ = blockIdx.x + gx * (blockIdx.y + gy * blockIdx.z);
    int w_ = (nblk & 7) ? d_ : ((d_ & 7) * (nblk >> 3) + (d_ >> 3));
    const int b = w_ / (gx * gy);
    const int rem_ = w_ % (gx * gy);
    const int m0 = (rem_ / gx) * 64, n0 = (rem_ % gx) * 64;
    const int t = threadIdx.x;
    const int lane = t & 63, w = t >> 6;
    const int wr = (w >> 1) * 32, wc = (w & 1) * 32;
    const int ml = lane & 15, q = lane >> 4;

    f32x4 acc[2][2] = {};

    for (int k0 = 0; k0 < K; k0 += 128) {
        __syncthreads();
        #pragma unroll
        for (int sub = 0; sub < 2; sub++) {
            int kb = k0 + sub * 64;
            #pragma unroll
            for (int e = 0; e < 2; e++) {
                int idx = t + e * 256;
                int row = idx >> 3, blk = idx & 7;
                int gblk = blk ^ (row & 7);
                int lofs = (e * 256 + (t & 192)) * 8;
                const unsigned short* sA = A + (long long)b * a_bs
                                         + (long long)(m0 + row) * a_lda + kb + gblk * 8;
                const unsigned short* sB = B + (long long)b * b_bs
                                         + (long long)(n0 + row) * b_lda + kb + gblk * 8;
                async16(sA,        &As[0][sub][0] + lofs);
                async16(sA + a_po, &As[1][sub][0] + lofs);
                async16(sB,        &Bs[0][sub][0] + lofs);
                async16(sB + b_po, &Bs[1][sub][0] + lofs);
            }
        }
        __syncthreads();
        #pragma unroll
        for (int sub = 0; sub < 2; sub++)
            #pragma unroll
            for (int kk = 0; kk < 2; kk++) {
                short8 ah[2], al[2], bh[2], bl[2];
                #pragma unroll
                for (int it = 0; it < 2; it++) {
                    int row = wr + it * 16 + ml;
                    int slot = (kk * 4 + q) ^ (row & 7);
                    ah[it] = *(const short8*)(&As[0][sub][row * 64 + slot * 8]);
                    al[it] = *(const short8*)(&As[1][sub][row * 64 + slot * 8]);
                }
                #pragma unroll
                for (int jt = 0; jt < 2; jt++) {
                    int row = wc + jt * 16 + ml;
                    int slot = (kk * 4 + q) ^ (row & 7);
                    bh[jt] = *(const short8*)(&Bs[0][sub][row * 64 + slot * 8]);
                    bl[jt] = *(const short8*)(&Bs[1][sub][row * 64 + slot * 8]);
                }
                #pragma unroll
                for (int it = 0; it < 2; it++)
                    #pragma unroll
                    for (int jt = 0; jt < 2; jt++) {
                        acc[it][jt] = __builtin_amdgcn_mfma_f32_16x16x32_bf16(ah[it], bh[jt], acc[it][jt], 0, 0, 0);
                        acc[it][jt] = __builtin_amdgcn_mfma_f32_16x16x32_bf16(ah[it], bl[jt], acc[it][jt], 0, 0, 0);
                        acc[it][jt] = __builtin_amdgcn_mfma_f32_16x16x32_bf16(al[it], bh[jt], acc[it][jt], 0, 0, 0);
                    }
            }
    }

    #pragma unroll
    for (int it = 0; it < 2; it++)
        #pragma unroll
        for (int jt = 0; jt < 2; jt++)
            #pragma unroll
            for (int r = 0; r < 4; r++)
                nt_epilogue(acc[it][jt][r], m0 + wr + it * 16 + q * 4 + r,
                            n0 + wc + jt * 16 + ml, b, Nb,
                            bias, bias_mode, bng, bnb, res, res_bs, res_ld, res_po,
                            act, out_mode, Cp, c_bs, c_ld, c_po);
}

// ---------------- E1: rs[p] = sum_m exp(e[p][m]), atomic row-sums ----------------
// R18 pipeline + XCD swizzle (y-fastest decode: each XCD owns 2 m-eighths).
__global__ __launch_bounds__(256)
void rs_k(const unsigned short* __restrict__ xq, float* __restrict__ rs)
{
    __shared__ unsigned short Kq[2][2][64 * 64];   // [dbuf][half] 32 KB
    // grid (8, 64, 2) = 1024 blocks; d -> XCD d%8; chunk = 128
    int d_ = blockIdx.x + 8 * (blockIdx.y + 64 * blockIdx.z);
    int w_ = (d_ & 7) * 128 + (d_ >> 3);
    const int p0 = (w_ % 64) * 64;          // y-fastest: p0 varies fastest
    const int xseg = (w_ / 64) % 8;
    const int b = w_ / 512;
    const int m_beg = xseg * (NPTS / RSSPLIT);
    const unsigned short* xqB = xq + (long long)b * NPTS * 128;
    const int t = threadIdx.x;
    const int lane = t & 63, w = t >> 6;
    const int pw = w * 16;
    const int ml = lane & 15, q = lane >> 4;

    short8 af[4];
    #pragma unroll
    for (int ks = 0; ks < 4; ks++)
        af[ks] = *(const short8*)(xqB + (long long)(p0 + pw + ml) * 128 + ks * 32 + q * 8);

    float rsum[4] = {0.f, 0.f, 0.f, 0.f};

    auto stageK = [&](int m0, int buf) {
        #pragma unroll
        for (int e = 0; e < 4; e++) {
            int idx = t + e * 256;
            int sub = idx >> 9, row = (idx >> 3) & 63, blk = idx & 7;
            int gblk = blk ^ (row & 7);
            int lofs = (e * 256 + (t & 192)) * 8;
            async16(xqB + (long long)(m0 + row) * 128 + sub * 64 + gblk * 8,
                    &Kq[buf][0][0] + lofs);
        }
    };

    constexpr int NIT = (NPTS / RSSPLIT) / 64;
    stageK(m_beg, 0);
    __syncthreads();

    for (int it = 0; it < NIT; ++it) {
        const int m0 = m_beg + it * 64;
        const int cur = it & 1;
        if (it + 1 < NIT) stageK(m0 + 64, cur ^ 1);
        f32x4 acc[4] = {};
        #pragma unroll
        for (int ks = 0; ks < 4; ks++) {
            int kh = ks >> 1, kk = ks & 1;
            #pragma unroll
            for (int jt = 0; jt < 4; jt++) {
                int row = jt * 16 + ml;
                int slot = (kk * 4 + q) ^ (row & 7);
                short8 bf = *(const short8*)(&Kq[cur][kh][row * 64 + slot * 8]);
                acc[jt] = __builtin_amdgcn_mfma_f32_16x16x32_bf16(af[ks], bf, acc[jt], 0, 0, 0);
            }
        }
        #pragma unroll
        for (int jt = 0; jt < 4; jt++)
            #pragma unroll
            for (int r = 0; r < 4; r++)
                rsum[r] += __expf(acc[jt][r]);
        __syncthreads();   // drains next-iter staging; protects Kq[cur] overwrite
    }
    #pragma unroll
    for (int r = 0; r < 4; r++) {
        float s = rsum[r];
        s += __shfl_xor(s, 1); s += __shfl_xor(s, 2);
        s += __shfl_xor(s, 4); s += __shfl_xor(s, 8);
        if (ml == 0) atomicAdd(&rs[b * NPTS + p0 + pw + q * 4 + r], s);
    }
}

// ---------------- E2: QK -> exp/rs[m] -> PV partials + cs partials ----------------
// R13 structure + XCD swizzle: XCD k gets exactly z=k's 64 p0-blocks, so the
// 16x re-staged xq/xv quarter panels are L2-resident per XCD.
__global__ __launch_bounds__(256)
void attn_pv(const unsigned short* __restrict__ xq,   // [B][N][128]
             const unsigned short* __restrict__ xv,   // [B][256][N]
             const float* __restrict__ rs,
             float* __restrict__ part,                // [B*MSPLIT][N][256]
             float* __restrict__ csp)                 // [B*MSPLIT][N]
{
    __shared__ unsigned short Kq[2][64 * 64];   // 16 KB
    __shared__ unsigned short Vv[256 * 64];     // 32 KB
    __shared__ unsigned short Pl[64][72];       // 9.2 KB
    // grid (1, 64, 8) = 512 blocks; chunk = 64 -> XCD k <=> z = k
    int d_ = blockIdx.y + 64 * blockIdx.z;
    int w_ = (d_ & 7) * 64 + (d_ >> 3);
    const int p0 = (w_ % 64) * 64;
    const int z = w_ / 64;
    const int b = z / MSPLIT, ms = z % MSPLIT;
    const unsigned short* xqB = xq + (long long)b * NPTS * 128;
    const unsigned short* xvB = xv + (long long)b * 256 * NPTS;
    const float* rsB = rs + b * NPTS;
    const int t = threadIdx.x;
    const int lane = t & 63, w = t >> 6;
    const int pw = w * 16;                      // QK p-strip
    const int cw = w * 64;                      // PV c-strip
    const int ml = lane & 15, q = lane >> 4;

    short8 af[4];
    #pragma unroll
    for (int ks = 0; ks < 4; ks++)
        af[ks] = *(const short8*)(xqB + (long long)(p0 + pw + ml) * 128 + ks * 32 + q * 8);

    f32x4 pv[4][4] = {};                        // [p-tile][c-tile]
    float csr[4] = {0.f, 0.f, 0.f, 0.f};

    const int m_beg = ms * (NPTS / MSPLIT);
    for (int m0 = m_beg; m0 < m_beg + NPTS / MSPLIT; m0 += 64) {
        __syncthreads();
        #pragma unroll
        for (int e = 0; e < 4; e++) {
            int idx = t + e * 256;
            int sub = idx >> 9, row = (idx >> 3) & 63, blk = idx & 7;
            int gblk = blk ^ (row & 7);
            int lofs = (e * 256 + (t & 192)) * 8;
            async16(xqB + (long long)(m0 + row) * 128 + sub * 64 + gblk * 8,
                    &Kq[0][0] + lofs);
        }
        #pragma unroll
        for (int e = 0; e < 8; e++) {
            int idx = t + e * 256;
            int row = idx >> 3, blk = idx & 7;
            int gblk = blk ^ (row & 7);
            int lofs = (e * 256 + (t & 192)) * 8;
            async16(xvB + (long long)row * NPTS + m0 + gblk * 8, Vv + lofs);
        }
        __syncthreads();
        // QK: e[p64][m64]; this wave: p-strip pw (identical chain to rs_k)
        f32x4 acc[4] = {};
        #pragma unroll
        for (int ks = 0; ks < 4; ks++) {
            int kh = ks >> 1, kk = ks & 1;
            #pragma unroll
            for (int jt = 0; jt < 4; jt++) {
                int row = jt * 16 + ml;
                int slot = (kk * 4 + q) ^ (row & 7);
                short8 bf = *(const short8*)(&Kq[kh][row * 64 + slot * 8]);
                acc[jt] = __builtin_amdgcn_mfma_f32_16x16x32_bf16(af[ks], bf, acc[jt], 0, 0, 0);
            }
        }
        // P' = exp(e)/rs[m]
        #pragma unroll
        for (int jt = 0; jt < 4; jt++) {
            float rvm = 1.f / rsB[m0 + jt * 16 + ml];
            #pragma unroll
            for (int r = 0; r < 4; r++) {
                float pvv = __expf(acc[jt][r]) * rvm;
                csr[r] += pvv;
                Pl[pw + q * 4 + r][jt * 16 + ml] = f2bf(pvv);
            }
        }
        __syncthreads();
        // PV: this wave c-strip cw; A = P'[64p][64m] (shared), B = Vv rows
        #pragma unroll
        for (int kk = 0; kk < 2; kk++) {
            short8 ap[4];
            #pragma unroll
            for (int pst = 0; pst < 4; pst++)
                ap[pst] = *(const short8*)(&Pl[pst * 16 + ml][kk * 32 + q * 8]);
            #pragma unroll
            for (int jt = 0; jt < 4; jt++) {
                int row = cw + jt * 16 + ml;
                int slot = (kk * 4 + q) ^ (row & 7);
                short8 bv = *(const short8*)(&Vv[row * 64 + slot * 8]);
                #pragma unroll
                for (int pst = 0; pst < 4; pst++)
                    pv[pst][jt] = __builtin_amdgcn_mfma_f32_16x16x32_bf16(
                        ap[pst], bv, pv[pst][jt], 0, 0, 0);
            }
        }
    }
    // cs partial: reduce over 16 m-lanes, one PLAIN store per (z, p-row)
    #pragma unroll
    for (int r = 0; r < 4; r++) {
        float s = csr[r];
        s += __shfl_xor(s, 1); s += __shfl_xor(s, 2);
        s += __shfl_xor(s, 4); s += __shfl_xor(s, 8);
        if (ml == 0) csp[(long long)z * NPTS + p0 + pw + q * 4 + r] = s;
    }
    // store PV partials (plain f32)
    float* C = part + (long long)z * ((long long)NPTS * 256);
    #pragma unroll
    for (int pst = 0; pst < 4; pst++)
        #pragma unroll
        for (int jt = 0; jt < 4; jt++)
            #pragma unroll
            for (int r = 0; r < 4; r++) {
                int rg = p0 + pst * 16 + q * 4 + r;
                int cg = cw + jt * 16 + ml;
                C[(long long)rg * 256 + cg] = pv[pst][jt][r];
            }
}

// ---------------- small kernels ----------------
__global__ __launch_bounds__(256)
void conv1_k(const float* __restrict__ x, const float* __restrict__ w,
             const float* __restrict__ g, const float* __restrict__ bb,
             unsigned short* __restrict__ h, long long h_po)
{
    int b = blockIdx.y;
    int p = blockIdx.x * 4 + (threadIdx.x >> 6);
    int c = threadIdx.x & 63;
    const float* xp = x + ((long long)b * NPTS + p) * 3;
    float y = xp[0] * w[c * 3] + xp[1] * w[c * 3 + 1] + xp[2] * w[c * 3 + 2];
    y = y * (INV_STD * g[c]) + bb[c];
    y = fmaxf(y, 0.f);
    long long i = ((long long)b * NPTS + p) * 64 + c;
    unsigned short hi = f2bf(y);
    h[i] = hi;
    h[h_po + i] = f2bf(y - bf2f(hi));
}

__global__ __launch_bounds__(256)
void zero_k(float* __restrict__ p, int n)
{
    int i = blockIdx.x * 256 + threadIdx.x;
    if (i < n) p[i] = 0.f;
}

// d = x - (sum_ms part)/(1e-9 + sum_ms csp); point-major, 256 channels
__global__ __launch_bounds__(256)
void diff_k(const unsigned short* __restrict__ xin, long long x_bs, int x_ld, long long x_po,
            const float* __restrict__ part, const float* __restrict__ csp,
            unsigned short* __restrict__ d, long long d_po)
{
    long long i = (long long)blockIdx.x * 256 + threadIdx.x;  // over NPTS*256
    int b = blockIdx.y;
    int p = (int)(i >> 8), c = (int)(i & 255);
    long long xi = (long long)b * x_bs + (long long)p * x_ld + c;
    float xv = bf2f(xin[xi]) + bf2f(xin[x_po + xi]);
    float xr = 0.f, den = 1e-9f;
    #pragma unroll
    for (int ks = 0; ks < MSPLIT; ks++) {
        int z = b * MSPLIT + ks;
        xr  += part[(long long)z * ((long long)NPTS * 256) + i];
        den += csp[(long long)z * NPTS + p];
    }
    float v = xv - xr / den;
    long long di = (long long)b * NPTS * 256 + i;
    unsigned short hi = f2bf(v);
    d[di] = hi;
    d[d_po + di] = f2bf(v - bf2f(hi));
}

__global__ __launch_bounds__(256)
void gmaxp_k(const unsigned short* __restrict__ face, long long f_po, float* __restrict__ pm)
{
    int c = blockIdx.x * 256 + threadIdx.x;   // 0..511
    int ch = blockIdx.y;                      // 16 point-chunks
    int b = blockIdx.z;
    float m = -3.4e38f;
    for (int j = 0; j < 256; j++) {
        long long i = ((long long)b * NPTS + ch * 256 + j) * 512 + c;
        m = fmaxf(m, bf2f(face[i]) + bf2f(face[f_po + i]));
    }
    pm[((long long)b * 16 + ch) * 512 + c] = m;
}

__global__ __launch_bounds__(256)
void gmaxr_k(const float* __restrict__ pm, float* __restrict__ gm)
{
    int idx = blockIdx.x * 256 + threadIdx.x;  // over BATCH*512
    int b = idx >> 9, c = idx & 511;
    float m = -3.4e38f;
    for (int ch = 0; ch < 16; ch++)
        m = fmaxf(m, pm[((long long)b * 16 + ch) * 512 + c]);
    gm[idx] = m;
}

__global__ __launch_bounds__(256)
void bias2_k(const float* __restrict__ w, const float* __restrict__ g, float* __restrict__ b2)
{
    int o = blockIdx.x * 256 + threadIdx.x;
    int b = blockIdx.y;
    if (o >= 512) return;
    float s = 0.f;
    for (int c = 0; c < 512; c++) s += w[(long long)o * 1024 + 512 + c] * g[b * 512 + c];
    b2[b * 512 + o] = s;
}

extern "C" void kernel_launch(void* const* d_in, const int* in_sizes, int n_in,
                              void* d_out, int out_size, void* d_ws, size_t ws_size,
                              hipStream_t stream)
{
    const float* x       = (const float*)d_in[0];
    const float* conv1_w = (const float*)d_in[1];
    const float* bn1_g   = (const float*)d_in[2];
    const float* bn1_b   = (const float*)d_in[3];
    const float* conv2_w = (const float*)d_in[4];
    const float* bn2_g   = (const float*)d_in[5];
    const float* bn2_b   = (const float*)d_in[6];
    const float* conv3_w = (const float*)d_in[7];
    const float* bn3_g   = (const float*)d_in[8];
    const float* bn3_b   = (const float*)d_in[9];
    const float* pt1_w   = (const float*)d_in[10];
    const float* pt1_g   = (const float*)d_in[11];
    const float* pt1_b   = (const float*)d_in[12];
    const float* pt2_w   = (const float*)d_in[13];
    const float* pt2_g   = (const float*)d_in[14];
    const float* pt2_b   = (const float*)d_in[15];
    const float* sa_qk[2] = {(const float*)d_in[16], (const float*)d_in[23]};
    const float* sa_vw[2] = {(const float*)d_in[17], (const float*)d_in[24]};
    const float* sa_vb[2] = {(const float*)d_in[18], (const float*)d_in[25]};
    const float* sa_tw[2] = {(const float*)d_in[19], (const float*)d_in[26]};
    const float* sa_tb[2] = {(const float*)d_in[20], (const float*)d_in[27]};
    const float* sa_g[2]  = {(const float*)d_in[21], (const float*)d_in[28]};
    const float* sa_b[2]  = {(const float*)d_in[22], (const float*)d_in[29]};
    const float* cf_w = (const float*)d_in[30];
    const float* cf_g = (const float*)d_in[31];
    const float* cf_b = (const float*)d_in[32];
    const float* s1_w = (const float*)d_in[33];
    const float* s1_g = (const float*)d_in[34];
    const float* s1_b = (const float*)d_in[35];
    const float* s2_w = (const float*)d_in[36];
    const float* s2_g = (const float*)d_in[37];
    const float* s2_b = (const float*)d_in[38];
    const float* s3_w = (const float*)d_in[39];

    char* base = (char*)d_ws;
    size_t off = 0;
    auto alloc = [&](size_t bytes) -> void* {
        void* p = base + off;
        off = (off + bytes + 255) & ~(size_t)255;
        return p;
    };
    const long long N = NPTS;
    const long long PO64   = (long long)BATCH * N * 64;
    const long long PO128  = (long long)BATCH * N * 128;
    const long long PO256  = (long long)BATCH * N * 256;
    const long long PO512  = (long long)BATCH * N * 512;
    const long long PO1024 = (long long)BATCH * N * 1024;

    unsigned short* S1  = (unsigned short*)alloc(2 * PO256 * 2);
    unsigned short* S2  = (unsigned short*)alloc(2 * PO256 * 2);
    unsigned short* Dv  = (unsigned short*)alloc(2 * PO256 * 2);
    unsigned short* cat = (unsigned short*)alloc(2 * PO1024 * 2);
    unsigned short* face = (unsigned short*)alloc(2 * PO512 * 2);
    unsigned short* xq  = (unsigned short*)alloc((size_t)BATCH * N * 128 * 2);
    unsigned short* xv  = (unsigned short*)alloc((size_t)BATCH * 256 * N * 2);
    unsigned short* s1b = (unsigned short*)alloc(2 * PO512 * 2);
    unsigned short* s2b = (unsigned short*)alloc(2 * PO256 * 2);
    float* part = (float*)alloc((size_t)BATCH * MSPLIT * N * 256 * 4);          // 32 MB
    float* csp  = (float*)alloc((size_t)BATCH * MSPLIT * N * 4);
    float* rs = (float*)alloc((size_t)BATCH * N * 4);
    float* pm = (float*)alloc((size_t)BATCH * 16 * 512 * 4);
    float* gm = (float*)alloc((size_t)BATCH * 512 * 4);
    float* b2 = (float*)alloc((size_t)BATCH * 512 * 4);
    unsigned short* wb = (unsigned short*)alloc((size_t)3400000 * 2);  // pre-split weights

    // ---- weight pre-split table ----
    WSplit wd;
    const float* wsrc[14] = {conv2_w, conv3_w, pt1_w, pt2_w, sa_qk[0], sa_qk[1],
                             sa_vw[0], sa_vw[1], sa_tw[0], sa_tw[1], cf_w, s1_w, s2_w, s3_w};
    int wn[14] = {128*64, 256*128, 256*256, 256*256, 128*256, 128*256,
                  256*256, 256*256, 256*256, 256*256, 512*1024, 512*1024, 256*512, 50*256};
    long long wo[14]; long long acc_ = 0;
    for (int i = 0; i < 14; i++) { wd.src[i] = wsrc[i]; wd.n[i] = wn[i]; wd.off[i] = acc_; wo[i] = acc_; acc_ += 2LL * wn[i]; }
    presplit_k<<<dim3((512*1024 + 255) / 256, 14), 256, 0, stream>>>(wd, wb);
    auto W = [&](int i) { return wb + wo[i]; };

    auto nt = [&](const unsigned short* A, long long a_bs, int a_lda, long long a_po,
                  const unsigned short* B, long long b_bs, int b_lda, long long b_po,
                  void* C, long long c_bs, int c_ld, long long c_po,
                  int Mrows, int Nb, int K,
                  const float* bias, int bias_mode,
                  const float* bng, const float* bnb,
                  const unsigned short* res, long long res_bs, int res_ld, long long res_po,
                  int act, int out_mode) {
        dim3 g((Nb + 63) / 64, Mrows / 64, BATCH);
        gemm_nt_split<<<g, 256, 0, stream>>>(A, a_bs, a_lda, a_po, B, b_bs, b_lda, b_po,
                                             C, c_bs, c_ld, c_po, Nb, K,
                                             bias, bias_mode, bng, bnb,
                                             res, res_bs, res_ld, res_po, act, out_mode);
    };
    auto ntB = [&](const unsigned short* A, long long a_bs, int a_lda, long long a_po,
                   const unsigned short* B, long long b_bs, int b_lda, long long b_po,
                   void* C, long long c_bs, int c_ld, long long c_po,
                   int Mrows, int Nb, int K,
                   const float* bias, int bias_mode,
                   const float* bng, const float* bnb,
                   const unsigned short* res, long long res_bs, int res_ld, long long res_po,
                   int act, int out_mode) {
        dim3 g((Nb + 63) / 64, Mrows / 64, BATCH);
        gemm_nt_splitB<<<g, 256, 0, stream>>>(A, a_bs, a_lda, a_po, B, b_bs, b_lda, b_po,
                                              C, c_bs, c_ld, c_po, Nb, K,
                                              bias, bias_mode, bng, bnb,
                                              res, res_bs, res_ld, res_po, act, out_mode);
    };

    // ---- stem ----
    conv1_k<<<dim3(NPTS / 4, BATCH), 256, 0, stream>>>(x, conv1_w, bn1_g, bn1_b, S1, PO64);
    nt(S1, N * 64, 64, PO64,    W(0), 0, 64, wn[0],  S2, N * 128, 128, PO128,
       NPTS, 128, 64,  nullptr, 0, bn2_g, bn2_b, nullptr, 0, 0, 0, 1, 0);
    ntB(S2, N * 128, 128, PO128, W(1), 0, 128, wn[1], S1, N * 256, 256, PO256,
        NPTS, 256, 128, nullptr, 0, bn3_g, bn3_b, nullptr, 0, 0, 0, 1, 0);
    ntB(S1, N * 256, 256, PO256, W(2), 0, 256, wn[2], S2, N * 256, 256, PO256,
        NPTS, 256, 256, nullptr, 0, pt1_g, pt1_b, nullptr, 0, 0, 0, 1, 0);
    ntB(S2, N * 256, 256, PO256, W(3), 0, 256, wn[3], S1, N * 256, 256, PO256,
        NPTS, 256, 256, nullptr, 0, pt2_g, pt2_b, nullptr, 0, 0, 0, 1, 0);

    // ---- 4 SA layers ----
    for (int i = 0; i < 4; i++) {
        int p = (i == 0) ? 0 : 1;
        const unsigned short* xin = (i == 0) ? S1 : cat + (size_t)(i - 1) * 256;
        long long xin_bs = (i == 0) ? N * 256 : N * 1024;
        int xin_ld = (i == 0) ? 256 : 1024;
        long long xin_po = (i == 0) ? PO256 : PO1024;

        // xq[n][128] plain bf16 (K=256)
        ntB(xin, xin_bs, xin_ld, xin_po, W(4 + p), 0, 256, wn[4 + p],
            xq, N * 128, 128, 0, NPTS, 128, 256,
            nullptr, 0, nullptr, nullptr, nullptr, 0, 0, 0, 0, 1);
        // xv[c][n] plain bf16 (A = weights, K=256)
        ntB(W(6 + p), 0, 256, wn[6 + p], xin, xin_bs, xin_ld, xin_po,
            xv, 256 * N, NPTS, 0, 256, NPTS, 256,
            sa_vb[p], 3, nullptr, nullptr, nullptr, 0, 0, 0, 0, 1);
        // zero rs (needed for rs_k atomics)
        zero_k<<<(BATCH * NPTS + 255) / 256, 256, 0, stream>>>(rs, BATCH * NPTS);
        // E1: rs row-sums (no att store)
        rs_k<<<dim3(RSSPLIT, NPTS / 64, BATCH), 256, 0, stream>>>(xq, rs);
        // E2: fused QK->exp/rs->PV partials + cs partials
        attn_pv<<<dim3(1, NPTS / 64, BATCH * MSPLIT), 256, 0, stream>>>(
            xq, xv, rs, part, csp);
        // d = x - (sum partials)/(1e-9 + sum cs partials)
        diff_k<<<dim3(NPTS * 256 / 256, BATCH), 256, 0, stream>>>(
            xin, xin_bs, xin_ld, xin_po, part, csp, Dv, PO256);
        // x_out = x + relu(bn(tw@d + tb)) -> cat slice i (K=256)
        ntB(Dv, N * 256, 256, PO256, W(8 + p), 0, 256, wn[8 + p],
            cat + (size_t)i * 256, N * 1024, 1024, PO1024,
            NPTS, 256, 256, sa_tb[p], 1, sa_g[p], sa_b[p],
            xin, xin_bs, xin_ld, xin_po, 1, 0);
    }

    // ---- head ----
    nt(cat, N * 1024, 1024, PO1024, W(10), 0, 1024, wn[10],
       face, N * 512, 512, PO512, NPTS, 512, 1024,
       nullptr, 0, cf_g, cf_b, nullptr, 0, 0, 0, 2, 0);
    gmaxp_k<<<dim3(2, 16, BATCH), 256, 0, stream>>>(face, PO512, pm);
    gmaxr_k<<<dim3(BATCH * 512 / 256), 256, 0, stream>>>(pm, gm);
    bias2_k<<<dim3(2, BATCH), 256, 0, stream>>>(s1_w, gm, b2);
    nt(face, N * 512, 512, PO512, W(11), 0, 1024, wn[11],
       s1b, N * 512, 512, PO512, NPTS, 512, 512,
       b2, 2, s1_g, s1_b, nullptr, 0, 0, 0, 2, 0);
    ntB(s1b, N * 512, 512, PO512, W(12), 0, 512, wn[12],
        s2b, N * 256, 256, PO256, NPTS, 256, 512,
        nullptr, 0, s2_g, s2_b, nullptr, 0, 0, 0, 2, 0);
    ntB(s2b, N * 256, 256, PO256, W(13), 0, 256, wn[13],
        d_out, N * 50, 50, 0, NPTS, 50, 256,
        nullptr, 0, nullptr, nullptr, nullptr, 0, 0, 0, 0, 2);
}

// Round 6
// 740.261 us; speedup vs baseline: 1.4279x; 1.0169x over previous
//
#include <hip/hip_runtime.h>
#include <hip/hip_bf16.h>

// PCT segmentation forward. R23 = R22 (752.8us: XCD swizzle everywhere) +
// three bit-exact local upgrades:
// - K3 (gemm_nt_split3): 128x64 tile, BK=64, 48KB LDS, wave=64x32 out
//   (acc 4x2). 24 MFMA / 12 ds_read per wave-K-step (2:1) flips the per-CU
//   balance MFMA-bound (K1 at 4 blk/CU is LDS-read-bound: 3072 read-cyc vs
//   1920 MFMA-cyc). Routed ONLY cf + s1 (N>=512 keeps grid 512 = 2/CU).
//   N=256 shapes stay K1B (128-tile grids would be 256 blocks = 1/CU, the
//   R21 failure).
// - gmaxp_k: wave-per-row short8 loads (16B/lane, was 2B/lane scalar),
//   128 blocks (was 32), LDS cross-wave max; pm now [B][64][512]. Exact.
// - diff_k: float4/short4 vectorized, same per-element op order. Exact.
// attn_pv untouched: R22 proved it fetch-insensitive (FETCH 25->6.2MB,
// dur 50.5->50.0); it is barrier/latency-bound at the 2 blk/CU grid cap.

#define NPTS 4096
#define BATCH 2
#define MSPLIT 4
#define RSSPLIT 8
static constexpr float INV_STD = 0.9999950000374997f;  // 1/sqrt(1+1e-5)

__device__ __forceinline__ float bf2f(unsigned short u) {
    return __uint_as_float(((unsigned int)u) << 16);
}
__device__ __forceinline__ unsigned short f2bf(float f) {
    unsigned int x = __float_as_uint(f);
    unsigned int r = (x + 0x7FFFu + ((x >> 16) & 1u)) >> 16;
    return (unsigned short)r;
}

// async global->LDS 16B DMA: LDS base wave-uniform; HW writes lptr+lane*16.
__device__ __forceinline__ void async16(const unsigned short* g, unsigned short* l)
{
    __builtin_amdgcn_global_load_lds(
        (const __attribute__((address_space(1))) unsigned int*)(const void*)g,
        (__attribute__((address_space(3))) unsigned int*)(void*)l,
        16, 0, 0);
}

typedef __attribute__((ext_vector_type(8))) short short8;
typedef __attribute__((ext_vector_type(4))) short s16x4;
typedef __attribute__((ext_vector_type(4))) float f32x4;

// ---------------- weight pre-split ----------------
struct WSplit {
    const float* src[14];
    int n[14];
    long long off[14];   // ushort offset of hi plane; lo at off+n
};

__global__ __launch_bounds__(256)
void presplit_k(WSplit d, unsigned short* __restrict__ wbuf)
{
    int wi = blockIdx.y;
    int i = blockIdx.x * 256 + threadIdx.x;
    int n = d.n[wi];
    if (i >= n) return;
    float v = d.src[wi][i];
    unsigned short h = f2bf(v);
    unsigned short* dst = wbuf + d.off[wi];
    dst[i] = h;
    dst[n + i] = f2bf(v - bf2f(h));
}

// shared epilogue
__device__ __forceinline__ void nt_epilogue(
    float y, int rg, int cg, int b, int Nb,
    const float* bias, int bias_mode,
    const float* bng, const float* bnb,
    const unsigned short* res, long long res_bs, int res_ld, long long res_po,
    int act, int out_mode,
    void* Cp, long long c_bs, int c_ld, long long c_po)
{
    if (bias) {
        if (bias_mode == 3)      y += bias[rg];
        else if (bias_mode == 2) y += bias[b * Nb + cg];
        else                     y += bias[cg];
    }
    if (bng) y = y * (INV_STD * bng[cg]) + bnb[cg];
    if (act == 1) y = fmaxf(y, 0.f);
    else if (act == 2) y = (y > 0.f) ? y : 0.2f * y;
    if (res) {
        long long ri_ = (long long)b * res_bs + (long long)rg * res_ld + cg;
        y += bf2f(res[ri_]) + bf2f(res[res_po + ri_]);
    }
    long long ci = (long long)b * c_bs + (long long)rg * c_ld + cg;
    if (out_mode == 0) {
        unsigned short* C = (unsigned short*)Cp;
        unsigned short h = f2bf(y);
        C[ci] = h;
        C[c_po + ci] = f2bf(y - bf2f(h));
    } else if (out_mode == 1) {
        ((unsigned short*)Cp)[ci] = f2bf(y);
    } else {
        if (cg < Nb) ((float*)Cp)[ci] = y;
    }
}

// ---------------- K1: split-bf16 NT GEMM, 64x64 tile, BK=64 ----------------
__global__ __launch_bounds__(256)
void gemm_nt_split(const unsigned short* __restrict__ A, long long a_bs, int a_lda, long long a_po,
                   const unsigned short* __restrict__ B, long long b_bs, int b_lda, long long b_po,
                   void* __restrict__ Cp, long long c_bs, int c_ld, long long c_po,
                   int Nb, int K,
                   const float* __restrict__ bias, int bias_mode,
                   const float* __restrict__ bng, const float* __restrict__ bnb,
                   const unsigned short* __restrict__ res, long long res_bs, int res_ld, long long res_po,
                   int act, int out_mode)
{
    __shared__ unsigned short As[2][64 * 64];
    __shared__ unsigned short Bs[2][64 * 64];
    const int gx = gridDim.x, gy = gridDim.y;
    const int nblk = gx * gy * (int)gridDim.z;
    int d_ = blockIdx.x + gx * (blockIdx.y + gy * blockIdx.z);
    int w_ = (nblk & 7) ? d_ : ((d_ & 7) * (nblk >> 3) + (d_ >> 3));
    const int b = w_ / (gx * gy);
    const int rem_ = w_ % (gx * gy);
    const int m0 = (rem_ / gx) * 64, n0 = (rem_ % gx) * 64;
    const int t = threadIdx.x;
    const int lane = t & 63, w = t >> 6;
    const int wr = (w >> 1) * 32, wc = (w & 1) * 32;
    const int ml = lane & 15, q = lane >> 4;

    f32x4 acc[2][2] = {};

    for (int k0 = 0; k0 < K; k0 += 64) {
        __syncthreads();
        #pragma unroll
        for (int e = 0; e < 2; e++) {
            int idx = t + e * 256;
            int row = idx >> 3, blk = idx & 7;
            int gblk = blk ^ (row & 7);
            int lofs = (e * 256 + (t & 192)) * 8;
            const unsigned short* sA = A + (long long)b * a_bs
                                     + (long long)(m0 + row) * a_lda + k0 + gblk * 8;
            const unsigned short* sB = B + (long long)b * b_bs
                                     + (long long)(n0 + row) * b_lda + k0 + gblk * 8;
            async16(sA,        &As[0][0] + lofs);
            async16(sA + a_po, &As[1][0] + lofs);
            async16(sB,        &Bs[0][0] + lofs);
            async16(sB + b_po, &Bs[1][0] + lofs);
        }
        __syncthreads();
        #pragma unroll
        for (int kk = 0; kk < 2; kk++) {
            short8 ah[2], al[2], bh[2], bl[2];
            #pragma unroll
            for (int it = 0; it < 2; it++) {
                int row = wr + it * 16 + ml;
                int slot = (kk * 4 + q) ^ (row & 7);
                ah[it] = *(const short8*)(&As[0][row * 64 + slot * 8]);
                al[it] = *(const short8*)(&As[1][row * 64 + slot * 8]);
            }
            #pragma unroll
            for (int jt = 0; jt < 2; jt++) {
                int row = wc + jt * 16 + ml;
                int slot = (kk * 4 + q) ^ (row & 7);
                bh[jt] = *(const short8*)(&Bs[0][row * 64 + slot * 8]);
                bl[jt] = *(const short8*)(&Bs[1][row * 64 + slot * 8]);
            }
            #pragma unroll
            for (int it = 0; it < 2; it++)
                #pragma unroll
                for (int jt = 0; jt < 2; jt++) {
                    acc[it][jt] = __builtin_amdgcn_mfma_f32_16x16x32_bf16(ah[it], bh[jt], acc[it][jt], 0, 0, 0);
                    acc[it][jt] = __builtin_amdgcn_mfma_f32_16x16x32_bf16(ah[it], bl[jt], acc[it][jt], 0, 0, 0);
                    acc[it][jt] = __builtin_amdgcn_mfma_f32_16x16x32_bf16(al[it], bh[jt], acc[it][jt], 0, 0, 0);
                }
        }
    }

    #pragma unroll
    for (int it = 0; it < 2; it++)
        #pragma unroll
        for (int jt = 0; jt < 2; jt++)
            #pragma unroll
            for (int r = 0; r < 4; r++)
                nt_epilogue(acc[it][jt][r], m0 + wr + it * 16 + q * 4 + r,
                            n0 + wc + jt * 16 + ml, b, Nb,
                            bias, bias_mode, bng, bnb, res, res_bs, res_ld, res_po,
                            act, out_mode, Cp, c_bs, c_ld, c_po);
}

// ---------------- K1B: split-bf16 NT GEMM, 64x64 tile, BK=128 ----------------
__global__ __launch_bounds__(256)
void gemm_nt_splitB(const unsigned short* __restrict__ A, long long a_bs, int a_lda, long long a_po,
                    const unsigned short* __restrict__ B, long long b_bs, int b_lda, long long b_po,
                    void* __restrict__ Cp, long long c_bs, int c_ld, long long c_po,
                    int Nb, int K,
                    const float* __restrict__ bias, int bias_mode,
                    const float* __restrict__ bng, const float* __restrict__ bnb,
                    const unsigned short* __restrict__ res, long long res_bs, int res_ld, long long res_po,
                    int act, int out_mode)
{
    __shared__ unsigned short As[2][2][64 * 64];   // [plane][sub] 32 KB
    __shared__ unsigned short Bs[2][2][64 * 64];   // 32 KB
    const int gx = gridDim.x, gy = gridDim.y;
    const int nblk = gx * gy * (int)gridDim.z;
    int d_ = blockIdx.x + gx * (blockIdx.y + gy * blockIdx.z);
    int w_ = (nblk & 7) ? d_ : ((d_ & 7) * (nblk >> 3) + (d_ >> 3));
    const int b = w_ / (gx * gy);
    const int rem_ = w_ % (gx * gy);
    const int m0 = (rem_ / gx) * 64, n0 = (rem_ % gx) * 64;
    const int t = threadIdx.x;
    const int lane = t & 63, w = t >> 6;
    const int wr = (w >> 1) * 32, wc = (w & 1) * 32;
    const int ml = lane & 15, q = lane >> 4;

    f32x4 acc[2][2] = {};

    for (int k0 = 0; k0 < K; k0 += 128) {
        __syncthreads();
        #pragma unroll
        for (int sub = 0; sub < 2; sub++) {
            int kb = k0 + sub * 64;
            #pragma unroll
            for (int e = 0; e < 2; e++) {
                int idx = t + e * 256;
                int row = idx >> 3, blk = idx & 7;
                int gblk = blk ^ (row & 7);
                int lofs = (e * 256 + (t & 192)) * 8;
                const unsigned short* sA = A + (long long)b * a_bs
                                         + (long long)(m0 + row) * a_lda + kb + gblk * 8;
                const unsigned short* sB = B + (long long)b * b_bs
                                         + (long long)(n0 + row) * b_lda + kb + gblk * 8;
                async16(sA,        &As[0][sub][0] + lofs);
                async16(sA + a_po, &As[1][sub][0] + lofs);
                async16(sB,        &Bs[0][sub][0] + lofs);
                async16(sB + b_po, &Bs[1][sub][0] + lofs);
            }
        }
        __syncthreads();
        #pragma unroll
        for (int sub = 0; sub < 2; sub++)
            #pragma unroll
            for (int kk = 0; kk < 2; kk++) {
                short8 ah[2], al[2], bh[2], bl[2];
                #pragma unroll
                for (int it = 0; it < 2; it++) {
                    int row = wr + it * 16 + ml;
                    int slot = (kk * 4 + q) ^ (row & 7);
                    ah[it] = *(const short8*)(&As[0][sub][row * 64 + slot * 8]);
                    al[it] = *(const short8*)(&As[1][sub][row * 64 + slot * 8]);
                }
                #pragma unroll
                for (int jt = 0; jt < 2; jt++) {
                    int row = wc + jt * 16 + ml;
                    int slot = (kk * 4 + q) ^ (row & 7);
                    bh[jt] = *(const short8*)(&Bs[0][sub][row * 64 + slot * 8]);
                    bl[jt] = *(const short8*)(&Bs[1][sub][row * 64 + slot * 8]);
                }
                #pragma unroll
                for (int it = 0; it < 2; it++)
                    #pragma unroll
                    for (int jt = 0; jt < 2; jt++) {
                        acc[it][jt] = __builtin_amdgcn_mfma_f32_16x16x32_bf16(ah[it], bh[jt], acc[it][jt], 0, 0, 0);
                        acc[it][jt] = __builtin_amdgcn_mfma_f32_16x16x32_bf16(ah[it], bl[jt], acc[it][jt], 0, 0, 0);
                        acc[it][jt] = __builtin_amdgcn_mfma_f32_16x16x32_bf16(al[it], bh[jt], acc[it][jt], 0, 0, 0);
                    }
            }
    }

    #pragma unroll
    for (int it = 0; it < 2; it++)
        #pragma unroll
        for (int jt = 0; jt < 2; jt++)
            #pragma unroll
            for (int r = 0; r < 4; r++)
                nt_epilogue(acc[it][jt][r], m0 + wr + it * 16 + q * 4 + r,
                            n0 + wc + jt * 16 + ml, b, Nb,
                            bias, bias_mode, bng, bnb, res, res_bs, res_ld, res_po,
                            act, out_mode, Cp, c_bs, c_ld, c_po);
}

// ---------------- K3: split-bf16 NT GEMM, 128x64 tile, BK=64 ----------------
// 4 waves in 2Mx2N, each 64x32 out (acc 4x2). 24 MFMA / 12 ds_read per
// wave-K-step. 48 KB LDS. Routed only where grid stays >= 512 (N>=512).
__global__ __launch_bounds__(256)
void gemm_nt_split3(const unsigned short* __restrict__ A, long long a_bs, int a_lda, long long a_po,
                    const unsigned short* __restrict__ B, long long b_bs, int b_lda, long long b_po,
                    void* __restrict__ Cp, long long c_bs, int c_ld, long long c_po,
                    int Nb, int K,
                    const float* __restrict__ bias, int bias_mode,
                    const float* __restrict__ bng, const float* __restrict__ bnb,
                    const unsigned short* __restrict__ res, long long res_bs, int res_ld, long long res_po,
                    int act, int out_mode)
{
    __shared__ unsigned short As[2][128 * 64];   // 32 KB (hi+lo)
    __shared__ unsigned short Bs[2][64 * 64];    // 16 KB
    const int gx = gridDim.x, gy = gridDim.y;
    const int nblk = gx * gy * (int)gridDim.z;
    int d_ = blockIdx.x + gx * (blockIdx.y + gy * blockIdx.z);
    int w_ = (nblk & 7) ? d_ : ((d_ & 7) * (nblk >> 3) + (d_ >> 3));
    const int b = w_ / (gx * gy);
    const int rem_ = w_ % (gx * gy);
    const int m0 = (rem_ / gx) * 128, n0 = (rem_ % gx) * 64;
    const int t = threadIdx.x;
    const int lane = t & 63, w = t >> 6;
    const int wr = (w >> 1) * 64, wc = (w & 1) * 32;
    const int ml = lane & 15, q = lane >> 4;

    f32x4 acc[4][2] = {};

    for (int k0 = 0; k0 < K; k0 += 64) {
        __syncthreads();
        #pragma unroll
        for (int e = 0; e < 4; e++) {            // A: 128 rows
            int idx = t + e * 256;
            int row = idx >> 3, blk = idx & 7;
            int gblk = blk ^ (row & 7);
            int lofs = (e * 256 + (t & 192)) * 8;
            const unsigned short* sA = A + (long long)b * a_bs
                                     + (long long)(m0 + row) * a_lda + k0 + gblk * 8;
            async16(sA,        &As[0][0] + lofs);
            async16(sA + a_po, &As[1][0] + lofs);
        }
        #pragma unroll
        for (int e = 0; e < 2; e++) {            // B: 64 rows
            int idx = t + e * 256;
            int row = idx >> 3, blk = idx & 7;
            int gblk = blk ^ (row & 7);
            int lofs = (e * 256 + (t & 192)) * 8;
            const unsigned short* sB = B + (long long)b * b_bs
                                     + (long long)(n0 + row) * b_lda + k0 + gblk * 8;
            async16(sB,        &Bs[0][0] + lofs);
            async16(sB + b_po, &Bs[1][0] + lofs);
        }
        __syncthreads();
        #pragma unroll
        for (int kk = 0; kk < 2; kk++) {
            short8 ah[4], al[4], bh[2], bl[2];
            #pragma unroll
            for (int it = 0; it < 4; it++) {
                int row = wr + it * 16 + ml;
                int slot = (kk * 4 + q) ^ (row & 7);
                ah[it] = *(const short8*)(&As[0][row * 64 + slot * 8]);
                al[it] = *(const short8*)(&As[1][row * 64 + slot * 8]);
            }
            #pragma unroll
            for (int jt = 0; jt < 2; jt++) {
                int row = wc + jt * 16 + ml;
                int slot = (kk * 4 + q) ^ (row & 7);
                bh[jt] = *(const short8*)(&Bs[0][row * 64 + slot * 8]);
                bl[jt] = *(const short8*)(&Bs[1][row * 64 + slot * 8]);
            }
            #pragma unroll
            for (int it = 0; it < 4; it++)
                #pragma unroll
                for (int jt = 0; jt < 2; jt++) {
                    acc[it][jt] = __builtin_amdgcn_mfma_f32_16x16x32_bf16(ah[it], bh[jt], acc[it][jt], 0, 0, 0);
                    acc[it][jt] = __builtin_amdgcn_mfma_f32_16x16x32_bf16(ah[it], bl[jt], acc[it][jt], 0, 0, 0);
                    acc[it][jt] = __builtin_amdgcn_mfma_f32_16x16x32_bf16(al[it], bh[jt], acc[it][jt], 0, 0, 0);
                }
        }
    }

    #pragma unroll
    for (int it = 0; it < 4; it++)
        #pragma unroll
        for (int jt = 0; jt < 2; jt++)
            #pragma unroll
            for (int r = 0; r < 4; r++)
                nt_epilogue(acc[it][jt][r], m0 + wr + it * 16 + q * 4 + r,
                            n0 + wc + jt * 16 + ml, b, Nb,
                            bias, bias_mode, bng, bnb, res, res_bs, res_ld, res_po,
                            act, out_mode, Cp, c_bs, c_ld, c_po);
}

// ---------------- E1: rs[p] = sum_m exp(e[p][m]), atomic row-sums ----------------
__global__ __launch_bounds__(256)
void rs_k(const unsigned short* __restrict__ xq, float* __restrict__ rs)
{
    __shared__ unsigned short Kq[2][2][64 * 64];   // [dbuf][half] 32 KB
    int d_ = blockIdx.x + 8 * (blockIdx.y + 64 * blockIdx.z);
    int w_ = (d_ & 7) * 128 + (d_ >> 3);
    const int p0 = (w_ % 64) * 64;
    const int xseg = (w_ / 64) % 8;
    const int b = w_ / 512;
    const int m_beg = xseg * (NPTS / RSSPLIT);
    const unsigned short* xqB = xq + (long long)b * NPTS * 128;
    const int t = threadIdx.x;
    const int lane = t & 63, w = t >> 6;
    const int pw = w * 16;
    const int ml = lane & 15, q = lane >> 4;

    short8 af[4];
    #pragma unroll
    for (int ks = 0; ks < 4; ks++)
        af[ks] = *(const short8*)(xqB + (long long)(p0 + pw + ml) * 128 + ks * 32 + q * 8);

    float rsum[4] = {0.f, 0.f, 0.f, 0.f};

    auto stageK = [&](int m0, int buf) {
        #pragma unroll
        for (int e = 0; e < 4; e++) {
            int idx = t + e * 256;
            int sub = idx >> 9, row = (idx >> 3) & 63, blk = idx & 7;
            int gblk = blk ^ (row & 7);
            int lofs = (e * 256 + (t & 192)) * 8;
            async16(xqB + (long long)(m0 + row) * 128 + sub * 64 + gblk * 8,
                    &Kq[buf][0][0] + lofs);
        }
    };

    constexpr int NIT = (NPTS / RSSPLIT) / 64;
    stageK(m_beg, 0);
    __syncthreads();

    for (int it = 0; it < NIT; ++it) {
        const int m0 = m_beg + it * 64;
        const int cur = it & 1;
        if (it + 1 < NIT) stageK(m0 + 64, cur ^ 1);
        f32x4 acc[4] = {};
        #pragma unroll
        for (int ks = 0; ks < 4; ks++) {
            int kh = ks >> 1, kk = ks & 1;
            #pragma unroll
            for (int jt = 0; jt < 4; jt++) {
                int row = jt * 16 + ml;
                int slot = (kk * 4 + q) ^ (row & 7);
                short8 bf = *(const short8*)(&Kq[cur][kh][row * 64 + slot * 8]);
                acc[jt] = __builtin_amdgcn_mfma_f32_16x16x32_bf16(af[ks], bf, acc[jt], 0, 0, 0);
            }
        }
        #pragma unroll
        for (int jt = 0; jt < 4; jt++)
            #pragma unroll
            for (int r = 0; r < 4; r++)
                rsum[r] += __expf(acc[jt][r]);
        __syncthreads();   // drains next-iter staging; protects Kq[cur] overwrite
    }
    #pragma unroll
    for (int r = 0; r < 4; r++) {
        float s = rsum[r];
        s += __shfl_xor(s, 1); s += __shfl_xor(s, 2);
        s += __shfl_xor(s, 4); s += __shfl_xor(s, 8);
        if (ml == 0) atomicAdd(&rs[b * NPTS + p0 + pw + q * 4 + r], s);
    }
}

// ---------------- E2: QK -> exp/rs[m] -> PV partials + cs partials ----------------
__global__ __launch_bounds__(256)
void attn_pv(const unsigned short* __restrict__ xq,   // [B][N][128]
             const unsigned short* __restrict__ xv,   // [B][256][N]
             const float* __restrict__ rs,
             float* __restrict__ part,                // [B*MSPLIT][N][256]
             float* __restrict__ csp)                 // [B*MSPLIT][N]
{
    __shared__ unsigned short Kq[2][64 * 64];   // 16 KB
    __shared__ unsigned short Vv[256 * 64];     // 32 KB
    __shared__ unsigned short Pl[64][72];       // 9.2 KB
    int d_ = blockIdx.y + 64 * blockIdx.z;
    int w_ = (d_ & 7) * 64 + (d_ >> 3);
    const int p0 = (w_ % 64) * 64;
    const int z = w_ / 64;
    const int b = z / MSPLIT, ms = z % MSPLIT;
    const unsigned short* xqB = xq + (long long)b * NPTS * 128;
    const unsigned short* xvB = xv + (long long)b * 256 * NPTS;
    const float* rsB = rs + b * NPTS;
    const int t = threadIdx.x;
    const int lane = t & 63, w = t >> 6;
    const int pw = w * 16;                      // QK p-strip
    const int cw = w * 64;                      // PV c-strip
    const int ml = lane & 15, q = lane >> 4;

    short8 af[4];
    #pragma unroll
    for (int ks = 0; ks < 4; ks++)
        af[ks] = *(const short8*)(xqB + (long long)(p0 + pw + ml) * 128 + ks * 32 + q * 8);

    f32x4 pv[4][4] = {};                        // [p-tile][c-tile]
    float csr[4] = {0.f, 0.f, 0.f, 0.f};

    const int m_beg = ms * (NPTS / MSPLIT);
    for (int m0 = m_beg; m0 < m_beg + NPTS / MSPLIT; m0 += 64) {
        __syncthreads();
        #pragma unroll
        for (int e = 0; e < 4; e++) {
            int idx = t + e * 256;
            int sub = idx >> 9, row = (idx >> 3) & 63, blk = idx & 7;
            int gblk = blk ^ (row & 7);
            int lofs = (e * 256 + (t & 192)) * 8;
            async16(xqB + (long long)(m0 + row) * 128 + sub * 64 + gblk * 8,
                    &Kq[0][0] + lofs);
        }
        #pragma unroll
        for (int e = 0; e < 8; e++) {
            int idx = t + e * 256;
            int row = idx >> 3, blk = idx & 7;
            int gblk = blk ^ (row & 7);
            int lofs = (e * 256 + (t & 192)) * 8;
            async16(xvB + (long long)row * NPTS + m0 + gblk * 8, Vv + lofs);
        }
        __syncthreads();
        // QK: e[p64][m64]; this wave: p-strip pw (identical chain to rs_k)
        f32x4 acc[4] = {};
        #pragma unroll
        for (int ks = 0; ks < 4; ks++) {
            int kh = ks >> 1, kk = ks & 1;
            #pragma unroll
            for (int jt = 0; jt < 4; jt++) {
                int row = jt * 16 + ml;
                int slot = (kk * 4 + q) ^ (row & 7);
                short8 bf = *(const short8*)(&Kq[kh][row * 64 + slot * 8]);
                acc[jt] = __builtin_amdgcn_mfma_f32_16x16x32_bf16(af[ks], bf, acc[jt], 0, 0, 0);
            }
        }
        // P' = exp(e)/rs[m]
        #pragma unroll
        for (int jt = 0; jt < 4; jt++) {
            float rvm = 1.f / rsB[m0 + jt * 16 + ml];
            #pragma unroll
            for (int r = 0; r < 4; r++) {
                float pvv = __expf(acc[jt][r]) * rvm;
                csr[r] += pvv;
                Pl[pw + q * 4 + r][jt * 16 + ml] = f2bf(pvv);
            }
        }
        __syncthreads();
        // PV: this wave c-strip cw; A = P'[64p][64m] (shared), B = Vv rows
        #pragma unroll
        for (int kk = 0; kk < 2; kk++) {
            short8 ap[4];
            #pragma unroll
            for (int pst = 0; pst < 4; pst++)
                ap[pst] = *(const short8*)(&Pl[pst * 16 + ml][kk * 32 + q * 8]);
            #pragma unroll
            for (int jt = 0; jt < 4; jt++) {
                int row = cw + jt * 16 + ml;
                int slot = (kk * 4 + q) ^ (row & 7);
                short8 bv = *(const short8*)(&Vv[row * 64 + slot * 8]);
                #pragma unroll
                for (int pst = 0; pst < 4; pst++)
                    pv[pst][jt] = __builtin_amdgcn_mfma_f32_16x16x32_bf16(
                        ap[pst], bv, pv[pst][jt], 0, 0, 0);
            }
        }
    }
    // cs partial: reduce over 16 m-lanes, one PLAIN store per (z, p-row)
    #pragma unroll
    for (int r = 0; r < 4; r++) {
        float s = csr[r];
        s += __shfl_xor(s, 1); s += __shfl_xor(s, 2);
        s += __shfl_xor(s, 4); s += __shfl_xor(s, 8);
        if (ml == 0) csp[(long long)z * NPTS + p0 + pw + q * 4 + r] = s;
    }
    // store PV partials (plain f32)
    float* C = part + (long long)z * ((long long)NPTS * 256);
    #pragma unroll
    for (int pst = 0; pst < 4; pst++)
        #pragma unroll
        for (int jt = 0; jt < 4; jt++)
            #pragma unroll
            for (int r = 0; r < 4; r++) {
                int rg = p0 + pst * 16 + q * 4 + r;
                int cg = cw + jt * 16 + ml;
                C[(long long)rg * 256 + cg] = pv[pst][jt][r];
            }
}

// ---------------- small kernels ----------------
__global__ __launch_bounds__(256)
void conv1_k(const float* __restrict__ x, const float* __restrict__ w,
             const float* __restrict__ g, const float* __restrict__ bb,
             unsigned short* __restrict__ h, long long h_po)
{
    int b = blockIdx.y;
    int p = blockIdx.x * 4 + (threadIdx.x >> 6);
    int c = threadIdx.x & 63;
    const float* xp = x + ((long long)b * NPTS + p) * 3;
    float y = xp[0] * w[c * 3] + xp[1] * w[c * 3 + 1] + xp[2] * w[c * 3 + 2];
    y = y * (INV_STD * g[c]) + bb[c];
    y = fmaxf(y, 0.f);
    long long i = ((long long)b * NPTS + p) * 64 + c;
    unsigned short hi = f2bf(y);
    h[i] = hi;
    h[h_po + i] = f2bf(y - bf2f(hi));
}

__global__ __launch_bounds__(256)
void zero_k(float* __restrict__ p, int n)
{
    int i = blockIdx.x * 256 + threadIdx.x;
    if (i < n) p[i] = 0.f;
}

// d = x - (sum_ms part)/(1e-9 + sum_ms csp); vectorized x4, bit-identical ops
__global__ __launch_bounds__(256)
void diff_k(const unsigned short* __restrict__ xin, long long x_bs, int x_ld, long long x_po,
            const float* __restrict__ part, const float* __restrict__ csp,
            unsigned short* __restrict__ d, long long d_po)
{
    long long i4 = ((long long)blockIdx.x * 256 + threadIdx.x) * 4;  // over NPTS*256
    int b = blockIdx.y;
    int p = (int)(i4 >> 8), c = (int)(i4 & 255);
    long long xi = (long long)b * x_bs + (long long)p * x_ld + c;
    s16x4 xh = *(const s16x4*)(xin + xi);
    s16x4 xl = *(const s16x4*)(xin + x_po + xi);
    float xr0 = 0.f, xr1 = 0.f, xr2 = 0.f, xr3 = 0.f, den = 1e-9f;
    #pragma unroll
    for (int ks = 0; ks < MSPLIT; ks++) {
        int z = b * MSPLIT + ks;
        f32x4 pv = *(const f32x4*)(part + (long long)z * ((long long)NPTS * 256) + i4);
        xr0 += pv[0]; xr1 += pv[1]; xr2 += pv[2]; xr3 += pv[3];
        den += csp[(long long)z * NPTS + p];
    }
    float v0 = bf2f((unsigned short)xh[0]) + bf2f((unsigned short)xl[0]) - xr0 / den;
    float v1 = bf2f((unsigned short)xh[1]) + bf2f((unsigned short)xl[1]) - xr1 / den;
    float v2 = bf2f((unsigned short)xh[2]) + bf2f((unsigned short)xl[2]) - xr2 / den;
    float v3 = bf2f((unsigned short)xh[3]) + bf2f((unsigned short)xl[3]) - xr3 / den;
    long long di = (long long)b * NPTS * 256 + i4;
    s16x4 hh, ll;
    hh[0] = (short)f2bf(v0); ll[0] = (short)f2bf(v0 - bf2f((unsigned short)hh[0]));
    hh[1] = (short)f2bf(v1); ll[1] = (short)f2bf(v1 - bf2f((unsigned short)hh[1]));
    hh[2] = (short)f2bf(v2); ll[2] = (short)f2bf(v2 - bf2f((unsigned short)hh[2]));
    hh[3] = (short)f2bf(v3); ll[3] = (short)f2bf(v3 - bf2f((unsigned short)hh[3]));
    *(s16x4*)(d + di) = hh;
    *(s16x4*)(d + d_po + di) = ll;
}

// gmax stage 1: grid (4, 16, B), block = 256 = 4 waves; block covers 64
// points x all 512 channels. Wave reads one full row (short8/lane) per step.
__global__ __launch_bounds__(256)
void gmaxp_k(const unsigned short* __restrict__ face, long long f_po, float* __restrict__ pm)
{
    __shared__ float red[4][512];
    int b = blockIdx.z;
    int seg = blockIdx.y * 4 + blockIdx.x;    // 0..63, 64-point segment
    int w = threadIdx.x >> 6, l = threadIdx.x & 63;
    float m8[8];
    #pragma unroll
    for (int k = 0; k < 8; k++) m8[k] = -3.4e38f;
    for (int jj = 0; jj < 16; jj++) {
        int i = seg * 64 + jj * 4 + w;
        long long off = ((long long)b * NPTS + i) * 512 + l * 8;
        short8 h = *(const short8*)(face + off);
        short8 lo = *(const short8*)(face + f_po + off);
        #pragma unroll
        for (int k = 0; k < 8; k++)
            m8[k] = fmaxf(m8[k], bf2f((unsigned short)h[k]) + bf2f((unsigned short)lo[k]));
    }
    #pragma unroll
    for (int k = 0; k < 8; k++) red[w][l * 8 + k] = m8[k];
    __syncthreads();
    for (int c = threadIdx.x; c < 512; c += 256) {
        float m = fmaxf(fmaxf(red[0][c], red[1][c]), fmaxf(red[2][c], red[3][c]));
        pm[((long long)b * 64 + seg) * 512 + c] = m;
    }
}

__global__ __launch_bounds__(256)
void gmaxr_k(const float* __restrict__ pm, float* __restrict__ gm)
{
    int idx = blockIdx.x * 256 + threadIdx.x;  // over BATCH*512
    int b = idx >> 9, c = idx & 511;
    float m = -3.4e38f;
    for (int ch = 0; ch < 64; ch++)
        m = fmaxf(m, pm[((long long)b * 64 + ch) * 512 + c]);
    gm[idx] = m;
}

__global__ __launch_bounds__(256)
void bias2_k(const float* __restrict__ w, const float* __restrict__ g, float* __restrict__ b2)
{
    int o = blockIdx.x * 256 + threadIdx.x;
    int b = blockIdx.y;
    if (o >= 512) return;
    float s = 0.f;
    for (int c = 0; c < 512; c++) s += w[(long long)o * 1024 + 512 + c] * g[b * 512 + c];
    b2[b * 512 + o] = s;
}

extern "C" void kernel_launch(void* const* d_in, const int* in_sizes, int n_in,
                              void* d_out, int out_size, void* d_ws, size_t ws_size,
                              hipStream_t stream)
{
    const float* x       = (const float*)d_in[0];
    const float* conv1_w = (const float*)d_in[1];
    const float* bn1_g   = (const float*)d_in[2];
    const float* bn1_b   = (const float*)d_in[3];
    const float* conv2_w = (const float*)d_in[4];
    const float* bn2_g   = (const float*)d_in[5];
    const float* bn2_b   = (const float*)d_in[6];
    const float* conv3_w = (const float*)d_in[7];
    const float* bn3_g   = (const float*)d_in[8];
    const float* bn3_b   = (const float*)d_in[9];
    const float* pt1_w   = (const float*)d_in[10];
    const float* pt1_g   = (const float*)d_in[11];
    const float* pt1_b   = (const float*)d_in[12];
    const float* pt2_w   = (const float*)d_in[13];
    const float* pt2_g   = (const float*)d_in[14];
    const float* pt2_b   = (const float*)d_in[15];
    const float* sa_qk[2] = {(const float*)d_in[16], (const float*)d_in[23]};
    const float* sa_vw[2] = {(const float*)d_in[17], (const float*)d_in[24]};
    const float* sa_vb[2] = {(const float*)d_in[18], (const float*)d_in[25]};
    const float* sa_tw[2] = {(const float*)d_in[19], (const float*)d_in[26]};
    const float* sa_tb[2] = {(const float*)d_in[20], (const float*)d_in[27]};
    const float* sa_g[2]  = {(const float*)d_in[21], (const float*)d_in[28]};
    const float* sa_b[2]  = {(const float*)d_in[22], (const float*)d_in[29]};
    const float* cf_w = (const float*)d_in[30];
    const float* cf_g = (const float*)d_in[31];
    const float* cf_b = (const float*)d_in[32];
    const float* s1_w = (const float*)d_in[33];
    const float* s1_g = (const float*)d_in[34];
    const float* s1_b = (const float*)d_in[35];
    const float* s2_w = (const float*)d_in[36];
    const float* s2_g = (const float*)d_in[37];
    const float* s2_b = (const float*)d_in[38];
    const float* s3_w = (const float*)d_in[39];

    char* base = (char*)d_ws;
    size_t off = 0;
    auto alloc = [&](size_t bytes) -> void* {
        void* p = base + off;
        off = (off + bytes + 255) & ~(size_t)255;
        return p;
    };
    const long long N = NPTS;
    const long long PO64   = (long long)BATCH * N * 64;
    const long long PO128  = (long long)BATCH * N * 128;
    const long long PO256  = (long long)BATCH * N * 256;
    const long long PO512  = (long long)BATCH * N * 512;
    const long long PO1024 = (long long)BATCH * N * 1024;

    unsigned short* S1  = (unsigned short*)alloc(2 * PO256 * 2);
    unsigned short* S2  = (unsigned short*)alloc(2 * PO256 * 2);
    unsigned short* Dv  = (unsigned short*)alloc(2 * PO256 * 2);
    unsigned short* cat = (unsigned short*)alloc(2 * PO1024 * 2);
    unsigned short* face = (unsigned short*)alloc(2 * PO512 * 2);
    unsigned short* xq  = (unsigned short*)alloc((size_t)BATCH * N * 128 * 2);
    unsigned short* xv  = (unsigned short*)alloc((size_t)BATCH * 256 * N * 2);
    unsigned short* s1b = (unsigned short*)alloc(2 * PO512 * 2);
    unsigned short* s2b = (unsigned short*)alloc(2 * PO256 * 2);
    float* part = (float*)alloc((size_t)BATCH * MSPLIT * N * 256 * 4);          // 32 MB
    float* csp  = (float*)alloc((size_t)BATCH * MSPLIT * N * 4);
    float* rs = (float*)alloc((size_t)BATCH * N * 4);
    float* pm = (float*)alloc((size_t)BATCH * 64 * 512 * 4);
    float* gm = (float*)alloc((size_t)BATCH * 512 * 4);
    float* b2 = (float*)alloc((size_t)BATCH * 512 * 4);
    unsigned short* wb = (unsigned short*)alloc((size_t)3400000 * 2);  // pre-split weights

    // ---- weight pre-split table ----
    WSplit wd;
    const float* wsrc[14] = {conv2_w, conv3_w, pt1_w, pt2_w, sa_qk[0], sa_qk[1],
                             sa_vw[0], sa_vw[1], sa_tw[0], sa_tw[1], cf_w, s1_w, s2_w, s3_w};
    int wn[14] = {128*64, 256*128, 256*256, 256*256, 128*256, 128*256,
                  256*256, 256*256, 256*256, 256*256, 512*1024, 512*1024, 256*512, 50*256};
    long long wo[14]; long long acc_ = 0;
    for (int i = 0; i < 14; i++) { wd.src[i] = wsrc[i]; wd.n[i] = wn[i]; wd.off[i] = acc_; wo[i] = acc_; acc_ += 2LL * wn[i]; }
    presplit_k<<<dim3((512*1024 + 255) / 256, 14), 256, 0, stream>>>(wd, wb);
    auto W = [&](int i) { return wb + wo[i]; };

    auto nt = [&](const unsigned short* A, long long a_bs, int a_lda, long long a_po,
                  const unsigned short* B, long long b_bs, int b_lda, long long b_po,
                  void* C, long long c_bs, int c_ld, long long c_po,
                  int Mrows, int Nb, int K,
                  const float* bias, int bias_mode,
                  const float* bng, const float* bnb,
                  const unsigned short* res, long long res_bs, int res_ld, long long res_po,
                  int act, int out_mode) {
        dim3 g((Nb + 63) / 64, Mrows / 64, BATCH);
        gemm_nt_split<<<g, 256, 0, stream>>>(A, a_bs, a_lda, a_po, B, b_bs, b_lda, b_po,
                                             C, c_bs, c_ld, c_po, Nb, K,
                                             bias, bias_mode, bng, bnb,
                                             res, res_bs, res_ld, res_po, act, out_mode);
    };
    auto ntB = [&](const unsigned short* A, long long a_bs, int a_lda, long long a_po,
                   const unsigned short* B, long long b_bs, int b_lda, long long b_po,
                   void* C, long long c_bs, int c_ld, long long c_po,
                   int Mrows, int Nb, int K,
                   const float* bias, int bias_mode,
                   const float* bng, const float* bnb,
                   const unsigned short* res, long long res_bs, int res_ld, long long res_po,
                   int act, int out_mode) {
        dim3 g((Nb + 63) / 64, Mrows / 64, BATCH);
        gemm_nt_splitB<<<g, 256, 0, stream>>>(A, a_bs, a_lda, a_po, B, b_bs, b_lda, b_po,
                                              C, c_bs, c_ld, c_po, Nb, K,
                                              bias, bias_mode, bng, bnb,
                                              res, res_bs, res_ld, res_po, act, out_mode);
    };
    auto nt3 = [&](const unsigned short* A, long long a_bs, int a_lda, long long a_po,
                   const unsigned short* B, long long b_bs, int b_lda, long long b_po,
                   void* C, long long c_bs, int c_ld, long long c_po,
                   int Mrows, int Nb, int K,
                   const float* bias, int bias_mode,
                   const float* bng, const float* bnb,
                   const unsigned short* res, long long res_bs, int res_ld, long long res_po,
                   int act, int out_mode) {
        dim3 g((Nb + 63) / 64, Mrows / 128, BATCH);
        gemm_nt_split3<<<g, 256, 0, stream>>>(A, a_bs, a_lda, a_po, B, b_bs, b_lda, b_po,
                                              C, c_bs, c_ld, c_po, Nb, K,
                                              bias, bias_mode, bng, bnb,
                                              res, res_bs, res_ld, res_po, act, out_mode);
    };

    // ---- stem ----
    conv1_k<<<dim3(NPTS / 4, BATCH), 256, 0, stream>>>(x, conv1_w, bn1_g, bn1_b, S1, PO64);
    nt(S1, N * 64, 64, PO64,    W(0), 0, 64, wn[0],  S2, N * 128, 128, PO128,
       NPTS, 128, 64,  nullptr, 0, bn2_g, bn2_b, nullptr, 0, 0, 0, 1, 0);
    ntB(S2, N * 128, 128, PO128, W(1), 0, 128, wn[1], S1, N * 256, 256, PO256,
        NPTS, 256, 128, nullptr, 0, bn3_g, bn3_b, nullptr, 0, 0, 0, 1, 0);
    ntB(S1, N * 256, 256, PO256, W(2), 0, 256, wn[2], S2, N * 256, 256, PO256,
        NPTS, 256, 256, nullptr, 0, pt1_g, pt1_b, nullptr, 0, 0, 0, 1, 0);
    ntB(S2, N * 256, 256, PO256, W(3), 0, 256, wn[3], S1, N * 256, 256, PO256,
        NPTS, 256, 256, nullptr, 0, pt2_g, pt2_b, nullptr, 0, 0, 0, 1, 0);

    // ---- 4 SA layers ----
    for (int i = 0; i < 4; i++) {
        int p = (i == 0) ? 0 : 1;
        const unsigned short* xin = (i == 0) ? S1 : cat + (size_t)(i - 1) * 256;
        long long xin_bs = (i == 0) ? N * 256 : N * 1024;
        int xin_ld = (i == 0) ? 256 : 1024;
        long long xin_po = (i == 0) ? PO256 : PO1024;

        // xq[n][128] plain bf16 (K=256)
        ntB(xin, xin_bs, xin_ld, xin_po, W(4 + p), 0, 256, wn[4 + p],
            xq, N * 128, 128, 0, NPTS, 128, 256,
            nullptr, 0, nullptr, nullptr, nullptr, 0, 0, 0, 0, 1);
        // xv[c][n] plain bf16 (A = weights, K=256)
        ntB(W(6 + p), 0, 256, wn[6 + p], xin, xin_bs, xin_ld, xin_po,
            xv, 256 * N, NPTS, 0, 256, NPTS, 256,
            sa_vb[p], 3, nullptr, nullptr, nullptr, 0, 0, 0, 0, 1);
        // zero rs (needed for rs_k atomics)
        zero_k<<<(BATCH * NPTS + 255) / 256, 256, 0, stream>>>(rs, BATCH * NPTS);
        // E1: rs row-sums (no att store)
        rs_k<<<dim3(RSSPLIT, NPTS / 64, BATCH), 256, 0, stream>>>(xq, rs);
        // E2: fused QK->exp/rs->PV partials + cs partials
        attn_pv<<<dim3(1, NPTS / 64, BATCH * MSPLIT), 256, 0, stream>>>(
            xq, xv, rs, part, csp);
        // d = x - (sum partials)/(1e-9 + sum cs partials)
        diff_k<<<dim3(NPTS * 256 / 1024, BATCH), 256, 0, stream>>>(
            xin, xin_bs, xin_ld, xin_po, part, csp, Dv, PO256);
        // x_out = x + relu(bn(tw@d + tb)) -> cat slice i (K=256)
        ntB(Dv, N * 256, 256, PO256, W(8 + p), 0, 256, wn[8 + p],
            cat + (size_t)i * 256, N * 1024, 1024, PO1024,
            NPTS, 256, 256, sa_tb[p], 1, sa_g[p], sa_b[p],
            xin, xin_bs, xin_ld, xin_po, 1, 0);
    }

    // ---- head ----
    nt3(cat, N * 1024, 1024, PO1024, W(10), 0, 1024, wn[10],
        face, N * 512, 512, PO512, NPTS, 512, 1024,
        nullptr, 0, cf_g, cf_b, nullptr, 0, 0, 0, 2, 0);
    gmaxp_k<<<dim3(4, 16, BATCH), 256, 0, stream>>>(face, PO512, pm);
    gmaxr_k<<<dim3(BATCH * 512 / 256), 256, 0, stream>>>(pm, gm);
    bias2_k<<<dim3(2, BATCH), 256, 0, stream>>>(s1_w, gm, b2);
    nt3(face, N * 512, 512, PO512, W(11), 0, 1024, wn[11],
        s1b, N * 512, 512, PO512, NPTS, 512, 512,
        b2, 2, s1_g, s1_b, nullptr, 0, 0, 0, 2, 0);
    ntB(s1b, N * 512, 512, PO512, W(12), 0, 512, wn[12],
        s2b, N * 256, 256, PO256, NPTS, 256, 512,
        nullptr, 0, s2_g, s2_b, nullptr, 0, 0, 0, 2, 0);
    ntB(s2b, N * 256, 256, PO256, W(13), 0, 256, wn[13],
        d_out, N * 50, 50, 0, NPTS, 50, 256,
        nullptr, 0, nullptr, nullptr, nullptr, 0, 0, 0, 0, 2);
}

// Round 7
// 729.781 us; speedup vs baseline: 1.4484x; 1.0144x over previous
//
#include <hip/hip_runtime.h>
#include <hip/hip_bf16.h>

// PCT segmentation forward. R24 = R23 (740.3us) + attn_pv pipeline fix:
// - attn_pv: Kq double-buffered (2x16KB; LDS 73KB, still 2 blk/CU). Kq(t) is
//   staged during iter t-1 and fenced by t-1's pre-PV __syncthreads(vmcnt 0),
//   so QK(t) starts with NO barrier after staging. 2 barriers/iter (was 3),
//   both draining loads issued a full compute-phase earlier:
//   A:sync -> issue Vv(t)+Kq(t+1) -> QK -> exp/Pl -> B:sync(drain) -> PV.
//   Vv DMA staging KEPT (R18's regression came from dropping it, not from
//   the barrier count — this isolates the barrier restructure).
// - everything else identical to R23: K3 for cf/s1, XCD swizzle everywhere,
//   vectorized gmaxp/diff, rs_k single-barrier pipeline.

#define NPTS 4096
#define BATCH 2
#define MSPLIT 4
#define RSSPLIT 8
static constexpr float INV_STD = 0.9999950000374997f;  // 1/sqrt(1+1e-5)

__device__ __forceinline__ float bf2f(unsigned short u) {
    return __uint_as_float(((unsigned int)u) << 16);
}
__device__ __forceinline__ unsigned short f2bf(float f) {
    unsigned int x = __float_as_uint(f);
    unsigned int r = (x + 0x7FFFu + ((x >> 16) & 1u)) >> 16;
    return (unsigned short)r;
}

// async global->LDS 16B DMA: LDS base wave-uniform; HW writes lptr+lane*16.
__device__ __forceinline__ void async16(const unsigned short* g, unsigned short* l)
{
    __builtin_amdgcn_global_load_lds(
        (const __attribute__((address_space(1))) unsigned int*)(const void*)g,
        (__attribute__((address_space(3))) unsigned int*)(void*)l,
        16, 0, 0);
}

typedef __attribute__((ext_vector_type(8))) short short8;
typedef __attribute__((ext_vector_type(4))) short s16x4;
typedef __attribute__((ext_vector_type(4))) float f32x4;

// ---------------- weight pre-split ----------------
struct WSplit {
    const float* src[14];
    int n[14];
    long long off[14];   // ushort offset of hi plane; lo at off+n
};

__global__ __launch_bounds__(256)
void presplit_k(WSplit d, unsigned short* __restrict__ wbuf)
{
    int wi = blockIdx.y;
    int i = blockIdx.x * 256 + threadIdx.x;
    int n = d.n[wi];
    if (i >= n) return;
    float v = d.src[wi][i];
    unsigned short h = f2bf(v);
    unsigned short* dst = wbuf + d.off[wi];
    dst[i] = h;
    dst[n + i] = f2bf(v - bf2f(h));
}

// shared epilogue
__device__ __forceinline__ void nt_epilogue(
    float y, int rg, int cg, int b, int Nb,
    const float* bias, int bias_mode,
    const float* bng, const float* bnb,
    const unsigned short* res, long long res_bs, int res_ld, long long res_po,
    int act, int out_mode,
    void* Cp, long long c_bs, int c_ld, long long c_po)
{
    if (bias) {
        if (bias_mode == 3)      y += bias[rg];
        else if (bias_mode == 2) y += bias[b * Nb + cg];
        else                     y += bias[cg];
    }
    if (bng) y = y * (INV_STD * bng[cg]) + bnb[cg];
    if (act == 1) y = fmaxf(y, 0.f);
    else if (act == 2) y = (y > 0.f) ? y : 0.2f * y;
    if (res) {
        long long ri_ = (long long)b * res_bs + (long long)rg * res_ld + cg;
        y += bf2f(res[ri_]) + bf2f(res[res_po + ri_]);
    }
    long long ci = (long long)b * c_bs + (long long)rg * c_ld + cg;
    if (out_mode == 0) {
        unsigned short* C = (unsigned short*)Cp;
        unsigned short h = f2bf(y);
        C[ci] = h;
        C[c_po + ci] = f2bf(y - bf2f(h));
    } else if (out_mode == 1) {
        ((unsigned short*)Cp)[ci] = f2bf(y);
    } else {
        if (cg < Nb) ((float*)Cp)[ci] = y;
    }
}

// ---------------- K1: split-bf16 NT GEMM, 64x64 tile, BK=64 ----------------
__global__ __launch_bounds__(256)
void gemm_nt_split(const unsigned short* __restrict__ A, long long a_bs, int a_lda, long long a_po,
                   const unsigned short* __restrict__ B, long long b_bs, int b_lda, long long b_po,
                   void* __restrict__ Cp, long long c_bs, int c_ld, long long c_po,
                   int Nb, int K,
                   const float* __restrict__ bias, int bias_mode,
                   const float* __restrict__ bng, const float* __restrict__ bnb,
                   const unsigned short* __restrict__ res, long long res_bs, int res_ld, long long res_po,
                   int act, int out_mode)
{
    __shared__ unsigned short As[2][64 * 64];
    __shared__ unsigned short Bs[2][64 * 64];
    const int gx = gridDim.x, gy = gridDim.y;
    const int nblk = gx * gy * (int)gridDim.z;
    int d_ = blockIdx.x + gx * (blockIdx.y + gy * blockIdx.z);
    int w_ = (nblk & 7) ? d_ : ((d_ & 7) * (nblk >> 3) + (d_ >> 3));
    const int b = w_ / (gx * gy);
    const int rem_ = w_ % (gx * gy);
    const int m0 = (rem_ / gx) * 64, n0 = (rem_ % gx) * 64;
    const int t = threadIdx.x;
    const int lane = t & 63, w = t >> 6;
    const int wr = (w >> 1) * 32, wc = (w & 1) * 32;
    const int ml = lane & 15, q = lane >> 4;

    f32x4 acc[2][2] = {};

    for (int k0 = 0; k0 < K; k0 += 64) {
        __syncthreads();
        #pragma unroll
        for (int e = 0; e < 2; e++) {
            int idx = t + e * 256;
            int row = idx >> 3, blk = idx & 7;
            int gblk = blk ^ (row & 7);
            int lofs = (e * 256 + (t & 192)) * 8;
            const unsigned short* sA = A + (long long)b * a_bs
                                     + (long long)(m0 + row) * a_lda + k0 + gblk * 8;
            const unsigned short* sB = B + (long long)b * b_bs
                                     + (long long)(n0 + row) * b_lda + k0 + gblk * 8;
            async16(sA,        &As[0][0] + lofs);
            async16(sA + a_po, &As[1][0] + lofs);
            async16(sB,        &Bs[0][0] + lofs);
            async16(sB + b_po, &Bs[1][0] + lofs);
        }
        __syncthreads();
        #pragma unroll
        for (int kk = 0; kk < 2; kk++) {
            short8 ah[2], al[2], bh[2], bl[2];
            #pragma unroll
            for (int it = 0; it < 2; it++) {
                int row = wr + it * 16 + ml;
                int slot = (kk * 4 + q) ^ (row & 7);
                ah[it] = *(const short8*)(&As[0][row * 64 + slot * 8]);
                al[it] = *(const short8*)(&As[1][row * 64 + slot * 8]);
            }
            #pragma unroll
            for (int jt = 0; jt < 2; jt++) {
                int row = wc + jt * 16 + ml;
                int slot = (kk * 4 + q) ^ (row & 7);
                bh[jt] = *(const short8*)(&Bs[0][row * 64 + slot * 8]);
                bl[jt] = *(const short8*)(&Bs[1][row * 64 + slot * 8]);
            }
            #pragma unroll
            for (int it = 0; it < 2; it++)
                #pragma unroll
                for (int jt = 0; jt < 2; jt++) {
                    acc[it][jt] = __builtin_amdgcn_mfma_f32_16x16x32_bf16(ah[it], bh[jt], acc[it][jt], 0, 0, 0);
                    acc[it][jt] = __builtin_amdgcn_mfma_f32_16x16x32_bf16(ah[it], bl[jt], acc[it][jt], 0, 0, 0);
                    acc[it][jt] = __builtin_amdgcn_mfma_f32_16x16x32_bf16(al[it], bh[jt], acc[it][jt], 0, 0, 0);
                }
        }
    }

    #pragma unroll
    for (int it = 0; it < 2; it++)
        #pragma unroll
        for (int jt = 0; jt < 2; jt++)
            #pragma unroll
            for (int r = 0; r < 4; r++)
                nt_epilogue(acc[it][jt][r], m0 + wr + it * 16 + q * 4 + r,
                            n0 + wc + jt * 16 + ml, b, Nb,
                            bias, bias_mode, bng, bnb, res, res_bs, res_ld, res_po,
                            act, out_mode, Cp, c_bs, c_ld, c_po);
}

// ---------------- K1B: split-bf16 NT GEMM, 64x64 tile, BK=128 ----------------
__global__ __launch_bounds__(256)
void gemm_nt_splitB(const unsigned short* __restrict__ A, long long a_bs, int a_lda, long long a_po,
                    const unsigned short* __restrict__ B, long long b_bs, int b_lda, long long b_po,
                    void* __restrict__ Cp, long long c_bs, int c_ld, long long c_po,
                    int Nb, int K,
                    const float* __restrict__ bias, int bias_mode,
                    const float* __restrict__ bng, const float* __restrict__ bnb,
                    const unsigned short* __restrict__ res, long long res_bs, int res_ld, long long res_po,
                    int act, int out_mode)
{
    __shared__ unsigned short As[2][2][64 * 64];   // [plane][sub] 32 KB
    __shared__ unsigned short Bs[2][2][64 * 64];   // 32 KB
    const int gx = gridDim.x, gy = gridDim.y;
    const int nblk = gx * gy * (int)gridDim.z;
    int d_ = blockIdx.x + gx * (blockIdx.y + gy * blockIdx.z);
    int w_ = (nblk & 7) ? d_ : ((d_ & 7) * (nblk >> 3) + (d_ >> 3));
    const int b = w_ / (gx * gy);
    const int rem_ = w_ % (gx * gy);
    const int m0 = (rem_ / gx) * 64, n0 = (rem_ % gx) * 64;
    const int t = threadIdx.x;
    const int lane = t & 63, w = t >> 6;
    const int wr = (w >> 1) * 32, wc = (w & 1) * 32;
    const int ml = lane & 15, q = lane >> 4;

    f32x4 acc[2][2] = {};

    for (int k0 = 0; k0 < K; k0 += 128) {
        __syncthreads();
        #pragma unroll
        for (int sub = 0; sub < 2; sub++) {
            int kb = k0 + sub * 64;
            #pragma unroll
            for (int e = 0; e < 2; e++) {
                int idx = t + e * 256;
                int row = idx >> 3, blk = idx & 7;
                int gblk = blk ^ (row & 7);
                int lofs = (e * 256 + (t & 192)) * 8;
                const unsigned short* sA = A + (long long)b * a_bs
                                         + (long long)(m0 + row) * a_lda + kb + gblk * 8;
                const unsigned short* sB = B + (long long)b * b_bs
                                         + (long long)(n0 + row) * b_lda + kb + gblk * 8;
                async16(sA,        &As[0][sub][0] + lofs);
                async16(sA + a_po, &As[1][sub][0] + lofs);
                async16(sB,        &Bs[0][sub][0] + lofs);
                async16(sB + b_po, &Bs[1][sub][0] + lofs);
            }
        }
        __syncthreads();
        #pragma unroll
        for (int sub = 0; sub < 2; sub++)
            #pragma unroll
            for (int kk = 0; kk < 2; kk++) {
                short8 ah[2], al[2], bh[2], bl[2];
                #pragma unroll
                for (int it = 0; it < 2; it++) {
                    int row = wr + it * 16 + ml;
                    int slot = (kk * 4 + q) ^ (row & 7);
                    ah[it] = *(const short8*)(&As[0][sub][row * 64 + slot * 8]);
                    al[it] = *(const short8*)(&As[1][sub][row * 64 + slot * 8]);
                }
                #pragma unroll
                for (int jt = 0; jt < 2; jt++) {
                    int row = wc + jt * 16 + ml;
                    int slot = (kk * 4 + q) ^ (row & 7);
                    bh[jt] = *(const short8*)(&Bs[0][sub][row * 64 + slot * 8]);
                    bl[jt] = *(const short8*)(&Bs[1][sub][row * 64 + slot * 8]);
                }
                #pragma unroll
                for (int it = 0; it < 2; it++)
                    #pragma unroll
                    for (int jt = 0; jt < 2; jt++) {
                        acc[it][jt] = __builtin_amdgcn_mfma_f32_16x16x32_bf16(ah[it], bh[jt], acc[it][jt], 0, 0, 0);
                        acc[it][jt] = __builtin_amdgcn_mfma_f32_16x16x32_bf16(ah[it], bl[jt], acc[it][jt], 0, 0, 0);
                        acc[it][jt] = __builtin_amdgcn_mfma_f32_16x16x32_bf16(al[it], bh[jt], acc[it][jt], 0, 0, 0);
                    }
            }
    }

    #pragma unroll
    for (int it = 0; it < 2; it++)
        #pragma unroll
        for (int jt = 0; jt < 2; jt++)
            #pragma unroll
            for (int r = 0; r < 4; r++)
                nt_epilogue(acc[it][jt][r], m0 + wr + it * 16 + q * 4 + r,
                            n0 + wc + jt * 16 + ml, b, Nb,
                            bias, bias_mode, bng, bnb, res, res_bs, res_ld, res_po,
                            act, out_mode, Cp, c_bs, c_ld, c_po);
}

// ---------------- K3: split-bf16 NT GEMM, 128x64 tile, BK=64 ----------------
__global__ __launch_bounds__(256)
void gemm_nt_split3(const unsigned short* __restrict__ A, long long a_bs, int a_lda, long long a_po,
                    const unsigned short* __restrict__ B, long long b_bs, int b_lda, long long b_po,
                    void* __restrict__ Cp, long long c_bs, int c_ld, long long c_po,
                    int Nb, int K,
                    const float* __restrict__ bias, int bias_mode,
                    const float* __restrict__ bng, const float* __restrict__ bnb,
                    const unsigned short* __restrict__ res, long long res_bs, int res_ld, long long res_po,
                    int act, int out_mode)
{
    __shared__ unsigned short As[2][128 * 64];   // 32 KB (hi+lo)
    __shared__ unsigned short Bs[2][64 * 64];    // 16 KB
    const int gx = gridDim.x, gy = gridDim.y;
    const int nblk = gx * gy * (int)gridDim.z;
    int d_ = blockIdx.x + gx * (blockIdx.y + gy * blockIdx.z);
    int w_ = (nblk & 7) ? d_ : ((d_ & 7) * (nblk >> 3) + (d_ >> 3));
    const int b = w_ / (gx * gy);
    const int rem_ = w_ % (gx * gy);
    const int m0 = (rem_ / gx) * 128, n0 = (rem_ % gx) * 64;
    const int t = threadIdx.x;
    const int lane = t & 63, w = t >> 6;
    const int wr = (w >> 1) * 64, wc = (w & 1) * 32;
    const int ml = lane & 15, q = lane >> 4;

    f32x4 acc[4][2] = {};

    for (int k0 = 0; k0 < K; k0 += 64) {
        __syncthreads();
        #pragma unroll
        for (int e = 0; e < 4; e++) {            // A: 128 rows
            int idx = t + e * 256;
            int row = idx >> 3, blk = idx & 7;
            int gblk = blk ^ (row & 7);
            int lofs = (e * 256 + (t & 192)) * 8;
            const unsigned short* sA = A + (long long)b * a_bs
                                     + (long long)(m0 + row) * a_lda + k0 + gblk * 8;
            async16(sA,        &As[0][0] + lofs);
            async16(sA + a_po, &As[1][0] + lofs);
        }
        #pragma unroll
        for (int e = 0; e < 2; e++) {            // B: 64 rows
            int idx = t + e * 256;
            int row = idx >> 3, blk = idx & 7;
            int gblk = blk ^ (row & 7);
            int lofs = (e * 256 + (t & 192)) * 8;
            const unsigned short* sB = B + (long long)b * b_bs
                                     + (long long)(n0 + row) * b_lda + k0 + gblk * 8;
            async16(sB,        &Bs[0][0] + lofs);
            async16(sB + b_po, &Bs[1][0] + lofs);
        }
        __syncthreads();
        #pragma unroll
        for (int kk = 0; kk < 2; kk++) {
            short8 ah[4], al[4], bh[2], bl[2];
            #pragma unroll
            for (int it = 0; it < 4; it++) {
                int row = wr + it * 16 + ml;
                int slot = (kk * 4 + q) ^ (row & 7);
                ah[it] = *(const short8*)(&As[0][row * 64 + slot * 8]);
                al[it] = *(const short8*)(&As[1][row * 64 + slot * 8]);
            }
            #pragma unroll
            for (int jt = 0; jt < 2; jt++) {
                int row = wc + jt * 16 + ml;
                int slot = (kk * 4 + q) ^ (row & 7);
                bh[jt] = *(const short8*)(&Bs[0][row * 64 + slot * 8]);
                bl[jt] = *(const short8*)(&Bs[1][row * 64 + slot * 8]);
            }
            #pragma unroll
            for (int it = 0; it < 4; it++)
                #pragma unroll
                for (int jt = 0; jt < 2; jt++) {
                    acc[it][jt] = __builtin_amdgcn_mfma_f32_16x16x32_bf16(ah[it], bh[jt], acc[it][jt], 0, 0, 0);
                    acc[it][jt] = __builtin_amdgcn_mfma_f32_16x16x32_bf16(ah[it], bl[jt], acc[it][jt], 0, 0, 0);
                    acc[it][jt] = __builtin_amdgcn_mfma_f32_16x16x32_bf16(al[it], bh[jt], acc[it][jt], 0, 0, 0);
                }
        }
    }

    #pragma unroll
    for (int it = 0; it < 4; it++)
        #pragma unroll
        for (int jt = 0; jt < 2; jt++)
            #pragma unroll
            for (int r = 0; r < 4; r++)
                nt_epilogue(acc[it][jt][r], m0 + wr + it * 16 + q * 4 + r,
                            n0 + wc + jt * 16 + ml, b, Nb,
                            bias, bias_mode, bng, bnb, res, res_bs, res_ld, res_po,
                            act, out_mode, Cp, c_bs, c_ld, c_po);
}

// ---------------- E1: rs[p] = sum_m exp(e[p][m]), atomic row-sums ----------------
__global__ __launch_bounds__(256)
void rs_k(const unsigned short* __restrict__ xq, float* __restrict__ rs)
{
    __shared__ unsigned short Kq[2][2][64 * 64];   // [dbuf][half] 32 KB
    int d_ = blockIdx.x + 8 * (blockIdx.y + 64 * blockIdx.z);
    int w_ = (d_ & 7) * 128 + (d_ >> 3);
    const int p0 = (w_ % 64) * 64;
    const int xseg = (w_ / 64) % 8;
    const int b = w_ / 512;
    const int m_beg = xseg * (NPTS / RSSPLIT);
    const unsigned short* xqB = xq + (long long)b * NPTS * 128;
    const int t = threadIdx.x;
    const int lane = t & 63, w = t >> 6;
    const int pw = w * 16;
    const int ml = lane & 15, q = lane >> 4;

    short8 af[4];
    #pragma unroll
    for (int ks = 0; ks < 4; ks++)
        af[ks] = *(const short8*)(xqB + (long long)(p0 + pw + ml) * 128 + ks * 32 + q * 8);

    float rsum[4] = {0.f, 0.f, 0.f, 0.f};

    auto stageK = [&](int m0, int buf) {
        #pragma unroll
        for (int e = 0; e < 4; e++) {
            int idx = t + e * 256;
            int sub = idx >> 9, row = (idx >> 3) & 63, blk = idx & 7;
            int gblk = blk ^ (row & 7);
            int lofs = (e * 256 + (t & 192)) * 8;
            async16(xqB + (long long)(m0 + row) * 128 + sub * 64 + gblk * 8,
                    &Kq[buf][0][0] + lofs);
        }
    };

    constexpr int NIT = (NPTS / RSSPLIT) / 64;
    stageK(m_beg, 0);
    __syncthreads();

    for (int it = 0; it < NIT; ++it) {
        const int m0 = m_beg + it * 64;
        const int cur = it & 1;
        if (it + 1 < NIT) stageK(m0 + 64, cur ^ 1);
        f32x4 acc[4] = {};
        #pragma unroll
        for (int ks = 0; ks < 4; ks++) {
            int kh = ks >> 1, kk = ks & 1;
            #pragma unroll
            for (int jt = 0; jt < 4; jt++) {
                int row = jt * 16 + ml;
                int slot = (kk * 4 + q) ^ (row & 7);
                short8 bf = *(const short8*)(&Kq[cur][kh][row * 64 + slot * 8]);
                acc[jt] = __builtin_amdgcn_mfma_f32_16x16x32_bf16(af[ks], bf, acc[jt], 0, 0, 0);
            }
        }
        #pragma unroll
        for (int jt = 0; jt < 4; jt++)
            #pragma unroll
            for (int r = 0; r < 4; r++)
                rsum[r] += __expf(acc[jt][r]);
        __syncthreads();   // drains next-iter staging; protects Kq[cur] overwrite
    }
    #pragma unroll
    for (int r = 0; r < 4; r++) {
        float s = rsum[r];
        s += __shfl_xor(s, 1); s += __shfl_xor(s, 2);
        s += __shfl_xor(s, 4); s += __shfl_xor(s, 8);
        if (ml == 0) atomicAdd(&rs[b * NPTS + p0 + pw + q * 4 + r], s);
    }
}

// ---------------- E2: QK -> exp/rs[m] -> PV partials + cs partials ----------------
// Kq double-buffered: Kq(t) staged during t-1, fenced by t-1's pre-PV sync.
// 2 barriers/iter: A (prev PV done) -> issue Vv(t)+Kq(t+1) -> QK (no wait)
// -> exp/Pl -> B (vmcnt0 drain: Vv hidden under QK+exp; Pl visible) -> PV.
__global__ __launch_bounds__(256)
void attn_pv(const unsigned short* __restrict__ xq,   // [B][N][128]
             const unsigned short* __restrict__ xv,   // [B][256][N]
             const float* __restrict__ rs,
             float* __restrict__ part,                // [B*MSPLIT][N][256]
             float* __restrict__ csp)                 // [B*MSPLIT][N]
{
    __shared__ unsigned short Kq[2][2][64 * 64];   // [dbuf][half] 32 KB
    __shared__ unsigned short Vv[256 * 64];        // 32 KB
    __shared__ unsigned short Pl[64][72];          // 9.2 KB  -> 73 KB, 2 blk/CU
    int d_ = blockIdx.y + 64 * blockIdx.z;
    int w_ = (d_ & 7) * 64 + (d_ >> 3);
    const int p0 = (w_ % 64) * 64;
    const int z = w_ / 64;
    const int b = z / MSPLIT, ms = z % MSPLIT;
    const unsigned short* xqB = xq + (long long)b * NPTS * 128;
    const unsigned short* xvB = xv + (long long)b * 256 * NPTS;
    const float* rsB = rs + b * NPTS;
    const int t = threadIdx.x;
    const int lane = t & 63, w = t >> 6;
    const int pw = w * 16;                      // QK p-strip
    const int cw = w * 64;                      // PV c-strip
    const int ml = lane & 15, q = lane >> 4;

    short8 af[4];
    #pragma unroll
    for (int ks = 0; ks < 4; ks++)
        af[ks] = *(const short8*)(xqB + (long long)(p0 + pw + ml) * 128 + ks * 32 + q * 8);

    f32x4 pv[4][4] = {};                        // [p-tile][c-tile]
    float csr[4] = {0.f, 0.f, 0.f, 0.f};

    auto stageK = [&](int m0, int buf) {
        #pragma unroll
        for (int e = 0; e < 4; e++) {
            int idx = t + e * 256;
            int sub = idx >> 9, row = (idx >> 3) & 63, blk = idx & 7;
            int gblk = blk ^ (row & 7);
            int lofs = (e * 256 + (t & 192)) * 8;
            async16(xqB + (long long)(m0 + row) * 128 + sub * 64 + gblk * 8,
                    &Kq[buf][0][0] + lofs);
        }
    };
    auto stageV = [&](int m0) {
        #pragma unroll
        for (int e = 0; e < 8; e++) {
            int idx = t + e * 256;
            int row = idx >> 3, blk = idx & 7;
            int gblk = blk ^ (row & 7);
            int lofs = (e * 256 + (t & 192)) * 8;
            async16(xvB + (long long)row * NPTS + m0 + gblk * 8, Vv + lofs);
        }
    };

    const int m_beg = ms * (NPTS / MSPLIT);
    constexpr int NIT = (NPTS / MSPLIT) / 64;
    stageK(m_beg, 0);
    __syncthreads();   // Kq(0) resident + fenced (vmcnt0 + barrier)

    for (int it = 0; it < NIT; ++it) {
        const int m0 = m_beg + it * 64;
        const int cur = it & 1;
        __syncthreads();   // A: PV(it-1) done -> Vv/Pl free (no-op drains at it=0)
        stageV(m0);                              // 8 DMA (drained at B)
        if (it + 1 < NIT) stageK(m0 + 64, cur ^ 1);  // 4 DMA (fenced at B)
        // QK from Kq[cur] — already resident; no barrier needed here.
        f32x4 acc[4] = {};
        #pragma unroll
        for (int ks = 0; ks < 4; ks++) {
            int kh = ks >> 1, kk = ks & 1;
            #pragma unroll
            for (int jt = 0; jt < 4; jt++) {
                int row = jt * 16 + ml;
                int slot = (kk * 4 + q) ^ (row & 7);
                short8 bf = *(const short8*)(&Kq[cur][kh][row * 64 + slot * 8]);
                acc[jt] = __builtin_amdgcn_mfma_f32_16x16x32_bf16(af[ks], bf, acc[jt], 0, 0, 0);
            }
        }
        // P' = exp(e)/rs[m]
        #pragma unroll
        for (int jt = 0; jt < 4; jt++) {
            float rvm = 1.f / rsB[m0 + jt * 16 + ml];
            #pragma unroll
            for (int r = 0; r < 4; r++) {
                float pvv = __expf(acc[jt][r]) * rvm;
                csr[r] += pvv;
                Pl[pw + q * 4 + r][jt * 16 + ml] = f2bf(pvv);
            }
        }
        __syncthreads();   // B: vmcnt(0) drains Vv(it)+Kq(it+1); Pl visible
        // PV: this wave c-strip cw; A = P'[64p][64m] (shared), B = Vv rows
        #pragma unroll
        for (int kk = 0; kk < 2; kk++) {
            short8 ap[4];
            #pragma unroll
            for (int pst = 0; pst < 4; pst++)
                ap[pst] = *(const short8*)(&Pl[pst * 16 + ml][kk * 32 + q * 8]);
            #pragma unroll
            for (int jt = 0; jt < 4; jt++) {
                int row = cw + jt * 16 + ml;
                int slot = (kk * 4 + q) ^ (row & 7);
                short8 bv = *(const short8*)(&Vv[row * 64 + slot * 8]);
                #pragma unroll
                for (int pst = 0; pst < 4; pst++)
                    pv[pst][jt] = __builtin_amdgcn_mfma_f32_16x16x32_bf16(
                        ap[pst], bv, pv[pst][jt], 0, 0, 0);
            }
        }
    }
    // cs partial: reduce over 16 m-lanes, one PLAIN store per (z, p-row)
    #pragma unroll
    for (int r = 0; r < 4; r++) {
        float s = csr[r];
        s += __shfl_xor(s, 1); s += __shfl_xor(s, 2);
        s += __shfl_xor(s, 4); s += __shfl_xor(s, 8);
        if (ml == 0) csp[(long long)z * NPTS + p0 + pw + q * 4 + r] = s;
    }
    // store PV partials (plain f32)
    float* C = part + (long long)z * ((long long)NPTS * 256);
    #pragma unroll
    for (int pst = 0; pst < 4; pst++)
        #pragma unroll
        for (int jt = 0; jt < 4; jt++)
            #pragma unroll
            for (int r = 0; r < 4; r++) {
                int rg = p0 + pst * 16 + q * 4 + r;
                int cg = cw + jt * 16 + ml;
                C[(long long)rg * 256 + cg] = pv[pst][jt][r];
            }
}

// ---------------- small kernels ----------------
__global__ __launch_bounds__(256)
void conv1_k(const float* __restrict__ x, const float* __restrict__ w,
             const float* __restrict__ g, const float* __restrict__ bb,
             unsigned short* __restrict__ h, long long h_po)
{
    int b = blockIdx.y;
    int p = blockIdx.x * 4 + (threadIdx.x >> 6);
    int c = threadIdx.x & 63;
    const float* xp = x + ((long long)b * NPTS + p) * 3;
    float y = xp[0] * w[c * 3] + xp[1] * w[c * 3 + 1] + xp[2] * w[c * 3 + 2];
    y = y * (INV_STD * g[c]) + bb[c];
    y = fmaxf(y, 0.f);
    long long i = ((long long)b * NPTS + p) * 64 + c;
    unsigned short hi = f2bf(y);
    h[i] = hi;
    h[h_po + i] = f2bf(y - bf2f(hi));
}

__global__ __launch_bounds__(256)
void zero_k(float* __restrict__ p, int n)
{
    int i = blockIdx.x * 256 + threadIdx.x;
    if (i < n) p[i] = 0.f;
}

// d = x - (sum_ms part)/(1e-9 + sum_ms csp); vectorized x4, bit-identical ops
__global__ __launch_bounds__(256)
void diff_k(const unsigned short* __restrict__ xin, long long x_bs, int x_ld, long long x_po,
            const float* __restrict__ part, const float* __restrict__ csp,
            unsigned short* __restrict__ d, long long d_po)
{
    long long i4 = ((long long)blockIdx.x * 256 + threadIdx.x) * 4;  // over NPTS*256
    int b = blockIdx.y;
    int p = (int)(i4 >> 8), c = (int)(i4 & 255);
    long long xi = (long long)b * x_bs + (long long)p * x_ld + c;
    s16x4 xh = *(const s16x4*)(xin + xi);
    s16x4 xl = *(const s16x4*)(xin + x_po + xi);
    float xr0 = 0.f, xr1 = 0.f, xr2 = 0.f, xr3 = 0.f, den = 1e-9f;
    #pragma unroll
    for (int ks = 0; ks < MSPLIT; ks++) {
        int z = b * MSPLIT + ks;
        f32x4 pv = *(const f32x4*)(part + (long long)z * ((long long)NPTS * 256) + i4);
        xr0 += pv[0]; xr1 += pv[1]; xr2 += pv[2]; xr3 += pv[3];
        den += csp[(long long)z * NPTS + p];
    }
    float v0 = bf2f((unsigned short)xh[0]) + bf2f((unsigned short)xl[0]) - xr0 / den;
    float v1 = bf2f((unsigned short)xh[1]) + bf2f((unsigned short)xl[1]) - xr1 / den;
    float v2 = bf2f((unsigned short)xh[2]) + bf2f((unsigned short)xl[2]) - xr2 / den;
    float v3 = bf2f((unsigned short)xh[3]) + bf2f((unsigned short)xl[3]) - xr3 / den;
    long long di = (long long)b * NPTS * 256 + i4;
    s16x4 hh, ll;
    hh[0] = (short)f2bf(v0); ll[0] = (short)f2bf(v0 - bf2f((unsigned short)hh[0]));
    hh[1] = (short)f2bf(v1); ll[1] = (short)f2bf(v1 - bf2f((unsigned short)hh[1]));
    hh[2] = (short)f2bf(v2); ll[2] = (short)f2bf(v2 - bf2f((unsigned short)hh[2]));
    hh[3] = (short)f2bf(v3); ll[3] = (short)f2bf(v3 - bf2f((unsigned short)hh[3]));
    *(s16x4*)(d + di) = hh;
    *(s16x4*)(d + d_po + di) = ll;
}

// gmax stage 1: grid (4, 16, B), block = 256 = 4 waves; block covers 64
// points x all 512 channels. Wave reads one full row (short8/lane) per step.
__global__ __launch_bounds__(256)
void gmaxp_k(const unsigned short* __restrict__ face, long long f_po, float* __restrict__ pm)
{
    __shared__ float red[4][512];
    int b = blockIdx.z;
    int seg = blockIdx.y * 4 + blockIdx.x;    // 0..63, 64-point segment
    int w = threadIdx.x >> 6, l = threadIdx.x & 63;
    float m8[8];
    #pragma unroll
    for (int k = 0; k < 8; k++) m8[k] = -3.4e38f;
    for (int jj = 0; jj < 16; jj++) {
        int i = seg * 64 + jj * 4 + w;
        long long off = ((long long)b * NPTS + i) * 512 + l * 8;
        short8 h = *(const short8*)(face + off);
        short8 lo = *(const short8*)(face + f_po + off);
        #pragma unroll
        for (int k = 0; k < 8; k++)
            m8[k] = fmaxf(m8[k], bf2f((unsigned short)h[k]) + bf2f((unsigned short)lo[k]));
    }
    #pragma unroll
    for (int k = 0; k < 8; k++) red[w][l * 8 + k] = m8[k];
    __syncthreads();
    for (int c = threadIdx.x; c < 512; c += 256) {
        float m = fmaxf(fmaxf(red[0][c], red[1][c]), fmaxf(red[2][c], red[3][c]));
        pm[((long long)b * 64 + seg) * 512 + c] = m;
    }
}

__global__ __launch_bounds__(256)
void gmaxr_k(const float* __restrict__ pm, float* __restrict__ gm)
{
    int idx = blockIdx.x * 256 + threadIdx.x;  // over BATCH*512
    int b = idx >> 9, c = idx & 511;
    float m = -3.4e38f;
    for (int ch = 0; ch < 64; ch++)
        m = fmaxf(m, pm[((long long)b * 64 + ch) * 512 + c]);
    gm[idx] = m;
}

__global__ __launch_bounds__(256)
void bias2_k(const float* __restrict__ w, const float* __restrict__ g, float* __restrict__ b2)
{
    int o = blockIdx.x * 256 + threadIdx.x;
    int b = blockIdx.y;
    if (o >= 512) return;
    float s = 0.f;
    for (int c = 0; c < 512; c++) s += w[(long long)o * 1024 + 512 + c] * g[b * 512 + c];
    b2[b * 512 + o] = s;
}

extern "C" void kernel_launch(void* const* d_in, const int* in_sizes, int n_in,
                              void* d_out, int out_size, void* d_ws, size_t ws_size,
                              hipStream_t stream)
{
    const float* x       = (const float*)d_in[0];
    const float* conv1_w = (const float*)d_in[1];
    const float* bn1_g   = (const float*)d_in[2];
    const float* bn1_b   = (const float*)d_in[3];
    const float* conv2_w = (const float*)d_in[4];
    const float* bn2_g   = (const float*)d_in[5];
    const float* bn2_b   = (const float*)d_in[6];
    const float* conv3_w = (const float*)d_in[7];
    const float* bn3_g   = (const float*)d_in[8];
    const float* bn3_b   = (const float*)d_in[9];
    const float* pt1_w   = (const float*)d_in[10];
    const float* pt1_g   = (const float*)d_in[11];
    const float* pt1_b   = (const float*)d_in[12];
    const float* pt2_w   = (const float*)d_in[13];
    const float* pt2_g   = (const float*)d_in[14];
    const float* pt2_b   = (const float*)d_in[15];
    const float* sa_qk[2] = {(const float*)d_in[16], (const float*)d_in[23]};
    const float* sa_vw[2] = {(const float*)d_in[17], (const float*)d_in[24]};
    const float* sa_vb[2] = {(const float*)d_in[18], (const float*)d_in[25]};
    const float* sa_tw[2] = {(const float*)d_in[19], (const float*)d_in[26]};
    const float* sa_tb[2] = {(const float*)d_in[20], (const float*)d_in[27]};
    const float* sa_g[2]  = {(const float*)d_in[21], (const float*)d_in[28]};
    const float* sa_b[2]  = {(const float*)d_in[22], (const float*)d_in[29]};
    const float* cf_w = (const float*)d_in[30];
    const float* cf_g = (const float*)d_in[31];
    const float* cf_b = (const float*)d_in[32];
    const float* s1_w = (const float*)d_in[33];
    const float* s1_g = (const float*)d_in[34];
    const float* s1_b = (const float*)d_in[35];
    const float* s2_w = (const float*)d_in[36];
    const float* s2_g = (const float*)d_in[37];
    const float* s2_b = (const float*)d_in[38];
    const float* s3_w = (const float*)d_in[39];

    char* base = (char*)d_ws;
    size_t off = 0;
    auto alloc = [&](size_t bytes) -> void* {
        void* p = base + off;
        off = (off + bytes + 255) & ~(size_t)255;
        return p;
    };
    const long long N = NPTS;
    const long long PO64   = (long long)BATCH * N * 64;
    const long long PO128  = (long long)BATCH * N * 128;
    const long long PO256  = (long long)BATCH * N * 256;
    const long long PO512  = (long long)BATCH * N * 512;
    const long long PO1024 = (long long)BATCH * N * 1024;

    unsigned short* S1  = (unsigned short*)alloc(2 * PO256 * 2);
    unsigned short* S2  = (unsigned short*)alloc(2 * PO256 * 2);
    unsigned short* Dv  = (unsigned short*)alloc(2 * PO256 * 2);
    unsigned short* cat = (unsigned short*)alloc(2 * PO1024 * 2);
    unsigned short* face = (unsigned short*)alloc(2 * PO512 * 2);
    unsigned short* xq  = (unsigned short*)alloc((size_t)BATCH * N * 128 * 2);
    unsigned short* xv  = (unsigned short*)alloc((size_t)BATCH * 256 * N * 2);
    unsigned short* s1b = (unsigned short*)alloc(2 * PO512 * 2);
    unsigned short* s2b = (unsigned short*)alloc(2 * PO256 * 2);
    float* part = (float*)alloc((size_t)BATCH * MSPLIT * N * 256 * 4);          // 32 MB
    float* csp  = (float*)alloc((size_t)BATCH * MSPLIT * N * 4);
    float* rs = (float*)alloc((size_t)BATCH * N * 4);
    float* pm = (float*)alloc((size_t)BATCH * 64 * 512 * 4);
    float* gm = (float*)alloc((size_t)BATCH * 512 * 4);
    float* b2 = (float*)alloc((size_t)BATCH * 512 * 4);
    unsigned short* wb = (unsigned short*)alloc((size_t)3400000 * 2);  // pre-split weights

    // ---- weight pre-split table ----
    WSplit wd;
    const float* wsrc[14] = {conv2_w, conv3_w, pt1_w, pt2_w, sa_qk[0], sa_qk[1],
                             sa_vw[0], sa_vw[1], sa_tw[0], sa_tw[1], cf_w, s1_w, s2_w, s3_w};
    int wn[14] = {128*64, 256*128, 256*256, 256*256, 128*256, 128*256,
                  256*256, 256*256, 256*256, 256*256, 512*1024, 512*1024, 256*512, 50*256};
    long long wo[14]; long long acc_ = 0;
    for (int i = 0; i < 14; i++) { wd.src[i] = wsrc[i]; wd.n[i] = wn[i]; wd.off[i] = acc_; wo[i] = acc_; acc_ += 2LL * wn[i]; }
    presplit_k<<<dim3((512*1024 + 255) / 256, 14), 256, 0, stream>>>(wd, wb);
    auto W = [&](int i) { return wb + wo[i]; };

    auto nt = [&](const unsigned short* A, long long a_bs, int a_lda, long long a_po,
                  const unsigned short* B, long long b_bs, int b_lda, long long b_po,
                  void* C, long long c_bs, int c_ld, long long c_po,
                  int Mrows, int Nb, int K,
                  const float* bias, int bias_mode,
                  const float* bng, const float* bnb,
                  const unsigned short* res, long long res_bs, int res_ld, long long res_po,
                  int act, int out_mode) {
        dim3 g((Nb + 63) / 64, Mrows / 64, BATCH);
        gemm_nt_split<<<g, 256, 0, stream>>>(A, a_bs, a_lda, a_po, B, b_bs, b_lda, b_po,
                                             C, c_bs, c_ld, c_po, Nb, K,
                                             bias, bias_mode, bng, bnb,
                                             res, res_bs, res_ld, res_po, act, out_mode);
    };
    auto ntB = [&](const unsigned short* A, long long a_bs, int a_lda, long long a_po,
                   const unsigned short* B, long long b_bs, int b_lda, long long b_po,
                   void* C, long long c_bs, int c_ld, long long c_po,
                   int Mrows, int Nb, int K,
                   const float* bias, int bias_mode,
                   const float* bng, const float* bnb,
                   const unsigned short* res, long long res_bs, int res_ld, long long res_po,
                   int act, int out_mode) {
        dim3 g((Nb + 63) / 64, Mrows / 64, BATCH);
        gemm_nt_splitB<<<g, 256, 0, stream>>>(A, a_bs, a_lda, a_po, B, b_bs, b_lda, b_po,
                                              C, c_bs, c_ld, c_po, Nb, K,
                                              bias, bias_mode, bng, bnb,
                                              res, res_bs, res_ld, res_po, act, out_mode);
    };
    auto nt3 = [&](const unsigned short* A, long long a_bs, int a_lda, long long a_po,
                   const unsigned short* B, long long b_bs, int b_lda, long long b_po,
                   void* C, long long c_bs, int c_ld, long long c_po,
                   int Mrows, int Nb, int K,
                   const float* bias, int bias_mode,
                   const float* bng, const float* bnb,
                   const unsigned short* res, long long res_bs, int res_ld, long long res_po,
                   int act, int out_mode) {
        dim3 g((Nb + 63) / 64, Mrows / 128, BATCH);
        gemm_nt_split3<<<g, 256, 0, stream>>>(A, a_bs, a_lda, a_po, B, b_bs, b_lda, b_po,
                                              C, c_bs, c_ld, c_po, Nb, K,
                                              bias, bias_mode, bng, bnb,
                                              res, res_bs, res_ld, res_po, act, out_mode);
    };

    // ---- stem ----
    conv1_k<<<dim3(NPTS / 4, BATCH), 256, 0, stream>>>(x, conv1_w, bn1_g, bn1_b, S1, PO64);
    nt(S1, N * 64, 64, PO64,    W(0), 0, 64, wn[0],  S2, N * 128, 128, PO128,
       NPTS, 128, 64,  nullptr, 0, bn2_g, bn2_b, nullptr, 0, 0, 0, 1, 0);
    ntB(S2, N * 128, 128, PO128, W(1), 0, 128, wn[1], S1, N * 256, 256, PO256,
        NPTS, 256, 128, nullptr, 0, bn3_g, bn3_b, nullptr, 0, 0, 0, 1, 0);
    ntB(S1, N * 256, 256, PO256, W(2), 0, 256, wn[2], S2, N * 256, 256, PO256,
        NPTS, 256, 256, nullptr, 0, pt1_g, pt1_b, nullptr, 0, 0, 0, 1, 0);
    ntB(S2, N * 256, 256, PO256, W(3), 0, 256, wn[3], S1, N * 256, 256, PO256,
        NPTS, 256, 256, nullptr, 0, pt2_g, pt2_b, nullptr, 0, 0, 0, 1, 0);

    // ---- 4 SA layers ----
    for (int i = 0; i < 4; i++) {
        int p = (i == 0) ? 0 : 1;
        const unsigned short* xin = (i == 0) ? S1 : cat + (size_t)(i - 1) * 256;
        long long xin_bs = (i == 0) ? N * 256 : N * 1024;
        int xin_ld = (i == 0) ? 256 : 1024;
        long long xin_po = (i == 0) ? PO256 : PO1024;

        // xq[n][128] plain bf16 (K=256)
        ntB(xin, xin_bs, xin_ld, xin_po, W(4 + p), 0, 256, wn[4 + p],
            xq, N * 128, 128, 0, NPTS, 128, 256,
            nullptr, 0, nullptr, nullptr, nullptr, 0, 0, 0, 0, 1);
        // xv[c][n] plain bf16 (A = weights, K=256)
        ntB(W(6 + p), 0, 256, wn[6 + p], xin, xin_bs, xin_ld, xin_po,
            xv, 256 * N, NPTS, 0, 256, NPTS, 256,
            sa_vb[p], 3, nullptr, nullptr, nullptr, 0, 0, 0, 0, 1);
        // zero rs (needed for rs_k atomics)
        zero_k<<<(BATCH * NPTS + 255) / 256, 256, 0, stream>>>(rs, BATCH * NPTS);
        // E1: rs row-sums (no att store)
        rs_k<<<dim3(RSSPLIT, NPTS / 64, BATCH), 256, 0, stream>>>(xq, rs);
        // E2: fused QK->exp/rs->PV partials + cs partials
        attn_pv<<<dim3(1, NPTS / 64, BATCH * MSPLIT), 256, 0, stream>>>(
            xq, xv, rs, part, csp);
        // d = x - (sum partials)/(1e-9 + sum cs partials)
        diff_k<<<dim3(NPTS * 256 / 1024, BATCH), 256, 0, stream>>>(
            xin, xin_bs, xin_ld, xin_po, part, csp, Dv, PO256);
        // x_out = x + relu(bn(tw@d + tb)) -> cat slice i (K=256)
        ntB(Dv, N * 256, 256, PO256, W(8 + p), 0, 256, wn[8 + p],
            cat + (size_t)i * 256, N * 1024, 1024, PO1024,
            NPTS, 256, 256, sa_tb[p], 1, sa_g[p], sa_b[p],
            xin, xin_bs, xin_ld, xin_po, 1, 0);
    }

    // ---- head ----
    nt3(cat, N * 1024, 1024, PO1024, W(10), 0, 1024, wn[10],
        face, N * 512, 512, PO512, NPTS, 512, 1024,
        nullptr, 0, cf_g, cf_b, nullptr, 0, 0, 0, 2, 0);
    gmaxp_k<<<dim3(4, 16, BATCH), 256, 0, stream>>>(face, PO512, pm);
    gmaxr_k<<<dim3(BATCH * 512 / 256), 256, 0, stream>>>(pm, gm);
    bias2_k<<<dim3(2, BATCH), 256, 0, stream>>>(s1_w, gm, b2);
    nt3(face, N * 512, 512, PO512, W(11), 0, 1024, wn[11],
        s1b, N * 512, 512, PO512, NPTS, 512, 512,
        b2, 2, s1_g, s1_b, nullptr, 0, 0, 0, 2, 0);
    ntB(s1b, N * 512, 512, PO512, W(12), 0, 512, wn[12],
        s2b, N * 256, 256, PO256, NPTS, 256, 512,
        nullptr, 0, s2_g, s2_b, nullptr, 0, 0, 0, 2, 0);
    ntB(s2b, N * 256, 256, PO256, W(13), 0, 256, wn[13],
        d_out, N * 50, 50, 0, NPTS, 50, 256,
        nullptr, 0, nullptr, nullptr, nullptr, 0, 0, 0, 0, 2);
}

// Round 8
// 721.919 us; speedup vs baseline: 1.4642x; 1.0109x over previous
//
#include <hip/hip_runtime.h>
#include <hip/hip_bf16.h>

// PCT segmentation forward. R25 = R24 (729.8us) + three exact cleanups:
// - attn_pv Pl XOR-swizzle: Pl[64][72] pad -> Pl[64][64] with column-block
//   swizzle col' = ((M>>3) ^ ((P>>1)&7))*8 + (M&7). Kills the ~4-way bank
//   conflict on the 16 scalar u16 P'-writes/thread/iter (SQ_LDS_BANK_CONFLICT
//   was 2^20/dispatch): write banks now 8(jt^q)+4(mh^rho)+(ml&7)>>1 = 32
//   distinct, 2 lanes each (free). Read fetches blk (4kk+q)^((ml>>1)&7) —
//   bijective, aligned, uniform residues. Bit-exact. LDS 73 -> 72.2 KB.
// - rs: 4 per-layer buffers, ONE zero_k for all (was 4 launches).
// - gmaxr_k fused into bias2_k (gm only fed bias2). 56 -> 52 dispatches.
// Base: R24 attn pipeline (Kq dbuf, 2 barriers/iter), K3 cf/s1, XCD swizzle,
// vectorized gmaxp/diff, rs_k 1-barrier pipeline.

#define NPTS 4096
#define BATCH 2
#define MSPLIT 4
#define RSSPLIT 8
static constexpr float INV_STD = 0.9999950000374997f;  // 1/sqrt(1+1e-5)

__device__ __forceinline__ float bf2f(unsigned short u) {
    return __uint_as_float(((unsigned int)u) << 16);
}
__device__ __forceinline__ unsigned short f2bf(float f) {
    unsigned int x = __float_as_uint(f);
    unsigned int r = (x + 0x7FFFu + ((x >> 16) & 1u)) >> 16;
    return (unsigned short)r;
}

// async global->LDS 16B DMA: LDS base wave-uniform; HW writes lptr+lane*16.
__device__ __forceinline__ void async16(const unsigned short* g, unsigned short* l)
{
    __builtin_amdgcn_global_load_lds(
        (const __attribute__((address_space(1))) unsigned int*)(const void*)g,
        (__attribute__((address_space(3))) unsigned int*)(void*)l,
        16, 0, 0);
}

typedef __attribute__((ext_vector_type(8))) short short8;
typedef __attribute__((ext_vector_type(4))) short s16x4;
typedef __attribute__((ext_vector_type(4))) float f32x4;

// ---------------- weight pre-split ----------------
struct WSplit {
    const float* src[14];
    int n[14];
    long long off[14];   // ushort offset of hi plane; lo at off+n
};

__global__ __launch_bounds__(256)
void presplit_k(WSplit d, unsigned short* __restrict__ wbuf)
{
    int wi = blockIdx.y;
    int i = blockIdx.x * 256 + threadIdx.x;
    int n = d.n[wi];
    if (i >= n) return;
    float v = d.src[wi][i];
    unsigned short h = f2bf(v);
    unsigned short* dst = wbuf + d.off[wi];
    dst[i] = h;
    dst[n + i] = f2bf(v - bf2f(h));
}

// shared epilogue
__device__ __forceinline__ void nt_epilogue(
    float y, int rg, int cg, int b, int Nb,
    const float* bias, int bias_mode,
    const float* bng, const float* bnb,
    const unsigned short* res, long long res_bs, int res_ld, long long res_po,
    int act, int out_mode,
    void* Cp, long long c_bs, int c_ld, long long c_po)
{
    if (bias) {
        if (bias_mode == 3)      y += bias[rg];
        else if (bias_mode == 2) y += bias[b * Nb + cg];
        else                     y += bias[cg];
    }
    if (bng) y = y * (INV_STD * bng[cg]) + bnb[cg];
    if (act == 1) y = fmaxf(y, 0.f);
    else if (act == 2) y = (y > 0.f) ? y : 0.2f * y;
    if (res) {
        long long ri_ = (long long)b * res_bs + (long long)rg * res_ld + cg;
        y += bf2f(res[ri_]) + bf2f(res[res_po + ri_]);
    }
    long long ci = (long long)b * c_bs + (long long)rg * c_ld + cg;
    if (out_mode == 0) {
        unsigned short* C = (unsigned short*)Cp;
        unsigned short h = f2bf(y);
        C[ci] = h;
        C[c_po + ci] = f2bf(y - bf2f(h));
    } else if (out_mode == 1) {
        ((unsigned short*)Cp)[ci] = f2bf(y);
    } else {
        if (cg < Nb) ((float*)Cp)[ci] = y;
    }
}

// ---------------- K1: split-bf16 NT GEMM, 64x64 tile, BK=64 ----------------
__global__ __launch_bounds__(256)
void gemm_nt_split(const unsigned short* __restrict__ A, long long a_bs, int a_lda, long long a_po,
                   const unsigned short* __restrict__ B, long long b_bs, int b_lda, long long b_po,
                   void* __restrict__ Cp, long long c_bs, int c_ld, long long c_po,
                   int Nb, int K,
                   const float* __restrict__ bias, int bias_mode,
                   const float* __restrict__ bng, const float* __restrict__ bnb,
                   const unsigned short* __restrict__ res, long long res_bs, int res_ld, long long res_po,
                   int act, int out_mode)
{
    __shared__ unsigned short As[2][64 * 64];
    __shared__ unsigned short Bs[2][64 * 64];
    const int gx = gridDim.x, gy = gridDim.y;
    const int nblk = gx * gy * (int)gridDim.z;
    int d_ = blockIdx.x + gx * (blockIdx.y + gy * blockIdx.z);
    int w_ = (nblk & 7) ? d_ : ((d_ & 7) * (nblk >> 3) + (d_ >> 3));
    const int b = w_ / (gx * gy);
    const int rem_ = w_ % (gx * gy);
    const int m0 = (rem_ / gx) * 64, n0 = (rem_ % gx) * 64;
    const int t = threadIdx.x;
    const int lane = t & 63, w = t >> 6;
    const int wr = (w >> 1) * 32, wc = (w & 1) * 32;
    const int ml = lane & 15, q = lane >> 4;

    f32x4 acc[2][2] = {};

    for (int k0 = 0; k0 < K; k0 += 64) {
        __syncthreads();
        #pragma unroll
        for (int e = 0; e < 2; e++) {
            int idx = t + e * 256;
            int row = idx >> 3, blk = idx & 7;
            int gblk = blk ^ (row & 7);
            int lofs = (e * 256 + (t & 192)) * 8;
            const unsigned short* sA = A + (long long)b * a_bs
                                     + (long long)(m0 + row) * a_lda + k0 + gblk * 8;
            const unsigned short* sB = B + (long long)b * b_bs
                                     + (long long)(n0 + row) * b_lda + k0 + gblk * 8;
            async16(sA,        &As[0][0] + lofs);
            async16(sA + a_po, &As[1][0] + lofs);
            async16(sB,        &Bs[0][0] + lofs);
            async16(sB + b_po, &Bs[1][0] + lofs);
        }
        __syncthreads();
        #pragma unroll
        for (int kk = 0; kk < 2; kk++) {
            short8 ah[2], al[2], bh[2], bl[2];
            #pragma unroll
            for (int it = 0; it < 2; it++) {
                int row = wr + it * 16 + ml;
                int slot = (kk * 4 + q) ^ (row & 7);
                ah[it] = *(const short8*)(&As[0][row * 64 + slot * 8]);
                al[it] = *(const short8*)(&As[1][row * 64 + slot * 8]);
            }
            #pragma unroll
            for (int jt = 0; jt < 2; jt++) {
                int row = wc + jt * 16 + ml;
                int slot = (kk * 4 + q) ^ (row & 7);
                bh[jt] = *(const short8*)(&Bs[0][row * 64 + slot * 8]);
                bl[jt] = *(const short8*)(&Bs[1][row * 64 + slot * 8]);
            }
            #pragma unroll
            for (int it = 0; it < 2; it++)
                #pragma unroll
                for (int jt = 0; jt < 2; jt++) {
                    acc[it][jt] = __builtin_amdgcn_mfma_f32_16x16x32_bf16(ah[it], bh[jt], acc[it][jt], 0, 0, 0);
                    acc[it][jt] = __builtin_amdgcn_mfma_f32_16x16x32_bf16(ah[it], bl[jt], acc[it][jt], 0, 0, 0);
                    acc[it][jt] = __builtin_amdgcn_mfma_f32_16x16x32_bf16(al[it], bh[jt], acc[it][jt], 0, 0, 0);
                }
        }
    }

    #pragma unroll
    for (int it = 0; it < 2; it++)
        #pragma unroll
        for (int jt = 0; jt < 2; jt++)
            #pragma unroll
            for (int r = 0; r < 4; r++)
                nt_epilogue(acc[it][jt][r], m0 + wr + it * 16 + q * 4 + r,
                            n0 + wc + jt * 16 + ml, b, Nb,
                            bias, bias_mode, bng, bnb, res, res_bs, res_ld, res_po,
                            act, out_mode, Cp, c_bs, c_ld, c_po);
}

// ---------------- K1B: split-bf16 NT GEMM, 64x64 tile, BK=128 ----------------
__global__ __launch_bounds__(256)
void gemm_nt_splitB(const unsigned short* __restrict__ A, long long a_bs, int a_lda, long long a_po,
                    const unsigned short* __restrict__ B, long long b_bs, int b_lda, long long b_po,
                    void* __restrict__ Cp, long long c_bs, int c_ld, long long c_po,
                    int Nb, int K,
                    const float* __restrict__ bias, int bias_mode,
                    const float* __restrict__ bng, const float* __restrict__ bnb,
                    const unsigned short* __restrict__ res, long long res_bs, int res_ld, long long res_po,
                    int act, int out_mode)
{
    __shared__ unsigned short As[2][2][64 * 64];   // [plane][sub] 32 KB
    __shared__ unsigned short Bs[2][2][64 * 64];   // 32 KB
    const int gx = gridDim.x, gy = gridDim.y;
    const int nblk = gx * gy * (int)gridDim.z;
    int d_ = blockIdx.x + gx * (blockIdx.y + gy * blockIdx.z);
    int w_ = (nblk & 7) ? d_ : ((d_ & 7) * (nblk >> 3) + (d_ >> 3));
    const int b = w_ / (gx * gy);
    const int rem_ = w_ % (gx * gy);
    const int m0 = (rem_ / gx) * 64, n0 = (rem_ % gx) * 64;
    const int t = threadIdx.x;
    const int lane = t & 63, w = t >> 6;
    const int wr = (w >> 1) * 32, wc = (w & 1) * 32;
    const int ml = lane & 15, q = lane >> 4;

    f32x4 acc[2][2] = {};

    for (int k0 = 0; k0 < K; k0 += 128) {
        __syncthreads();
        #pragma unroll
        for (int sub = 0; sub < 2; sub++) {
            int kb = k0 + sub * 64;
            #pragma unroll
            for (int e = 0; e < 2; e++) {
                int idx = t + e * 256;
                int row = idx >> 3, blk = idx & 7;
                int gblk = blk ^ (row & 7);
                int lofs = (e * 256 + (t & 192)) * 8;
                const unsigned short* sA = A + (long long)b * a_bs
                                         + (long long)(m0 + row) * a_lda + kb + gblk * 8;
                const unsigned short* sB = B + (long long)b * b_bs
                                         + (long long)(n0 + row) * b_lda + kb + gblk * 8;
                async16(sA,        &As[0][sub][0] + lofs);
                async16(sA + a_po, &As[1][sub][0] + lofs);
                async16(sB,        &Bs[0][sub][0] + lofs);
                async16(sB + b_po, &Bs[1][sub][0] + lofs);
            }
        }
        __syncthreads();
        #pragma unroll
        for (int sub = 0; sub < 2; sub++)
            #pragma unroll
            for (int kk = 0; kk < 2; kk++) {
                short8 ah[2], al[2], bh[2], bl[2];
                #pragma unroll
                for (int it = 0; it < 2; it++) {
                    int row = wr + it * 16 + ml;
                    int slot = (kk * 4 + q) ^ (row & 7);
                    ah[it] = *(const short8*)(&As[0][sub][row * 64 + slot * 8]);
                    al[it] = *(const short8*)(&As[1][sub][row * 64 + slot * 8]);
                }
                #pragma unroll
                for (int jt = 0; jt < 2; jt++) {
                    int row = wc + jt * 16 + ml;
                    int slot = (kk * 4 + q) ^ (row & 7);
                    bh[jt] = *(const short8*)(&Bs[0][sub][row * 64 + slot * 8]);
                    bl[jt] = *(const short8*)(&Bs[1][sub][row * 64 + slot * 8]);
                }
                #pragma unroll
                for (int it = 0; it < 2; it++)
                    #pragma unroll
                    for (int jt = 0; jt < 2; jt++) {
                        acc[it][jt] = __builtin_amdgcn_mfma_f32_16x16x32_bf16(ah[it], bh[jt], acc[it][jt], 0, 0, 0);
                        acc[it][jt] = __builtin_amdgcn_mfma_f32_16x16x32_bf16(ah[it], bl[jt], acc[it][jt], 0, 0, 0);
                        acc[it][jt] = __builtin_amdgcn_mfma_f32_16x16x32_bf16(al[it], bh[jt], acc[it][jt], 0, 0, 0);
                    }
            }
    }

    #pragma unroll
    for (int it = 0; it < 2; it++)
        #pragma unroll
        for (int jt = 0; jt < 2; jt++)
            #pragma unroll
            for (int r = 0; r < 4; r++)
                nt_epilogue(acc[it][jt][r], m0 + wr + it * 16 + q * 4 + r,
                            n0 + wc + jt * 16 + ml, b, Nb,
                            bias, bias_mode, bng, bnb, res, res_bs, res_ld, res_po,
                            act, out_mode, Cp, c_bs, c_ld, c_po);
}

// ---------------- K3: split-bf16 NT GEMM, 128x64 tile, BK=64 ----------------
__global__ __launch_bounds__(256)
void gemm_nt_split3(const unsigned short* __restrict__ A, long long a_bs, int a_lda, long long a_po,
                    const unsigned short* __restrict__ B, long long b_bs, int b_lda, long long b_po,
                    void* __restrict__ Cp, long long c_bs, int c_ld, long long c_po,
                    int Nb, int K,
                    const float* __restrict__ bias, int bias_mode,
                    const float* __restrict__ bng, const float* __restrict__ bnb,
                    const unsigned short* __restrict__ res, long long res_bs, int res_ld, long long res_po,
                    int act, int out_mode)
{
    __shared__ unsigned short As[2][128 * 64];   // 32 KB (hi+lo)
    __shared__ unsigned short Bs[2][64 * 64];    // 16 KB
    const int gx = gridDim.x, gy = gridDim.y;
    const int nblk = gx * gy * (int)gridDim.z;
    int d_ = blockIdx.x + gx * (blockIdx.y + gy * blockIdx.z);
    int w_ = (nblk & 7) ? d_ : ((d_ & 7) * (nblk >> 3) + (d_ >> 3));
    const int b = w_ / (gx * gy);
    const int rem_ = w_ % (gx * gy);
    const int m0 = (rem_ / gx) * 128, n0 = (rem_ % gx) * 64;
    const int t = threadIdx.x;
    const int lane = t & 63, w = t >> 6;
    const int wr = (w >> 1) * 64, wc = (w & 1) * 32;
    const int ml = lane & 15, q = lane >> 4;

    f32x4 acc[4][2] = {};

    for (int k0 = 0; k0 < K; k0 += 64) {
        __syncthreads();
        #pragma unroll
        for (int e = 0; e < 4; e++) {            // A: 128 rows
            int idx = t + e * 256;
            int row = idx >> 3, blk = idx & 7;
            int gblk = blk ^ (row & 7);
            int lofs = (e * 256 + (t & 192)) * 8;
            const unsigned short* sA = A + (long long)b * a_bs
                                     + (long long)(m0 + row) * a_lda + k0 + gblk * 8;
            async16(sA,        &As[0][0] + lofs);
            async16(sA + a_po, &As[1][0] + lofs);
        }
        #pragma unroll
        for (int e = 0; e < 2; e++) {            // B: 64 rows
            int idx = t + e * 256;
            int row = idx >> 3, blk = idx & 7;
            int gblk = blk ^ (row & 7);
            int lofs = (e * 256 + (t & 192)) * 8;
            const unsigned short* sB = B + (long long)b * b_bs
                                     + (long long)(n0 + row) * b_lda + k0 + gblk * 8;
            async16(sB,        &Bs[0][0] + lofs);
            async16(sB + b_po, &Bs[1][0] + lofs);
        }
        __syncthreads();
        #pragma unroll
        for (int kk = 0; kk < 2; kk++) {
            short8 ah[4], al[4], bh[2], bl[2];
            #pragma unroll
            for (int it = 0; it < 4; it++) {
                int row = wr + it * 16 + ml;
                int slot = (kk * 4 + q) ^ (row & 7);
                ah[it] = *(const short8*)(&As[0][row * 64 + slot * 8]);
                al[it] = *(const short8*)(&As[1][row * 64 + slot * 8]);
            }
            #pragma unroll
            for (int jt = 0; jt < 2; jt++) {
                int row = wc + jt * 16 + ml;
                int slot = (kk * 4 + q) ^ (row & 7);
                bh[jt] = *(const short8*)(&Bs[0][row * 64 + slot * 8]);
                bl[jt] = *(const short8*)(&Bs[1][row * 64 + slot * 8]);
            }
            #pragma unroll
            for (int it = 0; it < 4; it++)
                #pragma unroll
                for (int jt = 0; jt < 2; jt++) {
                    acc[it][jt] = __builtin_amdgcn_mfma_f32_16x16x32_bf16(ah[it], bh[jt], acc[it][jt], 0, 0, 0);
                    acc[it][jt] = __builtin_amdgcn_mfma_f32_16x16x32_bf16(ah[it], bl[jt], acc[it][jt], 0, 0, 0);
                    acc[it][jt] = __builtin_amdgcn_mfma_f32_16x16x32_bf16(al[it], bh[jt], acc[it][jt], 0, 0, 0);
                }
        }
    }

    #pragma unroll
    for (int it = 0; it < 4; it++)
        #pragma unroll
        for (int jt = 0; jt < 2; jt++)
            #pragma unroll
            for (int r = 0; r < 4; r++)
                nt_epilogue(acc[it][jt][r], m0 + wr + it * 16 + q * 4 + r,
                            n0 + wc + jt * 16 + ml, b, Nb,
                            bias, bias_mode, bng, bnb, res, res_bs, res_ld, res_po,
                            act, out_mode, Cp, c_bs, c_ld, c_po);
}

// ---------------- E1: rs[p] = sum_m exp(e[p][m]), atomic row-sums ----------------
__global__ __launch_bounds__(256)
void rs_k(const unsigned short* __restrict__ xq, float* __restrict__ rs)
{
    __shared__ unsigned short Kq[2][2][64 * 64];   // [dbuf][half] 32 KB
    int d_ = blockIdx.x + 8 * (blockIdx.y + 64 * blockIdx.z);
    int w_ = (d_ & 7) * 128 + (d_ >> 3);
    const int p0 = (w_ % 64) * 64;
    const int xseg = (w_ / 64) % 8;
    const int b = w_ / 512;
    const int m_beg = xseg * (NPTS / RSSPLIT);
    const unsigned short* xqB = xq + (long long)b * NPTS * 128;
    const int t = threadIdx.x;
    const int lane = t & 63, w = t >> 6;
    const int pw = w * 16;
    const int ml = lane & 15, q = lane >> 4;

    short8 af[4];
    #pragma unroll
    for (int ks = 0; ks < 4; ks++)
        af[ks] = *(const short8*)(xqB + (long long)(p0 + pw + ml) * 128 + ks * 32 + q * 8);

    float rsum[4] = {0.f, 0.f, 0.f, 0.f};

    auto stageK = [&](int m0, int buf) {
        #pragma unroll
        for (int e = 0; e < 4; e++) {
            int idx = t + e * 256;
            int sub = idx >> 9, row = (idx >> 3) & 63, blk = idx & 7;
            int gblk = blk ^ (row & 7);
            int lofs = (e * 256 + (t & 192)) * 8;
            async16(xqB + (long long)(m0 + row) * 128 + sub * 64 + gblk * 8,
                    &Kq[buf][0][0] + lofs);
        }
    };

    constexpr int NIT = (NPTS / RSSPLIT) / 64;
    stageK(m_beg, 0);
    __syncthreads();

    for (int it = 0; it < NIT; ++it) {
        const int m0 = m_beg + it * 64;
        const int cur = it & 1;
        if (it + 1 < NIT) stageK(m0 + 64, cur ^ 1);
        f32x4 acc[4] = {};
        #pragma unroll
        for (int ks = 0; ks < 4; ks++) {
            int kh = ks >> 1, kk = ks & 1;
            #pragma unroll
            for (int jt = 0; jt < 4; jt++) {
                int row = jt * 16 + ml;
                int slot = (kk * 4 + q) ^ (row & 7);
                short8 bf = *(const short8*)(&Kq[cur][kh][row * 64 + slot * 8]);
                acc[jt] = __builtin_amdgcn_mfma_f32_16x16x32_bf16(af[ks], bf, acc[jt], 0, 0, 0);
            }
        }
        #pragma unroll
        for (int jt = 0; jt < 4; jt++)
            #pragma unroll
            for (int r = 0; r < 4; r++)
                rsum[r] += __expf(acc[jt][r]);
        __syncthreads();   // drains next-iter staging; protects Kq[cur] overwrite
    }
    #pragma unroll
    for (int r = 0; r < 4; r++) {
        float s = rsum[r];
        s += __shfl_xor(s, 1); s += __shfl_xor(s, 2);
        s += __shfl_xor(s, 4); s += __shfl_xor(s, 8);
        if (ml == 0) atomicAdd(&rs[b * NPTS + p0 + pw + q * 4 + r], s);
    }
}

// ---------------- E2: QK -> exp/rs[m] -> PV partials + cs partials ----------------
// R24 pipeline (Kq dbuf, 2 barriers/iter) + Pl XOR-swizzled [64][64]:
// element (P, M) stored at col ((M>>3) ^ ((P>>1)&7))*8 + (M&7).
__global__ __launch_bounds__(256)
void attn_pv(const unsigned short* __restrict__ xq,   // [B][N][128]
             const unsigned short* __restrict__ xv,   // [B][256][N]
             const float* __restrict__ rs,
             float* __restrict__ part,                // [B*MSPLIT][N][256]
             float* __restrict__ csp)                 // [B*MSPLIT][N]
{
    __shared__ unsigned short Kq[2][2][64 * 64];   // [dbuf][half] 32 KB
    __shared__ unsigned short Vv[256 * 64];        // 32 KB
    __shared__ unsigned short Pl[64][64];          // 8 KB (XOR-swizzled cols)
    int d_ = blockIdx.y + 64 * blockIdx.z;
    int w_ = (d_ & 7) * 64 + (d_ >> 3);
    const int p0 = (w_ % 64) * 64;
    const int z = w_ / 64;
    const int b = z / MSPLIT, ms = z % MSPLIT;
    const unsigned short* xqB = xq + (long long)b * NPTS * 128;
    const unsigned short* xvB = xv + (long long)b * 256 * NPTS;
    const float* rsB = rs + b * NPTS;
    const int t = threadIdx.x;
    const int lane = t & 63, w = t >> 6;
    const int pw = w * 16;                      // QK p-strip
    const int cw = w * 64;                      // PV c-strip
    const int ml = lane & 15, q = lane >> 4;

    short8 af[4];
    #pragma unroll
    for (int ks = 0; ks < 4; ks++)
        af[ks] = *(const short8*)(xqB + (long long)(p0 + pw + ml) * 128 + ks * 32 + q * 8);

    f32x4 pv[4][4] = {};                        // [p-tile][c-tile]
    float csr[4] = {0.f, 0.f, 0.f, 0.f};

    auto stageK = [&](int m0, int buf) {
        #pragma unroll
        for (int e = 0; e < 4; e++) {
            int idx = t + e * 256;
            int sub = idx >> 9, row = (idx >> 3) & 63, blk = idx & 7;
            int gblk = blk ^ (row & 7);
            int lofs = (e * 256 + (t & 192)) * 8;
            async16(xqB + (long long)(m0 + row) * 128 + sub * 64 + gblk * 8,
                    &Kq[buf][0][0] + lofs);
        }
    };
    auto stageV = [&](int m0) {
        #pragma unroll
        for (int e = 0; e < 8; e++) {
            int idx = t + e * 256;
            int row = idx >> 3, blk = idx & 7;
            int gblk = blk ^ (row & 7);
            int lofs = (e * 256 + (t & 192)) * 8;
            async16(xvB + (long long)row * NPTS + m0 + gblk * 8, Vv + lofs);
        }
    };

    const int m_beg = ms * (NPTS / MSPLIT);
    constexpr int NIT = (NPTS / MSPLIT) / 64;
    stageK(m_beg, 0);
    __syncthreads();   // Kq(0) resident + fenced (vmcnt0 + barrier)

    for (int it = 0; it < NIT; ++it) {
        const int m0 = m_beg + it * 64;
        const int cur = it & 1;
        __syncthreads();   // A: PV(it-1) done -> Vv/Pl free
        stageV(m0);                              // 8 DMA (drained at B)
        if (it + 1 < NIT) stageK(m0 + 64, cur ^ 1);  // 4 DMA (fenced at B)
        // QK from Kq[cur] — already resident; no barrier needed here.
        f32x4 acc[4] = {};
        #pragma unroll
        for (int ks = 0; ks < 4; ks++) {
            int kh = ks >> 1, kk = ks & 1;
            #pragma unroll
            for (int jt = 0; jt < 4; jt++) {
                int row = jt * 16 + ml;
                int slot = (kk * 4 + q) ^ (row & 7);
                short8 bf = *(const short8*)(&Kq[cur][kh][row * 64 + slot * 8]);
                acc[jt] = __builtin_amdgcn_mfma_f32_16x16x32_bf16(af[ks], bf, acc[jt], 0, 0, 0);
            }
        }
        // P' = exp(e)/rs[m]; swizzled Pl write (conflict-free: 32 banks, 2 lanes)
        #pragma unroll
        for (int jt = 0; jt < 4; jt++) {
            float rvm = 1.f / rsB[m0 + jt * 16 + ml];
            #pragma unroll
            for (int r = 0; r < 4; r++) {
                float pvv = __expf(acc[jt][r]) * rvm;
                csr[r] += pvv;
                int cs_ = ((2 * jt + (ml >> 3)) ^ ((2 * q + (r >> 1)) & 7)) * 8 + (ml & 7);
                Pl[pw + q * 4 + r][cs_] = f2bf(pvv);
            }
        }
        __syncthreads();   // B: vmcnt(0) drains Vv(it)+Kq(it+1); Pl visible
        // PV: this wave c-strip cw; A = P' (swizzled read), B = Vv rows
        #pragma unroll
        for (int kk = 0; kk < 2; kk++) {
            short8 ap[4];
            #pragma unroll
            for (int pst = 0; pst < 4; pst++)
                ap[pst] = *(const short8*)(&Pl[pst * 16 + ml]
                           [((4 * kk + q) ^ ((ml >> 1) & 7)) * 8]);
            #pragma unroll
            for (int jt = 0; jt < 4; jt++) {
                int row = cw + jt * 16 + ml;
                int slot = (kk * 4 + q) ^ (row & 7);
                short8 bv = *(const short8*)(&Vv[row * 64 + slot * 8]);
                #pragma unroll
                for (int pst = 0; pst < 4; pst++)
                    pv[pst][jt] = __builtin_amdgcn_mfma_f32_16x16x32_bf16(
                        ap[pst], bv, pv[pst][jt], 0, 0, 0);
            }
        }
    }
    // cs partial: reduce over 16 m-lanes, one PLAIN store per (z, p-row)
    #pragma unroll
    for (int r = 0; r < 4; r++) {
        float s = csr[r];
        s += __shfl_xor(s, 1); s += __shfl_xor(s, 2);
        s += __shfl_xor(s, 4); s += __shfl_xor(s, 8);
        if (ml == 0) csp[(long long)z * NPTS + p0 + pw + q * 4 + r] = s;
    }
    // store PV partials (plain f32)
    float* C = part + (long long)z * ((long long)NPTS * 256);
    #pragma unroll
    for (int pst = 0; pst < 4; pst++)
        #pragma unroll
        for (int jt = 0; jt < 4; jt++)
            #pragma unroll
            for (int r = 0; r < 4; r++) {
                int rg = p0 + pst * 16 + q * 4 + r;
                int cg = cw + jt * 16 + ml;
                C[(long long)rg * 256 + cg] = pv[pst][jt][r];
            }
}

// ---------------- small kernels ----------------
__global__ __launch_bounds__(256)
void conv1_k(const float* __restrict__ x, const float* __restrict__ w,
             const float* __restrict__ g, const float* __restrict__ bb,
             unsigned short* __restrict__ h, long long h_po)
{
    int b = blockIdx.y;
    int p = blockIdx.x * 4 + (threadIdx.x >> 6);
    int c = threadIdx.x & 63;
    const float* xp = x + ((long long)b * NPTS + p) * 3;
    float y = xp[0] * w[c * 3] + xp[1] * w[c * 3 + 1] + xp[2] * w[c * 3 + 2];
    y = y * (INV_STD * g[c]) + bb[c];
    y = fmaxf(y, 0.f);
    long long i = ((long long)b * NPTS + p) * 64 + c;
    unsigned short hi = f2bf(y);
    h[i] = hi;
    h[h_po + i] = f2bf(y - bf2f(hi));
}

__global__ __launch_bounds__(256)
void zero_k(float* __restrict__ p, int n)
{
    int i = blockIdx.x * 256 + threadIdx.x;
    if (i < n) p[i] = 0.f;
}

// d = x - (sum_ms part)/(1e-9 + sum_ms csp); vectorized x4, bit-identical ops
__global__ __launch_bounds__(256)
void diff_k(const unsigned short* __restrict__ xin, long long x_bs, int x_ld, long long x_po,
            const float* __restrict__ part, const float* __restrict__ csp,
            unsigned short* __restrict__ d, long long d_po)
{
    long long i4 = ((long long)blockIdx.x * 256 + threadIdx.x) * 4;  // over NPTS*256
    int b = blockIdx.y;
    int p = (int)(i4 >> 8), c = (int)(i4 & 255);
    long long xi = (long long)b * x_bs + (long long)p * x_ld + c;
    s16x4 xh = *(const s16x4*)(xin + xi);
    s16x4 xl = *(const s16x4*)(xin + x_po + xi);
    float xr0 = 0.f, xr1 = 0.f, xr2 = 0.f, xr3 = 0.f, den = 1e-9f;
    #pragma unroll
    for (int ks = 0; ks < MSPLIT; ks++) {
        int z = b * MSPLIT + ks;
        f32x4 pv = *(const f32x4*)(part + (long long)z * ((long long)NPTS * 256) + i4);
        xr0 += pv[0]; xr1 += pv[1]; xr2 += pv[2]; xr3 += pv[3];
        den += csp[(long long)z * NPTS + p];
    }
    float v0 = bf2f((unsigned short)xh[0]) + bf2f((unsigned short)xl[0]) - xr0 / den;
    float v1 = bf2f((unsigned short)xh[1]) + bf2f((unsigned short)xl[1]) - xr1 / den;
    float v2 = bf2f((unsigned short)xh[2]) + bf2f((unsigned short)xl[2]) - xr2 / den;
    float v3 = bf2f((unsigned short)xh[3]) + bf2f((unsigned short)xl[3]) - xr3 / den;
    long long di = (long long)b * NPTS * 256 + i4;
    s16x4 hh, ll;
    hh[0] = (short)f2bf(v0); ll[0] = (short)f2bf(v0 - bf2f((unsigned short)hh[0]));
    hh[1] = (short)f2bf(v1); ll[1] = (short)f2bf(v1 - bf2f((unsigned short)hh[1]));
    hh[2] = (short)f2bf(v2); ll[2] = (short)f2bf(v2 - bf2f((unsigned short)hh[2]));
    hh[3] = (short)f2bf(v3); ll[3] = (short)f2bf(v3 - bf2f((unsigned short)hh[3]));
    *(s16x4*)(d + di) = hh;
    *(s16x4*)(d + d_po + di) = ll;
}

// gmax stage 1: grid (4, 16, B), block = 256 = 4 waves; block covers 64
// points x all 512 channels. Wave reads one full row (short8/lane) per step.
__global__ __launch_bounds__(256)
void gmaxp_k(const unsigned short* __restrict__ face, long long f_po, float* __restrict__ pm)
{
    __shared__ float red[4][512];
    int b = blockIdx.z;
    int seg = blockIdx.y * 4 + blockIdx.x;    // 0..63, 64-point segment
    int w = threadIdx.x >> 6, l = threadIdx.x & 63;
    float m8[8];
    #pragma unroll
    for (int k = 0; k < 8; k++) m8[k] = -3.4e38f;
    for (int jj = 0; jj < 16; jj++) {
        int i = seg * 64 + jj * 4 + w;
        long long off = ((long long)b * NPTS + i) * 512 + l * 8;
        short8 h = *(const short8*)(face + off);
        short8 lo = *(const short8*)(face + f_po + off);
        #pragma unroll
        for (int k = 0; k < 8; k++)
            m8[k] = fmaxf(m8[k], bf2f((unsigned short)h[k]) + bf2f((unsigned short)lo[k]));
    }
    #pragma unroll
    for (int k = 0; k < 8; k++) red[w][l * 8 + k] = m8[k];
    __syncthreads();
    for (int c = threadIdx.x; c < 512; c += 256) {
        float m = fmaxf(fmaxf(red[0][c], red[1][c]), fmaxf(red[2][c], red[3][c]));
        pm[((long long)b * 64 + seg) * 512 + c] = m;
    }
}

// gmax stage 2 + s1 broadcast-bias, fused: gm[512] in LDS, then 512-dot.
__global__ __launch_bounds__(256)
void bias2_k(const float* __restrict__ w, const float* __restrict__ pm, float* __restrict__ b2)
{
    __shared__ float gml[512];
    int b = blockIdx.y;
    for (int c = threadIdx.x; c < 512; c += 256) {
        float m = -3.4e38f;
        for (int ch = 0; ch < 64; ch++)
            m = fmaxf(m, pm[((long long)b * 64 + ch) * 512 + c]);
        gml[c] = m;
    }
    __syncthreads();
    int o = blockIdx.x * 256 + threadIdx.x;
    float s = 0.f;
    for (int c = 0; c < 512; c++) s += w[(long long)o * 1024 + 512 + c] * gml[c];
    b2[b * 512 + o] = s;
}

extern "C" void kernel_launch(void* const* d_in, const int* in_sizes, int n_in,
                              void* d_out, int out_size, void* d_ws, size_t ws_size,
                              hipStream_t stream)
{
    const float* x       = (const float*)d_in[0];
    const float* conv1_w = (const float*)d_in[1];
    const float* bn1_g   = (const float*)d_in[2];
    const float* bn1_b   = (const float*)d_in[3];
    const float* conv2_w = (const float*)d_in[4];
    const float* bn2_g   = (const float*)d_in[5];
    const float* bn2_b   = (const float*)d_in[6];
    const float* conv3_w = (const float*)d_in[7];
    const float* bn3_g   = (const float*)d_in[8];
    const float* bn3_b   = (const float*)d_in[9];
    const float* pt1_w   = (const float*)d_in[10];
    const float* pt1_g   = (const float*)d_in[11];
    const float* pt1_b   = (const float*)d_in[12];
    const float* pt2_w   = (const float*)d_in[13];
    const float* pt2_g   = (const float*)d_in[14];
    const float* pt2_b   = (const float*)d_in[15];
    const float* sa_qk[2] = {(const float*)d_in[16], (const float*)d_in[23]};
    const float* sa_vw[2] = {(const float*)d_in[17], (const float*)d_in[24]};
    const float* sa_vb[2] = {(const float*)d_in[18], (const float*)d_in[25]};
    const float* sa_tw[2] = {(const float*)d_in[19], (const float*)d_in[26]};
    const float* sa_tb[2] = {(const float*)d_in[20], (const float*)d_in[27]};
    const float* sa_g[2]  = {(const float*)d_in[21], (const float*)d_in[28]};
    const float* sa_b[2]  = {(const float*)d_in[22], (const float*)d_in[29]};
    const float* cf_w = (const float*)d_in[30];
    const float* cf_g = (const float*)d_in[31];
    const float* cf_b = (const float*)d_in[32];
    const float* s1_w = (const float*)d_in[33];
    const float* s1_g = (const float*)d_in[34];
    const float* s1_b = (const float*)d_in[35];
    const float* s2_w = (const float*)d_in[36];
    const float* s2_g = (const float*)d_in[37];
    const float* s2_b = (const float*)d_in[38];
    const float* s3_w = (const float*)d_in[39];

    char* base = (char*)d_ws;
    size_t off = 0;
    auto alloc = [&](size_t bytes) -> void* {
        void* p = base + off;
        off = (off + bytes + 255) & ~(size_t)255;
        return p;
    };
    const long long N = NPTS;
    const long long PO64   = (long long)BATCH * N * 64;
    const long long PO128  = (long long)BATCH * N * 128;
    const long long PO256  = (long long)BATCH * N * 256;
    const long long PO512  = (long long)BATCH * N * 512;
    const long long PO1024 = (long long)BATCH * N * 1024;

    unsigned short* S1  = (unsigned short*)alloc(2 * PO256 * 2);
    unsigned short* S2  = (unsigned short*)alloc(2 * PO256 * 2);
    unsigned short* Dv  = (unsigned short*)alloc(2 * PO256 * 2);
    unsigned short* cat = (unsigned short*)alloc(2 * PO1024 * 2);
    unsigned short* face = (unsigned short*)alloc(2 * PO512 * 2);
    unsigned short* xq  = (unsigned short*)alloc((size_t)BATCH * N * 128 * 2);
    unsigned short* xv  = (unsigned short*)alloc((size_t)BATCH * 256 * N * 2);
    unsigned short* s1b = (unsigned short*)alloc(2 * PO512 * 2);
    unsigned short* s2b = (unsigned short*)alloc(2 * PO256 * 2);
    float* part = (float*)alloc((size_t)BATCH * MSPLIT * N * 256 * 4);          // 32 MB
    float* csp  = (float*)alloc((size_t)BATCH * MSPLIT * N * 4);
    float* rs = (float*)alloc((size_t)4 * BATCH * N * 4);   // per-layer buffers
    float* pm = (float*)alloc((size_t)BATCH * 64 * 512 * 4);
    float* b2 = (float*)alloc((size_t)BATCH * 512 * 4);
    unsigned short* wb = (unsigned short*)alloc((size_t)3400000 * 2);  // pre-split weights

    // ---- weight pre-split table ----
    WSplit wd;
    const float* wsrc[14] = {conv2_w, conv3_w, pt1_w, pt2_w, sa_qk[0], sa_qk[1],
                             sa_vw[0], sa_vw[1], sa_tw[0], sa_tw[1], cf_w, s1_w, s2_w, s3_w};
    int wn[14] = {128*64, 256*128, 256*256, 256*256, 128*256, 128*256,
                  256*256, 256*256, 256*256, 256*256, 512*1024, 512*1024, 256*512, 50*256};
    long long wo[14]; long long acc_ = 0;
    for (int i = 0; i < 14; i++) { wd.src[i] = wsrc[i]; wd.n[i] = wn[i]; wd.off[i] = acc_; wo[i] = acc_; acc_ += 2LL * wn[i]; }
    presplit_k<<<dim3((512*1024 + 255) / 256, 14), 256, 0, stream>>>(wd, wb);
    auto W = [&](int i) { return wb + wo[i]; };

    auto nt = [&](const unsigned short* A, long long a_bs, int a_lda, long long a_po,
                  const unsigned short* B, long long b_bs, int b_lda, long long b_po,
                  void* C, long long c_bs, int c_ld, long long c_po,
                  int Mrows, int Nb, int K,
                  const float* bias, int bias_mode,
                  const float* bng, const float* bnb,
                  const unsigned short* res, long long res_bs, int res_ld, long long res_po,
                  int act, int out_mode) {
        dim3 g((Nb + 63) / 64, Mrows / 64, BATCH);
        gemm_nt_split<<<g, 256, 0, stream>>>(A, a_bs, a_lda, a_po, B, b_bs, b_lda, b_po,
                                             C, c_bs, c_ld, c_po, Nb, K,
                                             bias, bias_mode, bng, bnb,
                                             res, res_bs, res_ld, res_po, act, out_mode);
    };
    auto ntB = [&](const unsigned short* A, long long a_bs, int a_lda, long long a_po,
                   const unsigned short* B, long long b_bs, int b_lda, long long b_po,
                   void* C, long long c_bs, int c_ld, long long c_po,
                   int Mrows, int Nb, int K,
                   const float* bias, int bias_mode,
                   const float* bng, const float* bnb,
                   const unsigned short* res, long long res_bs, int res_ld, long long res_po,
                   int act, int out_mode) {
        dim3 g((Nb + 63) / 64, Mrows / 64, BATCH);
        gemm_nt_splitB<<<g, 256, 0, stream>>>(A, a_bs, a_lda, a_po, B, b_bs, b_lda, b_po,
                                              C, c_bs, c_ld, c_po, Nb, K,
                                              bias, bias_mode, bng, bnb,
                                              res, res_bs, res_ld, res_po, act, out_mode);
    };
    auto nt3 = [&](const unsigned short* A, long long a_bs, int a_lda, long long a_po,
                   const unsigned short* B, long long b_bs, int b_lda, long long b_po,
                   void* C, long long c_bs, int c_ld, long long c_po,
                   int Mrows, int Nb, int K,
                   const float* bias, int bias_mode,
                   const float* bng, const float* bnb,
                   const unsigned short* res, long long res_bs, int res_ld, long long res_po,
                   int act, int out_mode) {
        dim3 g((Nb + 63) / 64, Mrows / 128, BATCH);
        gemm_nt_split3<<<g, 256, 0, stream>>>(A, a_bs, a_lda, a_po, B, b_bs, b_lda, b_po,
                                              C, c_bs, c_ld, c_po, Nb, K,
                                              bias, bias_mode, bng, bnb,
                                              res, res_bs, res_ld, res_po, act, out_mode);
    };

    // ---- stem ----
    conv1_k<<<dim3(NPTS / 4, BATCH), 256, 0, stream>>>(x, conv1_w, bn1_g, bn1_b, S1, PO64);
    // zero ALL per-layer rs buffers once
    zero_k<<<(4 * BATCH * NPTS + 255) / 256, 256, 0, stream>>>(rs, 4 * BATCH * NPTS);
    nt(S1, N * 64, 64, PO64,    W(0), 0, 64, wn[0],  S2, N * 128, 128, PO128,
       NPTS, 128, 64,  nullptr, 0, bn2_g, bn2_b, nullptr, 0, 0, 0, 1, 0);
    ntB(S2, N * 128, 128, PO128, W(1), 0, 128, wn[1], S1, N * 256, 256, PO256,
        NPTS, 256, 128, nullptr, 0, bn3_g, bn3_b, nullptr, 0, 0, 0, 1, 0);
    ntB(S1, N * 256, 256, PO256, W(2), 0, 256, wn[2], S2, N * 256, 256, PO256,
        NPTS, 256, 256, nullptr, 0, pt1_g, pt1_b, nullptr, 0, 0, 0, 1, 0);
    ntB(S2, N * 256, 256, PO256, W(3), 0, 256, wn[3], S1, N * 256, 256, PO256,
        NPTS, 256, 256, nullptr, 0, pt2_g, pt2_b, nullptr, 0, 0, 0, 1, 0);

    // ---- 4 SA layers ----
    for (int i = 0; i < 4; i++) {
        int p = (i == 0) ? 0 : 1;
        const unsigned short* xin = (i == 0) ? S1 : cat + (size_t)(i - 1) * 256;
        long long xin_bs = (i == 0) ? N * 256 : N * 1024;
        int xin_ld = (i == 0) ? 256 : 1024;
        long long xin_po = (i == 0) ? PO256 : PO1024;
        float* rsL = rs + (size_t)i * BATCH * NPTS;

        // xq[n][128] plain bf16 (K=256)
        ntB(xin, xin_bs, xin_ld, xin_po, W(4 + p), 0, 256, wn[4 + p],
            xq, N * 128, 128, 0, NPTS, 128, 256,
            nullptr, 0, nullptr, nullptr, nullptr, 0, 0, 0, 0, 1);
        // xv[c][n] plain bf16 (A = weights, K=256)
        ntB(W(6 + p), 0, 256, wn[6 + p], xin, xin_bs, xin_ld, xin_po,
            xv, 256 * N, NPTS, 0, 256, NPTS, 256,
            sa_vb[p], 3, nullptr, nullptr, nullptr, 0, 0, 0, 0, 1);
        // E1: rs row-sums (atomic, rsL pre-zeroed)
        rs_k<<<dim3(RSSPLIT, NPTS / 64, BATCH), 256, 0, stream>>>(xq, rsL);
        // E2: fused QK->exp/rs->PV partials + cs partials
        attn_pv<<<dim3(1, NPTS / 64, BATCH * MSPLIT), 256, 0, stream>>>(
            xq, xv, rsL, part, csp);
        // d = x - (sum partials)/(1e-9 + sum cs partials)
        diff_k<<<dim3(NPTS * 256 / 1024, BATCH), 256, 0, stream>>>(
            xin, xin_bs, xin_ld, xin_po, part, csp, Dv, PO256);
        // x_out = x + relu(bn(tw@d + tb)) -> cat slice i (K=256)
        ntB(Dv, N * 256, 256, PO256, W(8 + p), 0, 256, wn[8 + p],
            cat + (size_t)i * 256, N * 1024, 1024, PO1024,
            NPTS, 256, 256, sa_tb[p], 1, sa_g[p], sa_b[p],
            xin, xin_bs, xin_ld, xin_po, 1, 0);
    }

    // ---- head ----
    nt3(cat, N * 1024, 1024, PO1024, W(10), 0, 1024, wn[10],
        face, N * 512, 512, PO512, NPTS, 512, 1024,
        nullptr, 0, cf_g, cf_b, nullptr, 0, 0, 0, 2, 0);
    gmaxp_k<<<dim3(4, 16, BATCH), 256, 0, stream>>>(face, PO512, pm);
    bias2_k<<<dim3(2, BATCH), 256, 0, stream>>>(s1_w, pm, b2);
    nt3(face, N * 512, 512, PO512, W(11), 0, 1024, wn[11],
        s1b, N * 512, 512, PO512, NPTS, 512, 512,
        b2, 2, s1_g, s1_b, nullptr, 0, 0, 0, 2, 0);
    ntB(s1b, N * 512, 512, PO512, W(12), 0, 512, wn[12],
        s2b, N * 256, 256, PO256, NPTS, 256, 512,
        nullptr, 0, s2_g, s2_b, nullptr, 0, 0, 0, 2, 0);
    ntB(s2b, N * 256, 256, PO256, W(13), 0, 256, wn[13],
        d_out, N * 50, 50, 0, NPTS, 50, 256,
        nullptr, 0, nullptr, nullptr, nullptr, 0, 0, 0, 0, 2);
}